// Round 10
// baseline (1698.824 us; speedup 1.0000x reference)
//
#include <hip/hip_runtime.h>
#include <stdint.h>

#define NN 8192
#define NE 65536
#define ET (NE + NN)
#define F_IN   3247
#define F_IN_P 3264
#define F_EXP   7993
#define F_EXP_P 8000

typedef __attribute__((ext_vector_type(8))) short bf16x8;
typedef __attribute__((ext_vector_type(4))) float f32x4;

typedef const __attribute__((address_space(1))) void gvoid_t;
typedef __attribute__((address_space(3))) void lvoid_t;

__device__ __forceinline__ float bf2f(uint16_t u) {
  union { uint32_t i; float f; } v; v.i = ((uint32_t)u) << 16; return v.f;
}
__device__ __forceinline__ uint16_t f2bf(float f) {
  union { float f; uint32_t i; } v; v.f = f;
  uint32_t r = v.i + 0x7fffu + ((v.i >> 16) & 1u);  // RNE
  return (uint16_t)(r >> 16);
}

__device__ __forceinline__ void gld_lds16(const void* g, void* l) {
  __builtin_amdgcn_global_load_lds((gvoid_t*)g, (lvoid_t*)l, 16, 0, 0);
}

#define SBAR() __builtin_amdgcn_sched_barrier(0)
#define BARRIER() do { SBAR(); __builtin_amdgcn_s_barrier(); SBAR(); } while (0)
#define VMCNT(n) asm volatile("s_waitcnt vmcnt(" #n ")" ::: "memory")
#define MFMA16(a, b, c) __builtin_amdgcn_mfma_f32_16x16x32_bf16(a, b, c, 0, 0, 0)

// =================================================================== gemm256
// 256x256 tile, BK=64, 8 waves (2M x 4N). 4 phases/K-tile, 1 barrier/phase.
// Low-pressure lookahead (peak 20 frag groups), b01 re-read, T2 swizzle.
// Staging: one half-tile (2 gld_lds) per phase with hazard-safe placement:
//   P0: B-half0(T+1)->other buf   (other-B last read-issue: T-1.P2)
//   P1: B-half1(T+1)->other buf
//   P2: A-half0(T+2)->this buf    (this-A last read-issue: a47 @ P1)
//   P3: A-half1(T+2)->this buf
// Counted vmcnt guards BEFORE the closing barrier (cross-wave sound):
//   end-P2: retire A(T+1)  -> vmcnt(nls?6:4)   [guards P3's a03(T+1) read]
//   end-P3: retire B(T+1)  -> vmcnt(nls?4:0)   [guards next P0's b reads]
__device__ __forceinline__ void stage2(const char* src, char* dst, size_t Kb) {
  gld_lds16(src, dst);
  gld_lds16(src + (size_t)64 * Kb, dst + 8192);
}

#define KTILE(T, BUF)                                                          \
  do {                                                                         \
    const char* aB_  = smem + (BUF) + arow;                                    \
    const char* bB_  = smem + 65536 + (BUF) + brow_o;                          \
    const char* aBn_ = smem + ((BUF) ^ 32768) + arow;                          \
    char* sAt = sA + (BUF);                                                    \
    char* sBo = sB + ((BUF) ^ 32768);                                          \
    const bool nls = ((T) + 2 < nk);                                           \
    const bool nlr = ((T) + 1 < nk);                                           \
    /* P0: read b01,b23(T); stage B-half0(T+1); MFMA Q0 (a03 x b01) */         \
    _Pragma("unroll")                                                          \
    for (int n = 0; n < 2; ++n) {                                              \
      b01[n * 2]     = *(const bf16x8*)(bB_ + n * 2048 + sw0);                 \
      b01[n * 2 + 1] = *(const bf16x8*)(bB_ + n * 2048 + sw1);                 \
    }                                                                          \
    _Pragma("unroll")                                                          \
    for (int n = 0; n < 2; ++n) {                                              \
      b23[n * 2]     = *(const bf16x8*)(bB_ + (n + 2) * 2048 + sw0);           \
      b23[n * 2 + 1] = *(const bf16x8*)(bB_ + (n + 2) * 2048 + sw1);           \
    }                                                                          \
    if (nlr) stage2(pB + (size_t)((T) + 1) * 128, sBo, Kb);                    \
    SBAR();                                                                    \
    __builtin_amdgcn_s_setprio(1);                                             \
    _Pragma("unroll")                                                          \
    for (int m = 0; m < 4; ++m)                                                \
      _Pragma("unroll")                                                        \
      for (int n = 0; n < 2; ++n) {                                            \
        acc[m][n] = MFMA16(a03[m * 2],     b01[n * 2],     acc[m][n]);         \
        acc[m][n] = MFMA16(a03[m * 2 + 1], b01[n * 2 + 1], acc[m][n]);         \
      }                                                                        \
    __builtin_amdgcn_s_setprio(0);                                             \
    BARRIER();                                                                 \
    /* P1: read a47(T); stage B-half1(T+1); MFMA Q1 (a03 x b23) */             \
    _Pragma("unroll")                                                          \
    for (int m = 0; m < 4; ++m) {                                              \
      a47[m * 2]     = *(const bf16x8*)(aB_ + (m + 4) * 2048 + sw0);           \
      a47[m * 2 + 1] = *(const bf16x8*)(aB_ + (m + 4) * 2048 + sw1);           \
    }                                                                          \
    if (nlr) stage2(pB + (size_t)((T) + 1) * 128 + 128 * Kb, sBo + 16384, Kb); \
    SBAR();                                                                    \
    __builtin_amdgcn_s_setprio(1);                                             \
    _Pragma("unroll")                                                          \
    for (int m = 0; m < 4; ++m)                                                \
      _Pragma("unroll")                                                        \
      for (int n = 0; n < 2; ++n) {                                            \
        acc[m][n + 2] = MFMA16(a03[m * 2],     b23[n * 2],     acc[m][n + 2]); \
        acc[m][n + 2] = MFMA16(a03[m * 2 + 1], b23[n * 2 + 1], acc[m][n + 2]); \
      }                                                                        \
    __builtin_amdgcn_s_setprio(0);                                             \
    BARRIER();                                                                 \
    /* P2: re-read b01(T); stage A-half0(T+2); MFMA Q2 (a47 x b23); guard A(T+1) */ \
    _Pragma("unroll")                                                          \
    for (int n = 0; n < 2; ++n) {                                              \
      b01[n * 2]     = *(const bf16x8*)(bB_ + n * 2048 + sw0);                 \
      b01[n * 2 + 1] = *(const bf16x8*)(bB_ + n * 2048 + sw1);                 \
    }                                                                          \
    if (nls) stage2(pA + (size_t)((T) + 2) * 128, sAt, Kb);                    \
    SBAR();                                                                    \
    __builtin_amdgcn_s_setprio(1);                                             \
    _Pragma("unroll")                                                          \
    for (int m = 0; m < 4; ++m)                                                \
      _Pragma("unroll")                                                        \
      for (int n = 0; n < 2; ++n) {                                            \
        acc[m + 4][n + 2] = MFMA16(a47[m * 2],     b23[n * 2],     acc[m + 4][n + 2]); \
        acc[m + 4][n + 2] = MFMA16(a47[m * 2 + 1], b23[n * 2 + 1], acc[m + 4][n + 2]); \
      }                                                                        \
    __builtin_amdgcn_s_setprio(0);                                             \
    if (nlr) { if (nls) { VMCNT(6); } else { VMCNT(4); } }                     \
    BARRIER();                                                                 \
    /* P3: read a03(T+1); stage A-half1(T+2); MFMA Q3 (a47 x b01); guard B(T+1) */ \
    if (nlr) {                                                                 \
      _Pragma("unroll")                                                        \
      for (int m = 0; m < 4; ++m) {                                            \
        a03[m * 2]     = *(const bf16x8*)(aBn_ + m * 2048 + sw0);              \
        a03[m * 2 + 1] = *(const bf16x8*)(aBn_ + m * 2048 + sw1);              \
      }                                                                        \
    }                                                                          \
    if (nls) stage2(pA + (size_t)((T) + 2) * 128 + 128 * Kb, sAt + 16384, Kb); \
    SBAR();                                                                    \
    __builtin_amdgcn_s_setprio(1);                                             \
    _Pragma("unroll")                                                          \
    for (int m = 0; m < 4; ++m)                                                \
      _Pragma("unroll")                                                        \
      for (int n = 0; n < 2; ++n) {                                            \
        acc[m + 4][n] = MFMA16(a47[m * 2],     b01[n * 2],     acc[m + 4][n]); \
        acc[m + 4][n] = MFMA16(a47[m * 2 + 1], b01[n * 2 + 1], acc[m + 4][n]); \
      }                                                                        \
    __builtin_amdgcn_s_setprio(0);                                             \
    if (nlr) { if (nls) { VMCNT(4); } else { VMCNT(0); } }                     \
    BARRIER();                                                                 \
  } while (0)

__global__ __launch_bounds__(512, 2)
void gemm256(const uint16_t* __restrict__ A, const uint16_t* __restrict__ Bt,
             const float* __restrict__ bias, int biasN, int relu,
             uint16_t* __restrict__ C, int Kp, int ldc, int nbn)
{
  extern __shared__ char smem[];   // [A: 2buf x 4 x 64rows x 128B = 64K][B: same]
  const int tid = threadIdx.x;
  const int w = tid >> 6, lane = tid & 63;
  const int wr = w >> 2, wc = w & 3;
  const int fr = lane & 15, g = lane >> 4;

  // T1: bijective XCD swizzle
  const int nwg = (int)gridDim.x;
  const int id = (int)blockIdx.x;
  const int q = nwg >> 3, r = nwg & 7;
  const int xcd = id & 7, idx = id >> 3;
  const int wg = (xcd < r ? xcd * (q + 1) : r * (q + 1) + (xcd - r) * q) + idx;
  const int brow = (wg / nbn) * 256, bcol = (wg % nbn) * 256;

  const size_t Kb = (size_t)Kp * 2;

  // staging: thread tid -> LDS j*8192 + (tid>>3)*128 + (tid&7)*16 (lane*16 by HW)
  const int srow = tid >> 3;
  const int sswz = ((tid & 7) ^ (srow & 7)) * 16;
  const char* pA = (const char*)A + (size_t)(brow + srow) * Kb + sswz;
  const char* pB = (const char*)Bt + (size_t)(bcol + srow) * Kb + sswz;
  char* sA = smem + w * 1024;
  char* sB = smem + 65536 + w * 1024;

  // frag read: slot q=kk*4+g stored at q ^ (row&7), row&7 == fr&7
  const int sw0 = (g ^ (fr & 7)) * 16;
  const int sw1 = ((g + 4) ^ (fr & 7)) * 16;
  const int arow = (wr * 128 + fr) * 128;   // + m*2048
  const int brow_o = (wc * 64 + fr) * 128;  // + n*2048

  f32x4 acc[8][4];
#pragma unroll
  for (int m = 0; m < 8; ++m)
#pragma unroll
    for (int n = 0; n < 4; ++n) acc[m][n] = (f32x4){0.f, 0.f, 0.f, 0.f};
  bf16x8 a03[8], a47[8], b01[4], b23[4];

  // prologue: A(0), B(0), A(1) staged (12 loads); retire through B(0); preload a03(0)
  stage2(pA, sA, Kb);                                  // A-half0(0)
  stage2(pA + 128 * Kb, sA + 16384, Kb);               // A-half1(0)
  stage2(pB, sB, Kb);                                  // B-half0(0)
  stage2(pB + 128 * Kb, sB + 16384, Kb);               // B-half1(0)
  stage2(pA + 128, sA + 32768, Kb);                    // A-half0(1)
  stage2(pA + 128 + 128 * Kb, sA + 32768 + 16384, Kb); // A-half1(1)
  VMCNT(4);                                            // retire A(0),B(0)
  BARRIER();
  {
    const char* aB = smem + arow;
#pragma unroll
    for (int m = 0; m < 4; ++m) {
      a03[m * 2]     = *(const bf16x8*)(aB + m * 2048 + sw0);
      a03[m * 2 + 1] = *(const bf16x8*)(aB + m * 2048 + sw1);
    }
  }
  SBAR();

  const int nk = Kp >> 6;
  for (int t = 0; t < nk; t += 2) {
    KTILE(t, 0);
    if (t + 1 < nk) KTILE(t + 1, 32768);
  }

  // epilogue: C/D layout col=lane&15, row=(lane>>4)*4+j
#pragma unroll
  for (int m = 0; m < 8; ++m) {
    const int row = brow + wr * 128 + m * 16 + g * 4;
#pragma unroll
    for (int n = 0; n < 4; ++n) {
      const int col = bcol + wc * 64 + n * 16 + fr;
      const float bv = (col < biasN) ? bias[col] : 0.f;
#pragma unroll
      for (int j = 0; j < 4; ++j) {
        float v = acc[m][n][j] + bv;
        if (relu) v = fmaxf(v, 0.f);
        C[(size_t)(row + j) * ldc + col] = f2bf(v);
      }
    }
  }
}

// ---------------------------------------------------------------- GEMM (m97 structure, small N)
__global__ __launch_bounds__(256)
void gemm_bt(const uint16_t* __restrict__ A, const uint16_t* __restrict__ Bt,
             const float* __restrict__ bias, int biasN, int relu,
             uint16_t* __restrict__ C, int Kp, int ldc)
{
  __shared__ uint16_t As[128 * 32];
  __shared__ uint16_t Bs[128 * 32];
  const int tid  = threadIdx.x;
  const int wave = tid >> 6, lane = tid & 63;
  const int brow = blockIdx.x * 128, bcol = blockIdx.y * 128;
  const int wr = wave >> 1, wc = wave & 1;
  const int fr = lane & 15, g = lane >> 4;

  f32x4 acc[4][4];
#pragma unroll
  for (int m = 0; m < 4; ++m)
#pragma unroll
    for (int n = 0; n < 4; ++n) acc[m][n] = (f32x4){0.f, 0.f, 0.f, 0.f};

  const int rA = tid >> 2;
  const int kc = (tid & 3) * 8;
  const uint16_t* aptr = A  + (size_t)(brow + rA) * Kp + kc;
  const uint16_t* bptr = Bt + (size_t)(bcol + rA) * Kp + kc;
  char* ldsA = (char*)As + wave * 1024;
  char* ldsB = (char*)Bs + wave * 1024;
  const size_t rowskip = (size_t)64 * Kp;

  const int nk = Kp >> 5;
  for (int kt = 0; kt < nk; ++kt) {
    __syncthreads();
    gld_lds16(aptr,           ldsA);
    gld_lds16(aptr + rowskip, ldsA + 4096);
    gld_lds16(bptr,           ldsB);
    gld_lds16(bptr + rowskip, ldsB + 4096);
    aptr += 32; bptr += 32;
    __syncthreads();

    bf16x8 af[4], bfr[4];
#pragma unroll
    for (int m = 0; m < 4; ++m)
      af[m] = *(const bf16x8*)&As[(wr * 64 + m * 16 + fr) * 32 + g * 8];
#pragma unroll
    for (int n = 0; n < 4; ++n)
      bfr[n] = *(const bf16x8*)&Bs[(wc * 64 + n * 16 + fr) * 32 + g * 8];
#pragma unroll
    for (int m = 0; m < 4; ++m)
#pragma unroll
      for (int n = 0; n < 4; ++n)
        acc[m][n] = MFMA16(af[m], bfr[n], acc[m][n]);
  }

#pragma unroll
  for (int m = 0; m < 4; ++m) {
    const int row = brow + wr * 64 + m * 16 + g * 4;
#pragma unroll
    for (int n = 0; n < 4; ++n) {
      const int col = bcol + wc * 64 + n * 16 + fr;
      const float bv = (col < biasN) ? bias[col] : 0.f;
#pragma unroll
      for (int j = 0; j < 4; ++j) {
        float v = acc[m][n][j] + bv;
        if (relu) v = fmaxf(v, 0.f);
        C[(size_t)(row + j) * ldc + col] = f2bf(v);
      }
    }
  }
}

// ---------------------------------------------------------------- conversions
__global__ __launch_bounds__(256)
void cvt_pad(const float* __restrict__ in, uint16_t* __restrict__ out, int cols, int colsPad)
{
  const int r = blockIdx.y;
  const int c = (blockIdx.x * 256 + threadIdx.x) * 2;
  if (c >= colsPad) return;
  const float* ip = in + (size_t)r * cols;
  const float v0 = (c < cols)     ? ip[c]     : 0.f;
  const float v1 = (c + 1 < cols) ? ip[c + 1] : 0.f;
  const uint32_t pk = (uint32_t)f2bf(v0) | ((uint32_t)f2bf(v1) << 16);
  *(uint32_t*)(out + (size_t)r * colsPad + c) = pk;
}

__global__ __launch_bounds__(256)
void transpose_w(const float* __restrict__ W, uint16_t* __restrict__ Wt,
                 int K, int N, int Kp, int Np)
{
  __shared__ float t[32][33];
  const int tx = threadIdx.x, ty = threadIdx.y;
  const int k0 = blockIdx.x * 32, n0 = blockIdx.y * 32;
#pragma unroll
  for (int j = 0; j < 4; ++j) {
    const int k = k0 + ty + j * 8, n = n0 + tx;
    t[ty + j * 8][tx] = (k < K && n < N) ? W[(size_t)k * N + n] : 0.f;
  }
  __syncthreads();
#pragma unroll
  for (int j = 0; j < 4; ++j) {
    const int n = n0 + ty + j * 8, k = k0 + tx;
    Wt[(size_t)n * Kp + k] = f2bf(t[tx][ty + j * 8]);
  }
}

__global__ void concat_bias(const float* __restrict__ bl, const float* __restrict__ br,
                            float* __restrict__ out)
{
  const int i = blockIdx.x * 256 + threadIdx.x;
  if (i < 1536) out[i] = bl[i];
  else if (i < 3072) out[i] = br[i - 1536];
}

// ---------------------------------------------------------------- CSR build
__global__ void count_deg(const int* __restrict__ ei, int* __restrict__ counts)
{
  const int e = blockIdx.x * 256 + threadIdx.x;
  if (e >= ET) return;
  const int d = (e < NE) ? ei[NE + e] : (e - NE);
  atomicAdd(&counts[d], 1);
}

__global__ __launch_bounds__(1024)
void scan_deg(const int* __restrict__ counts, int* __restrict__ row_start, int* __restrict__ cursor)
{
  __shared__ int part[1024];
  const int tid = threadIdx.x;
  int loc[8], pre[8], s = 0;
#pragma unroll
  for (int j = 0; j < 8; ++j) { loc[j] = counts[tid * 8 + j]; pre[j] = s; s += loc[j]; }
  part[tid] = s;
  __syncthreads();
  for (int o = 1; o < 1024; o <<= 1) {
    const int v = part[tid];
    const int a = (tid >= o) ? part[tid - o] : 0;
    __syncthreads();
    part[tid] = v + a;
    __syncthreads();
  }
  const int excl = part[tid] - s;
#pragma unroll
  for (int j = 0; j < 8; ++j) {
    const int v = excl + pre[j];
    row_start[tid * 8 + j] = v;
    cursor[tid * 8 + j]    = v;
  }
  if (tid == 1023) row_start[8192] = excl + s;
}

__global__ void scatter_e(const int* __restrict__ ei, int* __restrict__ cursor,
                          int* __restrict__ csr_src, int* __restrict__ csr_dst)
{
  const int e = blockIdx.x * 256 + threadIdx.x;
  if (e >= ET) return;
  const int sx = (e < NE) ? ei[e]      : (e - NE);
  const int d  = (e < NE) ? ei[NE + e] : (e - NE);
  const int pos = atomicAdd(&cursor[d], 1);
  csr_src[pos] = sx;
  csr_dst[pos] = d;
}

// ---------------------------------------------------------------- GATv2 fused attention
// One wave per node. Single pass over the node's edges: read xl[src] row once
// (3 bf16x8/lane), compute logit (shuffle reduce, wave-uniform), online-softmax
// rescale a 24-f32/lane accumulator. out[i] = relu(acc/z + ob).
__global__ __launch_bounds__(256)
void gat_fused(const uint16_t* __restrict__ xlr, int ld,
               const int* __restrict__ csr_src, const int* __restrict__ row_start,
               const float* __restrict__ att, const float* __restrict__ ob,
               uint16_t* __restrict__ out, int ldc)
{
  const int node = (blockIdx.x << 2) + (threadIdx.x >> 6);
  const int lane = threadIdx.x & 63;

  float av[3][8], xr[3][8];
  const bf16x8* pr = (const bf16x8*)(xlr + (size_t)node * ld + 1536);
#pragma unroll
  for (int h = 0; h < 3; ++h) {
    const float4 a0 = *(const float4*)(att + h * 512 + lane * 8);
    const float4 a1 = *(const float4*)(att + h * 512 + lane * 8 + 4);
    av[h][0] = a0.x; av[h][1] = a0.y; av[h][2] = a0.z; av[h][3] = a0.w;
    av[h][4] = a1.x; av[h][5] = a1.y; av[h][6] = a1.z; av[h][7] = a1.w;
    const bf16x8 v = pr[h * 64 + lane];
#pragma unroll
    for (int j = 0; j < 8; ++j) xr[h][j] = bf2f((uint16_t)v[j]);
  }

  float m[3] = {-1e30f, -1e30f, -1e30f};
  float z[3] = {0.f, 0.f, 0.f};
  float acc[3][8];
#pragma unroll
  for (int h = 0; h < 3; ++h)
#pragma unroll
    for (int j = 0; j < 8; ++j) acc[h][j] = 0.f;

  const int s0 = row_start[node], s1 = row_start[node + 1];
  for (int s = s0; s < s1; ++s) {
    const bf16x8* pl = (const bf16x8*)(xlr + (size_t)csr_src[s] * ld);
    bf16x8 vl[3];
#pragma unroll
    for (int h = 0; h < 3; ++h) vl[h] = pl[h * 64 + lane];

    float hacc[3];
#pragma unroll
    for (int h = 0; h < 3; ++h) {
      float sacc = 0.f;
#pragma unroll
      for (int j = 0; j < 8; ++j) {
        float v = bf2f((uint16_t)vl[h][j]) + xr[h][j];
        v = v > 0.f ? v : 0.2f * v;
        sacc += v * av[h][j];
      }
      hacc[h] = sacc;
    }
#pragma unroll
    for (int o = 32; o; o >>= 1) {
      hacc[0] += __shfl_xor(hacc[0], o);
      hacc[1] += __shfl_xor(hacc[1], o);
      hacc[2] += __shfl_xor(hacc[2], o);
    }
    // online softmax update (wave-uniform scale/p)
#pragma unroll
    for (int h = 0; h < 3; ++h) {
      const float nm = fmaxf(m[h], hacc[h]);
      const float sc = __expf(m[h] - nm);
      const float p  = __expf(hacc[h] - nm);
      z[h] = z[h] * sc + p;
#pragma unroll
      for (int j = 0; j < 8; ++j)
        acc[h][j] = acc[h][j] * sc + p * bf2f((uint16_t)vl[h][j]);
      m[h] = nm;
    }
  }

#pragma unroll
  for (int h = 0; h < 3; ++h) {
    const float rz = 1.f / z[h];
    const float4 b0 = *(const float4*)(ob + h * 512 + lane * 8);
    const float4 b1 = *(const float4*)(ob + h * 512 + lane * 8 + 4);
    float bv[8] = {b0.x, b0.y, b0.z, b0.w, b1.x, b1.y, b1.z, b1.w};
    bf16x8 pk;
#pragma unroll
    for (int j = 0; j < 8; ++j) {
      const float v = fmaxf(acc[h][j] * rz + bv[j], 0.f);
      pk[j] = (short)f2bf(v);
    }
    *(bf16x8*)(out + (size_t)node * ldc + h * 512 + lane * 8) = pk;
  }
}

// ---------------------------------------------------------------- final dot
__global__ __launch_bounds__(256)
void final_dot(const uint16_t* __restrict__ z2, const float* __restrict__ w,
               const float* __restrict__ b, float* __restrict__ out)
{
  const int row  = blockIdx.x * 4 + (threadIdx.x >> 6);
  const int lane = threadIdx.x & 63;
  const uint16_t* p = z2 + (size_t)row * 512;
  float s = 0.f;
#pragma unroll
  for (int j = 0; j < 8; ++j) { const int c = lane + j * 64; s += bf2f(p[c]) * w[c]; }
#pragma unroll
  for (int o = 32; o; o >>= 1) s += __shfl_xor(s, o);
  if (lane == 0) out[row] = s + b[0];
}

// ---------------------------------------------------------------- orchestration
extern "C" void kernel_launch(void* const* d_in, const int* in_sizes, int n_in,
                              void* d_out, int out_size, void* d_ws, size_t ws_size,
                              hipStream_t stream)
{
  (void)in_sizes; (void)n_in; (void)out_size; (void)ws_size;

  const float* x    = (const float*)d_in[0];
  const int*   ei   = (const int*)  d_in[1];
  const float* expm = (const float*)d_in[2];
  const float* w1l = (const float*)d_in[3];  const float* b1l = (const float*)d_in[4];
  const float* w1r = (const float*)d_in[5];  const float* b1r = (const float*)d_in[6];
  const float* a1  = (const float*)d_in[7];  const float* o1  = (const float*)d_in[8];
  const float* w2l = (const float*)d_in[9];  const float* b2l = (const float*)d_in[10];
  const float* w2r = (const float*)d_in[11]; const float* b2r = (const float*)d_in[12];
  const float* a2  = (const float*)d_in[13]; const float* o2  = (const float*)d_in[14];
  const float* w3l = (const float*)d_in[15]; const float* b3l = (const float*)d_in[16];
  const float* w3r = (const float*)d_in[17]; const float* b3r = (const float*)d_in[18];
  const float* a3  = (const float*)d_in[19]; const float* o3  = (const float*)d_in[20];
  const float* e1w = (const float*)d_in[21]; const float* e1b = (const float*)d_in[22];
  const float* e2w = (const float*)d_in[23]; const float* e2b = (const float*)d_in[24];
  const float* e3w = (const float*)d_in[25]; const float* e3b = (const float*)d_in[26];
  const float* l1w = (const float*)d_in[27]; const float* l1b = (const float*)d_in[28];
  const float* l2w = (const float*)d_in[29]; const float* l2b = (const float*)d_in[30];
  const float* l3w = (const float*)d_in[31]; const float* l3b = (const float*)d_in[32];
  float* out = (float*)d_out;

  hipFuncSetAttribute((const void*)gemm256, hipFuncAttributeMaxDynamicSharedMemorySize, 131072);

  char* ws = (char*)d_ws;
  size_t off = 0;
  auto take = [&](size_t b) { char* p = ws + off; off += (b + 255) & ~(size_t)255; return p; };

  int*      counts    = (int*)take((size_t)NN * 4);
  int*      row_start = (int*)take((size_t)(NN + 1) * 4);
  int*      cursor    = (int*)take((size_t)NN * 4);
  int*      csr_src   = (int*)take((size_t)ET * 4);
  int*      csr_dst   = (int*)take((size_t)ET * 4);
  float*    bc1       = (float*)take(3072 * 4);
  float*    bc2       = (float*)take(3072 * 4);
  float*    bc3       = (float*)take(3072 * 4);
  uint16_t* zbuf      = (uint16_t*)take((size_t)NN * 2048 * 2);
  char*     regA      = take((size_t)NN * F_EXP_P * 2);
  char*     regW      = take((size_t)4096 * F_EXP_P * 2);
  char*     regC      = take((size_t)NN * 4096 * 2 + (size_t)NN * 1536 * 2);

  uint16_t* xbf   = (uint16_t*)regA;
  uint16_t* expbf = (uint16_t*)regA;
  uint16_t* wT    = (uint16_t*)regW;
  // phase 1: xlr [8192][3072] + hbuf [8192][1536]
  uint16_t* xlr   = (uint16_t*)regC;
  uint16_t* hbuf  = (uint16_t*)(regC + (size_t)NN * 3072 * 2);
  // phase 2 (encoder): cell1 [8192][4096] | cell2 [8192][1536]
  uint16_t* cell1 = (uint16_t*)regC;
  uint16_t* cell2 = (uint16_t*)(regC + (size_t)NN * 4096 * 2);
  // phase 3 (head): zz1 [8192][1024] | zz2 [8192][512]
  uint16_t* zz1   = (uint16_t*)regC;
  uint16_t* zz2   = (uint16_t*)(regC + (size_t)NN * 1024 * 2);

  // ---- CSR + fused biases
  hipMemsetAsync(counts, 0, (size_t)NN * 4, stream);
  count_deg<<<(ET + 255) / 256, 256, 0, stream>>>(ei, counts);
  scan_deg<<<1, 1024, 0, stream>>>(counts, row_start, cursor);
  scatter_e<<<(ET + 255) / 256, 256, 0, stream>>>(ei, cursor, csr_src, csr_dst);
  concat_bias<<<12, 256, 0, stream>>>(b1l, b1r, bc1);
  concat_bias<<<12, 256, 0, stream>>>(b2l, b2r, bc2);
  concat_bias<<<12, 256, 0, stream>>>(b3l, b3r, bc3);

  // ---- GAT layer 1 (Kp = 3264), fused l|r GEMM -> xlr
  cvt_pad<<<dim3((F_IN_P / 2 + 255) / 256, NN), 256, 0, stream>>>(x, xbf, F_IN, F_IN_P);
  transpose_w<<<dim3(F_IN_P / 32, 1536 / 32), dim3(32, 8), 0, stream>>>(w1l, wT, F_IN, 1536, F_IN_P, 1536);
  transpose_w<<<dim3(F_IN_P / 32, 1536 / 32), dim3(32, 8), 0, stream>>>(w1r, wT + (size_t)1536 * F_IN_P, F_IN, 1536, F_IN_P, 1536);
  gemm256<<<32 * 12, 512, 131072, stream>>>(xbf, wT, bc1, 3072, 0, xlr, F_IN_P, 3072, 12);
  gat_fused<<<NN / 4, 256, 0, stream>>>(xlr, 3072, csr_src, row_start, a1, o1, hbuf, 1536);

  // ---- GAT layer 2 (K = 1536)
  transpose_w<<<dim3(48, 48), dim3(32, 8), 0, stream>>>(w2l, wT, 1536, 1536, 1536, 1536);
  transpose_w<<<dim3(48, 48), dim3(32, 8), 0, stream>>>(w2r, wT + (size_t)1536 * 1536, 1536, 1536, 1536, 1536);
  gemm256<<<32 * 12, 512, 131072, stream>>>(hbuf, wT, bc2, 3072, 0, xlr, 1536, 3072, 12);
  gat_fused<<<NN / 4, 256, 0, stream>>>(xlr, 3072, csr_src, row_start, a2, o2, hbuf, 1536);

  // ---- GAT layer 3 -> zbuf cols [0,1536)
  transpose_w<<<dim3(48, 48), dim3(32, 8), 0, stream>>>(w3l, wT, 1536, 1536, 1536, 1536);
  transpose_w<<<dim3(48, 48), dim3(32, 8), 0, stream>>>(w3r, wT + (size_t)1536 * 1536, 1536, 1536, 1536, 1536);
  gemm256<<<32 * 12, 512, 131072, stream>>>(hbuf, wT, bc3, 3072, 0, xlr, 1536, 3072, 12);
  gat_fused<<<NN / 4, 256, 0, stream>>>(xlr, 3072, csr_src, row_start, a3, o3, zbuf, 2048);

  // ---- encoder: 7993 -> 4000 -> 1500 -> 512 (last into zbuf cols [1536,2048))
  cvt_pad<<<dim3((F_EXP_P / 2 + 255) / 256, NN), 256, 0, stream>>>(expm, expbf, F_EXP, F_EXP_P);
  transpose_w<<<dim3(F_EXP_P / 32, 4096 / 32), dim3(32, 8), 0, stream>>>(e1w, wT, F_EXP, 4000, F_EXP_P, 4096);
  gemm256<<<32 * 16, 512, 131072, stream>>>(expbf, wT, e1b, 4000, 1, cell1, F_EXP_P, 4096, 16);
  transpose_w<<<dim3(4096 / 32, 1536 / 32), dim3(32, 8), 0, stream>>>(e2w, wT, 4000, 1500, 4096, 1536);
  gemm256<<<32 * 6, 512, 131072, stream>>>(cell1, wT, e2b, 1500, 1, cell2, 4096, 1536, 6);
  transpose_w<<<dim3(1536 / 32, 512 / 32), dim3(32, 8), 0, stream>>>(e3w, wT, 1500, 512, 1536, 512);
  gemm_bt<<<dim3(64, 4), 256, 0, stream>>>(cell2, wT, e3b, 512, 0, zbuf + 1536, 1536, 2048);

  // ---- head
  transpose_w<<<dim3(2048 / 32, 1024 / 32), dim3(32, 8), 0, stream>>>(l1w, wT, 2048, 1024, 2048, 1024);
  gemm_bt<<<dim3(64, 8), 256, 0, stream>>>(zbuf, wT, l1b, 1024, 1, zz1, 2048, 1024);
  transpose_w<<<dim3(1024 / 32, 512 / 32), dim3(32, 8), 0, stream>>>(l2w, wT, 1024, 512, 1024, 512);
  gemm_bt<<<dim3(64, 4), 256, 0, stream>>>(zz1, wT, l2b, 512, 1, zz2, 1024, 512);
  final_dot<<<NN / 4, 256, 0, stream>>>(zz2, l3w, l3b, out);
}

// Round 11
// 1466.422 us; speedup vs baseline: 1.1585x; 1.1585x over previous
//
#include <hip/hip_runtime.h>
#include <stdint.h>

#define NN 8192
#define NE 65536
#define ET (NE + NN)
#define F_IN   3247
#define F_IN_P 3264
#define F_EXP   7993
#define F_EXP_P 8000

typedef __attribute__((ext_vector_type(8))) short bf16x8;
typedef __attribute__((ext_vector_type(4))) float f32x4;

typedef const __attribute__((address_space(1))) void gvoid_t;
typedef __attribute__((address_space(3))) void lvoid_t;

__device__ __forceinline__ float bf2f(uint16_t u) {
  union { uint32_t i; float f; } v; v.i = ((uint32_t)u) << 16; return v.f;
}
__device__ __forceinline__ uint16_t f2bf(float f) {
  union { float f; uint32_t i; } v; v.f = f;
  uint32_t r = v.i + 0x7fffu + ((v.i >> 16) & 1u);  // RNE
  return (uint16_t)(r >> 16);
}

__device__ __forceinline__ void gld_lds16(const void* g, void* l) {
  __builtin_amdgcn_global_load_lds((gvoid_t*)g, (lvoid_t*)l, 16, 0, 0);
}

#define SBAR() __builtin_amdgcn_sched_barrier(0)
#define BARRIER() do { SBAR(); __builtin_amdgcn_s_barrier(); SBAR(); } while (0)
#define VMCNT(n) asm volatile("s_waitcnt vmcnt(" #n ")" ::: "memory")
#define MFMA16(a, b, c) __builtin_amdgcn_mfma_f32_16x16x32_bf16(a, b, c, 0, 0, 0)

// =================================================================== gemm256
// 256x256 tile, BK=64, 8 waves (2M x 4N). 4 phases/K-tile, 1 barrier/phase.
// Low-pressure lookahead (peak 20 frag groups), b01 re-read, T2 swizzle,
// counted vmcnt, setprio. K-loop manually doubled => compile-time LDS bases.
// R8 schedule (verified best): A(T+2) staged as burst in P2, B(T+2) in P3 —
// 2-tile prefetch distance. R10's distance-1 redistribution regressed 27%.
__device__ __forceinline__ void stage4(const char* src, char* dst, size_t Kb) {
#pragma unroll
  for (int j = 0; j < 4; ++j)
    gld_lds16(src + (size_t)(j * 64) * Kb, dst + j * 8192);
}

// One K-tile: T = tile index, BUF = compile-time LDS buffer offset (0 or 32768)
#define KTILE(T, BUF)                                                          \
  do {                                                                         \
    const char* aB_  = smem + (BUF) + arow;                                    \
    const char* bB_  = smem + 65536 + (BUF) + brow_o;                          \
    const char* aBn_ = smem + ((BUF) ^ 32768) + arow;                          \
    const bool nls = ((T) + 2 < nk);                                           \
    const bool nlr = ((T) + 1 < nk);                                           \
    /* P0: guard B(T); read b01,b23; MFMA Q0 (a03 x b01) */                    \
    if (nlr) { VMCNT(8); } else { VMCNT(0); }                                  \
    _Pragma("unroll")                                                          \
    for (int n = 0; n < 2; ++n) {                                              \
      b01[n * 2]     = *(const bf16x8*)(bB_ + n * 2048 + sw0);                 \
      b01[n * 2 + 1] = *(const bf16x8*)(bB_ + n * 2048 + sw1);                 \
    }                                                                          \
    _Pragma("unroll")                                                          \
    for (int n = 0; n < 2; ++n) {                                              \
      b23[n * 2]     = *(const bf16x8*)(bB_ + (n + 2) * 2048 + sw0);           \
      b23[n * 2 + 1] = *(const bf16x8*)(bB_ + (n + 2) * 2048 + sw1);           \
    }                                                                          \
    SBAR();                                                                    \
    __builtin_amdgcn_s_setprio(1);                                             \
    _Pragma("unroll")                                                          \
    for (int m = 0; m < 4; ++m)                                                \
      _Pragma("unroll")                                                        \
      for (int n = 0; n < 2; ++n) {                                            \
        acc[m][n] = MFMA16(a03[m * 2],     b01[n * 2],     acc[m][n]);         \
        acc[m][n] = MFMA16(a03[m * 2 + 1], b01[n * 2 + 1], acc[m][n]);         \
      }                                                                        \
    __builtin_amdgcn_s_setprio(0);                                             \
    BARRIER();                                                                 \
    /* P1: read a47; MFMA Q1 (a03 x b23) */                                    \
    _Pragma("unroll")                                                          \
    for (int m = 0; m < 4; ++m) {                                              \
      a47[m * 2]     = *(const bf16x8*)(aB_ + (m + 4) * 2048 + sw0);           \
      a47[m * 2 + 1] = *(const bf16x8*)(aB_ + (m + 4) * 2048 + sw1);           \
    }                                                                          \
    SBAR();                                                                    \
    __builtin_amdgcn_s_setprio(1);                                             \
    _Pragma("unroll")                                                          \
    for (int m = 0; m < 4; ++m)                                                \
      _Pragma("unroll")                                                        \
      for (int n = 0; n < 2; ++n) {                                            \
        acc[m][n + 2] = MFMA16(a03[m * 2],     b23[n * 2],     acc[m][n + 2]); \
        acc[m][n + 2] = MFMA16(a03[m * 2 + 1], b23[n * 2 + 1], acc[m][n + 2]); \
      }                                                                        \
    __builtin_amdgcn_s_setprio(0);                                             \
    BARRIER();                                                                 \
    /* P2: stage A(T+2); re-read b01; MFMA Q2 (a47 x b23) */                   \
    if (nls) stage4(pA + (size_t)((T) + 2) * 128, sA + (BUF), Kb);             \
    _Pragma("unroll")                                                          \
    for (int n = 0; n < 2; ++n) {                                              \
      b01[n * 2]     = *(const bf16x8*)(bB_ + n * 2048 + sw0);                 \
      b01[n * 2 + 1] = *(const bf16x8*)(bB_ + n * 2048 + sw1);                 \
    }                                                                          \
    SBAR();                                                                    \
    __builtin_amdgcn_s_setprio(1);                                             \
    _Pragma("unroll")                                                          \
    for (int m = 0; m < 4; ++m)                                                \
      _Pragma("unroll")                                                        \
      for (int n = 0; n < 2; ++n) {                                            \
        acc[m + 4][n + 2] = MFMA16(a47[m * 2],     b23[n * 2],     acc[m + 4][n + 2]); \
        acc[m + 4][n + 2] = MFMA16(a47[m * 2 + 1], b23[n * 2 + 1], acc[m + 4][n + 2]); \
      }                                                                        \
    __builtin_amdgcn_s_setprio(0);                                             \
    BARRIER();                                                                 \
    /* P3: guard A(T+1); read a03(T+1); stage B(T+2); MFMA Q3 (a47 x b01) */   \
    if (nls)      { VMCNT(10); }                                               \
    else if (nlr) { VMCNT(4); }                                                \
    if (nlr) {                                                                 \
      _Pragma("unroll")                                                        \
      for (int m = 0; m < 4; ++m) {                                            \
        a03[m * 2]     = *(const bf16x8*)(aBn_ + m * 2048 + sw0);              \
        a03[m * 2 + 1] = *(const bf16x8*)(aBn_ + m * 2048 + sw1);              \
      }                                                                        \
    }                                                                          \
    if (nls) stage4(pB + (size_t)((T) + 2) * 128, sB + (BUF), Kb);             \
    SBAR();                                                                    \
    __builtin_amdgcn_s_setprio(1);                                             \
    _Pragma("unroll")                                                          \
    for (int m = 0; m < 4; ++m)                                                \
      _Pragma("unroll")                                                        \
      for (int n = 0; n < 2; ++n) {                                            \
        acc[m + 4][n] = MFMA16(a47[m * 2],     b01[n * 2],     acc[m + 4][n]); \
        acc[m + 4][n] = MFMA16(a47[m * 2 + 1], b01[n * 2 + 1], acc[m + 4][n]); \
      }                                                                        \
    __builtin_amdgcn_s_setprio(0);                                             \
    BARRIER();                                                                 \
  } while (0)

__global__ __launch_bounds__(512, 2)
void gemm256(const uint16_t* __restrict__ A, const uint16_t* __restrict__ Bt,
             const float* __restrict__ bias, int biasN, int relu,
             uint16_t* __restrict__ C, int Kp, int ldc, int nbn)
{
  extern __shared__ char smem[];   // [A: 2buf x 4 x 64rows x 128B = 64K][B: same]
  const int tid = threadIdx.x;
  const int w = tid >> 6, lane = tid & 63;
  const int wr = w >> 2, wc = w & 3;
  const int fr = lane & 15, g = lane >> 4;

  // T1: bijective XCD swizzle
  const int nwg = (int)gridDim.x;
  const int id = (int)blockIdx.x;
  const int q = nwg >> 3, r = nwg & 7;
  const int xcd = id & 7, idx = id >> 3;
  const int wg = (xcd < r ? xcd * (q + 1) : r * (q + 1) + (xcd - r) * q) + idx;
  const int brow = (wg / nbn) * 256, bcol = (wg % nbn) * 256;

  const size_t Kb = (size_t)Kp * 2;

  // staging: thread tid -> LDS j*8192 + (tid>>3)*128 + (tid&7)*16 (lane*16 by HW)
  const int srow = tid >> 3;
  const int sswz = ((tid & 7) ^ (srow & 7)) * 16;
  const char* pA = (const char*)A + (size_t)(brow + srow) * Kb + sswz;
  const char* pB = (const char*)Bt + (size_t)(bcol + srow) * Kb + sswz;
  char* sA = smem + w * 1024;
  char* sB = smem + 65536 + w * 1024;

  // frag read: slot q=kk*4+g stored at q ^ (row&7), row&7 == fr&7
  const int sw0 = (g ^ (fr & 7)) * 16;
  const int sw1 = ((g + 4) ^ (fr & 7)) * 16;
  const int arow = (wr * 128 + fr) * 128;   // + m*2048
  const int brow_o = (wc * 64 + fr) * 128;  // + n*2048

  f32x4 acc[8][4];
#pragma unroll
  for (int m = 0; m < 8; ++m)
#pragma unroll
    for (int n = 0; n < 4; ++n) acc[m][n] = (f32x4){0.f, 0.f, 0.f, 0.f};
  bf16x8 a03[8], a47[8], b01[4], b23[4];

  // prologue: stage tiles 0,1; wait tile0; preload a03(0)
  stage4(pA, sA, Kb);
  stage4(pB, sB, Kb);
  stage4(pA + 128, sA + 32768, Kb);
  stage4(pB + 128, sB + 32768, Kb);
  VMCNT(8);
  BARRIER();
  {
    const char* aB = smem + arow;
#pragma unroll
    for (int m = 0; m < 4; ++m) {
      a03[m * 2]     = *(const bf16x8*)(aB + m * 2048 + sw0);
      a03[m * 2 + 1] = *(const bf16x8*)(aB + m * 2048 + sw1);
    }
  }
  SBAR();

  const int nk = Kp >> 6;
  for (int t = 0; t < nk; t += 2) {
    KTILE(t, 0);
    if (t + 1 < nk) KTILE(t + 1, 32768);
  }

  // epilogue: C/D layout col=lane&15, row=(lane>>4)*4+j
#pragma unroll
  for (int m = 0; m < 8; ++m) {
    const int row = brow + wr * 128 + m * 16 + g * 4;
#pragma unroll
    for (int n = 0; n < 4; ++n) {
      const int col = bcol + wc * 64 + n * 16 + fr;
      const float bv = (col < biasN) ? bias[col] : 0.f;
#pragma unroll
      for (int j = 0; j < 4; ++j) {
        float v = acc[m][n][j] + bv;
        if (relu) v = fmaxf(v, 0.f);
        C[(size_t)(row + j) * ldc + col] = f2bf(v);
      }
    }
  }
}

// ---------------------------------------------------------------- GEMM (m97 structure, small N)
__global__ __launch_bounds__(256)
void gemm_bt(const uint16_t* __restrict__ A, const uint16_t* __restrict__ Bt,
             const float* __restrict__ bias, int biasN, int relu,
             uint16_t* __restrict__ C, int Kp, int ldc)
{
  __shared__ uint16_t As[128 * 32];
  __shared__ uint16_t Bs[128 * 32];
  const int tid  = threadIdx.x;
  const int wave = tid >> 6, lane = tid & 63;
  const int brow = blockIdx.x * 128, bcol = blockIdx.y * 128;
  const int wr = wave >> 1, wc = wave & 1;
  const int fr = lane & 15, g = lane >> 4;

  f32x4 acc[4][4];
#pragma unroll
  for (int m = 0; m < 4; ++m)
#pragma unroll
    for (int n = 0; n < 4; ++n) acc[m][n] = (f32x4){0.f, 0.f, 0.f, 0.f};

  const int rA = tid >> 2;
  const int kc = (tid & 3) * 8;
  const uint16_t* aptr = A  + (size_t)(brow + rA) * Kp + kc;
  const uint16_t* bptr = Bt + (size_t)(bcol + rA) * Kp + kc;
  char* ldsA = (char*)As + wave * 1024;
  char* ldsB = (char*)Bs + wave * 1024;
  const size_t rowskip = (size_t)64 * Kp;

  const int nk = Kp >> 5;
  for (int kt = 0; kt < nk; ++kt) {
    __syncthreads();
    gld_lds16(aptr,           ldsA);
    gld_lds16(aptr + rowskip, ldsA + 4096);
    gld_lds16(bptr,           ldsB);
    gld_lds16(bptr + rowskip, ldsB + 4096);
    aptr += 32; bptr += 32;
    __syncthreads();

    bf16x8 af[4], bfr[4];
#pragma unroll
    for (int m = 0; m < 4; ++m)
      af[m] = *(const bf16x8*)&As[(wr * 64 + m * 16 + fr) * 32 + g * 8];
#pragma unroll
    for (int n = 0; n < 4; ++n)
      bfr[n] = *(const bf16x8*)&Bs[(wc * 64 + n * 16 + fr) * 32 + g * 8];
#pragma unroll
    for (int m = 0; m < 4; ++m)
#pragma unroll
      for (int n = 0; n < 4; ++n)
        acc[m][n] = MFMA16(af[m], bfr[n], acc[m][n]);
  }

#pragma unroll
  for (int m = 0; m < 4; ++m) {
    const int row = brow + wr * 64 + m * 16 + g * 4;
#pragma unroll
    for (int n = 0; n < 4; ++n) {
      const int col = bcol + wc * 64 + n * 16 + fr;
      const float bv = (col < biasN) ? bias[col] : 0.f;
#pragma unroll
      for (int j = 0; j < 4; ++j) {
        float v = acc[m][n][j] + bv;
        if (relu) v = fmaxf(v, 0.f);
        C[(size_t)(row + j) * ldc + col] = f2bf(v);
      }
    }
  }
}

// ---------------------------------------------------------------- conversions
__global__ __launch_bounds__(256)
void cvt_pad(const float* __restrict__ in, uint16_t* __restrict__ out, int cols, int colsPad)
{
  const int r = blockIdx.y;
  const int c = (blockIdx.x * 256 + threadIdx.x) * 2;
  if (c >= colsPad) return;
  const float* ip = in + (size_t)r * cols;
  const float v0 = (c < cols)     ? ip[c]     : 0.f;
  const float v1 = (c + 1 < cols) ? ip[c + 1] : 0.f;
  const uint32_t pk = (uint32_t)f2bf(v0) | ((uint32_t)f2bf(v1) << 16);
  *(uint32_t*)(out + (size_t)r * colsPad + c) = pk;
}

__global__ __launch_bounds__(256)
void transpose_w(const float* __restrict__ W, uint16_t* __restrict__ Wt,
                 int K, int N, int Kp, int Np)
{
  __shared__ float t[32][33];
  const int tx = threadIdx.x, ty = threadIdx.y;
  const int k0 = blockIdx.x * 32, n0 = blockIdx.y * 32;
#pragma unroll
  for (int j = 0; j < 4; ++j) {
    const int k = k0 + ty + j * 8, n = n0 + tx;
    t[ty + j * 8][tx] = (k < K && n < N) ? W[(size_t)k * N + n] : 0.f;
  }
  __syncthreads();
#pragma unroll
  for (int j = 0; j < 4; ++j) {
    const int n = n0 + ty + j * 8, k = k0 + tx;
    Wt[(size_t)n * Kp + k] = f2bf(t[tx][ty + j * 8]);
  }
}

__global__ void concat_bias(const float* __restrict__ bl, const float* __restrict__ br,
                            float* __restrict__ out)
{
  const int i = blockIdx.x * 256 + threadIdx.x;
  if (i < 1536) out[i] = bl[i];
  else if (i < 3072) out[i] = br[i - 1536];
}

// ---------------------------------------------------------------- CSR build
__global__ void count_deg(const int* __restrict__ ei, int* __restrict__ counts)
{
  const int e = blockIdx.x * 256 + threadIdx.x;
  if (e >= ET) return;
  const int d = (e < NE) ? ei[NE + e] : (e - NE);
  atomicAdd(&counts[d], 1);
}

__global__ __launch_bounds__(1024)
void scan_deg(const int* __restrict__ counts, int* __restrict__ row_start, int* __restrict__ cursor)
{
  __shared__ int part[1024];
  const int tid = threadIdx.x;
  int loc[8], pre[8], s = 0;
#pragma unroll
  for (int j = 0; j < 8; ++j) { loc[j] = counts[tid * 8 + j]; pre[j] = s; s += loc[j]; }
  part[tid] = s;
  __syncthreads();
  for (int o = 1; o < 1024; o <<= 1) {
    const int v = part[tid];
    const int a = (tid >= o) ? part[tid - o] : 0;
    __syncthreads();
    part[tid] = v + a;
    __syncthreads();
  }
  const int excl = part[tid] - s;
#pragma unroll
  for (int j = 0; j < 8; ++j) {
    const int v = excl + pre[j];
    row_start[tid * 8 + j] = v;
    cursor[tid * 8 + j]    = v;
  }
  if (tid == 1023) row_start[8192] = excl + s;
}

__global__ void scatter_e(const int* __restrict__ ei, int* __restrict__ cursor,
                          int* __restrict__ csr_src, int* __restrict__ csr_dst)
{
  const int e = blockIdx.x * 256 + threadIdx.x;
  if (e >= ET) return;
  const int sx = (e < NE) ? ei[e]      : (e - NE);
  const int d  = (e < NE) ? ei[NE + e] : (e - NE);
  const int pos = atomicAdd(&cursor[d], 1);
  csr_src[pos] = sx;
  csr_dst[pos] = d;
}

// ---------------------------------------------------------------- GATv2 fused attention
// One wave per node. Single pass over the node's edges: read xl[src] row once
// (3 bf16x8/lane), compute logit (shuffle reduce, wave-uniform), online-softmax
// rescale a 24-f32/lane accumulator. out[i] = relu(acc/z + ob).
__global__ __launch_bounds__(256)
void gat_fused(const uint16_t* __restrict__ xlr, int ld,
               const int* __restrict__ csr_src, const int* __restrict__ row_start,
               const float* __restrict__ att, const float* __restrict__ ob,
               uint16_t* __restrict__ out, int ldc)
{
  const int node = (blockIdx.x << 2) + (threadIdx.x >> 6);
  const int lane = threadIdx.x & 63;

  float av[3][8], xr[3][8];
  const bf16x8* pr = (const bf16x8*)(xlr + (size_t)node * ld + 1536);
#pragma unroll
  for (int h = 0; h < 3; ++h) {
    const float4 a0 = *(const float4*)(att + h * 512 + lane * 8);
    const float4 a1 = *(const float4*)(att + h * 512 + lane * 8 + 4);
    av[h][0] = a0.x; av[h][1] = a0.y; av[h][2] = a0.z; av[h][3] = a0.w;
    av[h][4] = a1.x; av[h][5] = a1.y; av[h][6] = a1.z; av[h][7] = a1.w;
    const bf16x8 v = pr[h * 64 + lane];
#pragma unroll
    for (int j = 0; j < 8; ++j) xr[h][j] = bf2f((uint16_t)v[j]);
  }

  float m[3] = {-1e30f, -1e30f, -1e30f};
  float z[3] = {0.f, 0.f, 0.f};
  float acc[3][8];
#pragma unroll
  for (int h = 0; h < 3; ++h)
#pragma unroll
    for (int j = 0; j < 8; ++j) acc[h][j] = 0.f;

  const int s0 = row_start[node], s1 = row_start[node + 1];
  for (int s = s0; s < s1; ++s) {
    const bf16x8* pl = (const bf16x8*)(xlr + (size_t)csr_src[s] * ld);
    bf16x8 vl[3];
#pragma unroll
    for (int h = 0; h < 3; ++h) vl[h] = pl[h * 64 + lane];

    float hacc[3];
#pragma unroll
    for (int h = 0; h < 3; ++h) {
      float sacc = 0.f;
#pragma unroll
      for (int j = 0; j < 8; ++j) {
        float v = bf2f((uint16_t)vl[h][j]) + xr[h][j];
        v = v > 0.f ? v : 0.2f * v;
        sacc += v * av[h][j];
      }
      hacc[h] = sacc;
    }
#pragma unroll
    for (int o = 32; o; o >>= 1) {
      hacc[0] += __shfl_xor(hacc[0], o);
      hacc[1] += __shfl_xor(hacc[1], o);
      hacc[2] += __shfl_xor(hacc[2], o);
    }
    // online softmax update (wave-uniform scale/p)
#pragma unroll
    for (int h = 0; h < 3; ++h) {
      const float nm = fmaxf(m[h], hacc[h]);
      const float sc = __expf(m[h] - nm);
      const float p  = __expf(hacc[h] - nm);
      z[h] = z[h] * sc + p;
#pragma unroll
      for (int j = 0; j < 8; ++j)
        acc[h][j] = acc[h][j] * sc + p * bf2f((uint16_t)vl[h][j]);
      m[h] = nm;
    }
  }

#pragma unroll
  for (int h = 0; h < 3; ++h) {
    const float rz = 1.f / z[h];
    const float4 b0 = *(const float4*)(ob + h * 512 + lane * 8);
    const float4 b1 = *(const float4*)(ob + h * 512 + lane * 8 + 4);
    float bv[8] = {b0.x, b0.y, b0.z, b0.w, b1.x, b1.y, b1.z, b1.w};
    bf16x8 pk;
#pragma unroll
    for (int j = 0; j < 8; ++j) {
      const float v = fmaxf(acc[h][j] * rz + bv[j], 0.f);
      pk[j] = (short)f2bf(v);
    }
    *(bf16x8*)(out + (size_t)node * ldc + h * 512 + lane * 8) = pk;
  }
}

// ---------------------------------------------------------------- final dot
__global__ __launch_bounds__(256)
void final_dot(const uint16_t* __restrict__ z2, const float* __restrict__ w,
               const float* __restrict__ b, float* __restrict__ out)
{
  const int row  = blockIdx.x * 4 + (threadIdx.x >> 6);
  const int lane = threadIdx.x & 63;
  const uint16_t* p = z2 + (size_t)row * 512;
  float s = 0.f;
#pragma unroll
  for (int j = 0; j < 8; ++j) { const int c = lane + j * 64; s += bf2f(p[c]) * w[c]; }
#pragma unroll
  for (int o = 32; o; o >>= 1) s += __shfl_xor(s, o);
  if (lane == 0) out[row] = s + b[0];
}

// ---------------------------------------------------------------- orchestration
extern "C" void kernel_launch(void* const* d_in, const int* in_sizes, int n_in,
                              void* d_out, int out_size, void* d_ws, size_t ws_size,
                              hipStream_t stream)
{
  (void)in_sizes; (void)n_in; (void)out_size; (void)ws_size;

  const float* x    = (const float*)d_in[0];
  const int*   ei   = (const int*)  d_in[1];
  const float* expm = (const float*)d_in[2];
  const float* w1l = (const float*)d_in[3];  const float* b1l = (const float*)d_in[4];
  const float* w1r = (const float*)d_in[5];  const float* b1r = (const float*)d_in[6];
  const float* a1  = (const float*)d_in[7];  const float* o1  = (const float*)d_in[8];
  const float* w2l = (const float*)d_in[9];  const float* b2l = (const float*)d_in[10];
  const float* w2r = (const float*)d_in[11]; const float* b2r = (const float*)d_in[12];
  const float* a2  = (const float*)d_in[13]; const float* o2  = (const float*)d_in[14];
  const float* w3l = (const float*)d_in[15]; const float* b3l = (const float*)d_in[16];
  const float* w3r = (const float*)d_in[17]; const float* b3r = (const float*)d_in[18];
  const float* a3  = (const float*)d_in[19]; const float* o3  = (const float*)d_in[20];
  const float* e1w = (const float*)d_in[21]; const float* e1b = (const float*)d_in[22];
  const float* e2w = (const float*)d_in[23]; const float* e2b = (const float*)d_in[24];
  const float* e3w = (const float*)d_in[25]; const float* e3b = (const float*)d_in[26];
  const float* l1w = (const float*)d_in[27]; const float* l1b = (const float*)d_in[28];
  const float* l2w = (const float*)d_in[29]; const float* l2b = (const float*)d_in[30];
  const float* l3w = (const float*)d_in[31]; const float* l3b = (const float*)d_in[32];
  float* out = (float*)d_out;

  hipFuncSetAttribute((const void*)gemm256, hipFuncAttributeMaxDynamicSharedMemorySize, 131072);

  char* ws = (char*)d_ws;
  size_t off = 0;
  auto take = [&](size_t b) { char* p = ws + off; off += (b + 255) & ~(size_t)255; return p; };

  int*      counts    = (int*)take((size_t)NN * 4);
  int*      row_start = (int*)take((size_t)(NN + 1) * 4);
  int*      cursor    = (int*)take((size_t)NN * 4);
  int*      csr_src   = (int*)take((size_t)ET * 4);
  int*      csr_dst   = (int*)take((size_t)ET * 4);
  float*    bc1       = (float*)take(3072 * 4);
  float*    bc2       = (float*)take(3072 * 4);
  float*    bc3       = (float*)take(3072 * 4);
  uint16_t* zbuf      = (uint16_t*)take((size_t)NN * 2048 * 2);
  char*     regA      = take((size_t)NN * F_EXP_P * 2);
  char*     regW      = take((size_t)4096 * F_EXP_P * 2);
  char*     regC      = take((size_t)NN * 4096 * 2 + (size_t)NN * 1536 * 2);

  uint16_t* xbf   = (uint16_t*)regA;
  uint16_t* expbf = (uint16_t*)regA;
  uint16_t* wT    = (uint16_t*)regW;
  // phase 1: xlr [8192][3072] + hbuf [8192][1536]
  uint16_t* xlr   = (uint16_t*)regC;
  uint16_t* hbuf  = (uint16_t*)(regC + (size_t)NN * 3072 * 2);
  // phase 2 (encoder): cell1 [8192][4096] | cell2 [8192][1536]
  uint16_t* cell1 = (uint16_t*)regC;
  uint16_t* cell2 = (uint16_t*)(regC + (size_t)NN * 4096 * 2);
  // phase 3 (head): zz1 [8192][1024] | zz2 [8192][512]
  uint16_t* zz1   = (uint16_t*)regC;
  uint16_t* zz2   = (uint16_t*)(regC + (size_t)NN * 1024 * 2);

  // ---- CSR + fused biases
  hipMemsetAsync(counts, 0, (size_t)NN * 4, stream);
  count_deg<<<(ET + 255) / 256, 256, 0, stream>>>(ei, counts);
  scan_deg<<<1, 1024, 0, stream>>>(counts, row_start, cursor);
  scatter_e<<<(ET + 255) / 256, 256, 0, stream>>>(ei, cursor, csr_src, csr_dst);
  concat_bias<<<12, 256, 0, stream>>>(b1l, b1r, bc1);
  concat_bias<<<12, 256, 0, stream>>>(b2l, b2r, bc2);
  concat_bias<<<12, 256, 0, stream>>>(b3l, b3r, bc3);

  // ---- GAT layer 1 (Kp = 3264), fused l|r GEMM -> xlr
  cvt_pad<<<dim3((F_IN_P / 2 + 255) / 256, NN), 256, 0, stream>>>(x, xbf, F_IN, F_IN_P);
  transpose_w<<<dim3(F_IN_P / 32, 1536 / 32), dim3(32, 8), 0, stream>>>(w1l, wT, F_IN, 1536, F_IN_P, 1536);
  transpose_w<<<dim3(F_IN_P / 32, 1536 / 32), dim3(32, 8), 0, stream>>>(w1r, wT + (size_t)1536 * F_IN_P, F_IN, 1536, F_IN_P, 1536);
  gemm256<<<32 * 12, 512, 131072, stream>>>(xbf, wT, bc1, 3072, 0, xlr, F_IN_P, 3072, 12);
  gat_fused<<<NN / 4, 256, 0, stream>>>(xlr, 3072, csr_src, row_start, a1, o1, hbuf, 1536);

  // ---- GAT layer 2 (K = 1536)
  transpose_w<<<dim3(48, 48), dim3(32, 8), 0, stream>>>(w2l, wT, 1536, 1536, 1536, 1536);
  transpose_w<<<dim3(48, 48), dim3(32, 8), 0, stream>>>(w2r, wT + (size_t)1536 * 1536, 1536, 1536, 1536, 1536);
  gemm256<<<32 * 12, 512, 131072, stream>>>(hbuf, wT, bc2, 3072, 0, xlr, 1536, 3072, 12);
  gat_fused<<<NN / 4, 256, 0, stream>>>(xlr, 3072, csr_src, row_start, a2, o2, hbuf, 1536);

  // ---- GAT layer 3 -> zbuf cols [0,1536)
  transpose_w<<<dim3(48, 48), dim3(32, 8), 0, stream>>>(w3l, wT, 1536, 1536, 1536, 1536);
  transpose_w<<<dim3(48, 48), dim3(32, 8), 0, stream>>>(w3r, wT + (size_t)1536 * 1536, 1536, 1536, 1536, 1536);
  gemm256<<<32 * 12, 512, 131072, stream>>>(hbuf, wT, bc3, 3072, 0, xlr, 1536, 3072, 12);
  gat_fused<<<NN / 4, 256, 0, stream>>>(xlr, 3072, csr_src, row_start, a3, o3, zbuf, 2048);

  // ---- encoder: 7993 -> 4000 -> 1500 -> 512 (last into zbuf cols [1536,2048))
  cvt_pad<<<dim3((F_EXP_P / 2 + 255) / 256, NN), 256, 0, stream>>>(expm, expbf, F_EXP, F_EXP_P);
  transpose_w<<<dim3(F_EXP_P / 32, 4096 / 32), dim3(32, 8), 0, stream>>>(e1w, wT, F_EXP, 4000, F_EXP_P, 4096);
  gemm256<<<32 * 16, 512, 131072, stream>>>(expbf, wT, e1b, 4000, 1, cell1, F_EXP_P, 4096, 16);
  transpose_w<<<dim3(4096 / 32, 1536 / 32), dim3(32, 8), 0, stream>>>(e2w, wT, 4000, 1500, 4096, 1536);
  gemm256<<<32 * 6, 512, 131072, stream>>>(cell1, wT, e2b, 1500, 1, cell2, 4096, 1536, 6);
  transpose_w<<<dim3(1536 / 32, 512 / 32), dim3(32, 8), 0, stream>>>(e3w, wT, 1500, 512, 1536, 512);
  gemm_bt<<<dim3(64, 4), 256, 0, stream>>>(cell2, wT, e3b, 512, 0, zbuf + 1536, 1536, 2048);

  // ---- head
  transpose_w<<<dim3(2048 / 32, 1024 / 32), dim3(32, 8), 0, stream>>>(l1w, wT, 2048, 1024, 2048, 1024);
  gemm_bt<<<dim3(64, 8), 256, 0, stream>>>(zbuf, wT, l1b, 1024, 1, zz1, 2048, 1024);
  transpose_w<<<dim3(1024 / 32, 512 / 32), dim3(32, 8), 0, stream>>>(l2w, wT, 1024, 512, 1024, 512);
  gemm_bt<<<dim3(64, 4), 256, 0, stream>>>(zz1, wT, l2b, 512, 1, zz2, 1024, 512);
  final_dot<<<NN / 4, 256, 0, stream>>>(zz2, l3w, l3b, out);
}

// Round 14
// 1443.570 us; speedup vs baseline: 1.1768x; 1.0158x over previous
//
#include <hip/hip_runtime.h>
#include <stdint.h>

#define NN 8192
#define NE 65536
#define ET (NE + NN)
#define F_IN   3247
#define F_IN_P 3264
#define F_EXP   7993
#define F_EXP_P 8000

typedef __attribute__((ext_vector_type(8))) short bf16x8;
typedef __attribute__((ext_vector_type(4))) float f32x4;

typedef const __attribute__((address_space(1))) void gvoid_t;
typedef __attribute__((address_space(3))) void lvoid_t;

__device__ __forceinline__ float bf2f(uint16_t u) {
  union { uint32_t i; float f; } v; v.i = ((uint32_t)u) << 16; return v.f;
}
__device__ __forceinline__ uint16_t f2bf(float f) {
  union { float f; uint32_t i; } v; v.f = f;
  uint32_t r = v.i + 0x7fffu + ((v.i >> 16) & 1u);  // RNE
  return (uint16_t)(r >> 16);
}

__device__ __forceinline__ void gld_lds16(const void* g, void* l) {
  __builtin_amdgcn_global_load_lds((gvoid_t*)g, (lvoid_t*)l, 16, 0, 0);
}

#define SBAR() __builtin_amdgcn_sched_barrier(0)
#define BARRIER() do { SBAR(); __builtin_amdgcn_s_barrier(); SBAR(); } while (0)
#define LGKM0() do { asm volatile("s_waitcnt lgkmcnt(0)" ::: "memory"); SBAR(); } while (0)
#define VMCNT(n) asm volatile("s_waitcnt vmcnt(" #n ")" ::: "memory")
#define MFMA16(a, b, c) __builtin_amdgcn_mfma_f32_16x16x32_bf16(a, b, c, 0, 0, 0)

// =================================================================== gemm256
// 256x256 tile, BK=64, 8 waves (2M x 4N). (m-half x k-slot) quadrant schedule:
// 24 frag reads/tile (minimum), 16-group peak liveness, 3 barriers/tile.
// SOUNDNESS (vs failed R12/R13): every DMA is drained by its issuing wave
// BEFORE a barrier preceding any cross-wave read (VMCNT at end-R2, not
// start-R3); every LDS read is lgkm-drained before the barrier preceding
// its buffer's overwrite (LGKM0 at end-R1b / end-R2). Barrier-backed, not
// timing-based.
// Per-wave VM queue (steady): end-R2 VMCNT(4): [B(T+1),A(T+1),B(T+2)] ->
// retires B(T+1)+A(T+1), leaving B(T+2). Tails: nls? 4 : (nlr? 0 : none).
__device__ __forceinline__ void stage4(const char* src, char* dst, size_t Kb) {
#pragma unroll
  for (int j = 0; j < 4; ++j)
    gld_lds16(src + (size_t)(j * 64) * Kb, dst + j * 8192);
}

#define KTILE(T, BUF)                                                          \
  do {                                                                         \
    const char* aB_  = smem + (BUF) + arow;                                    \
    const char* bB_  = smem + 65536 + (BUF) + brow_o;                          \
    const char* aBn_ = smem + ((BUF) ^ 32768) + arow;                          \
    const char* bBn_ = smem + 65536 + ((BUF) ^ 32768) + brow_o;                \
    const bool nls = ((T) + 2 < nk);                                           \
    const bool nlr = ((T) + 1 < nk);                                           \
    /* R1a: read a1=a[mh1,k0]; MFMA Q(mh0,k0)=a0 x b0 (operands reg-resident) */ \
    _Pragma("unroll")                                                          \
    for (int m = 0; m < 4; ++m)                                                \
      a1f[m] = *(const bf16x8*)(aB_ + (m + 4) * 2048 + sw0);                   \
    SBAR();                                                                    \
    __builtin_amdgcn_s_setprio(1);                                             \
    _Pragma("unroll")                                                          \
    for (int m = 0; m < 4; ++m)                                                \
      _Pragma("unroll")                                                        \
      for (int n = 0; n < 4; ++n)                                              \
        acc[m][n] = MFMA16(a0f[m], b0f[n], acc[m][n]);                         \
    __builtin_amdgcn_s_setprio(0);                                             \
    SBAR();                                                                    \
    /* R1b: read a2=a[mh0,k1] (into a0f), b1=b[*,k1]; MFMA Q(mh1,k0)=a1 x b0 */ \
    _Pragma("unroll")                                                          \
    for (int m = 0; m < 4; ++m)                                                \
      a0f[m] = *(const bf16x8*)(aB_ + m * 2048 + sw1);                         \
    _Pragma("unroll")                                                          \
    for (int n = 0; n < 4; ++n)                                                \
      b1f[n] = *(const bf16x8*)(bB_ + n * 2048 + sw1);                         \
    SBAR();                                                                    \
    __builtin_amdgcn_s_setprio(1);                                             \
    _Pragma("unroll")                                                          \
    for (int m = 0; m < 4; ++m)                                                \
      _Pragma("unroll")                                                        \
      for (int n = 0; n < 4; ++n)                                              \
        acc[m + 4][n] = MFMA16(a1f[m], b0f[n], acc[m + 4][n]);                 \
    __builtin_amdgcn_s_setprio(0);                                             \
    LGKM0();    /* b1f/a2 complete before any wave's R2 B-stage */             \
    BARRIER();                                                                 \
    /* R2: stage B(T+2)->this-B; read a3 (into a1f); MFMA Q(mh0,k1)=a2 x b1;   \
       end: VMCNT drains A(T+1)+B(T+1) (cross-wave, barrier-backed) */         \
    if (nls) stage4(pB + (size_t)((T) + 2) * 128, sB + (BUF), Kb);             \
    _Pragma("unroll")                                                          \
    for (int m = 0; m < 4; ++m)                                                \
      a1f[m] = *(const bf16x8*)(aB_ + (m + 4) * 2048 + sw1);                   \
    SBAR();                                                                    \
    __builtin_amdgcn_s_setprio(1);                                             \
    _Pragma("unroll")                                                          \
    for (int m = 0; m < 4; ++m)                                                \
      _Pragma("unroll")                                                        \
      for (int n = 0; n < 4; ++n)                                              \
        acc[m][n] = MFMA16(a0f[m], b1f[n], acc[m][n]);                         \
    __builtin_amdgcn_s_setprio(0);                                             \
    if (nls)      { VMCNT(4); }                                                \
    else if (nlr) { VMCNT(0); }                                                \
    LGKM0();    /* a3 complete before any wave's R3 A-stage */                 \
    BARRIER();                                                                 \
    /* R3: read a0',b0' (T+1, other buf — DMAs barrier-backed complete);       \
       stage A(T+2)->this-A; MFMA Q(mh1,k1)=a3 x b1 */                         \
    if (nlr) {                                                                 \
      _Pragma("unroll")                                                        \
      for (int m = 0; m < 4; ++m)                                              \
        a0f[m] = *(const bf16x8*)(aBn_ + m * 2048 + sw0);                      \
      _Pragma("unroll")                                                        \
      for (int n = 0; n < 4; ++n)                                              \
        b0f[n] = *(const bf16x8*)(bBn_ + n * 2048 + sw0);                      \
    }                                                                          \
    if (nls) stage4(pA + (size_t)((T) + 2) * 128, sA + (BUF), Kb);             \
    SBAR();                                                                    \
    __builtin_amdgcn_s_setprio(1);                                             \
    _Pragma("unroll")                                                          \
    for (int m = 0; m < 4; ++m)                                                \
      _Pragma("unroll")                                                        \
      for (int n = 0; n < 4; ++n)                                              \
        acc[m + 4][n] = MFMA16(a1f[m], b1f[n], acc[m + 4][n]);                 \
    __builtin_amdgcn_s_setprio(0);                                             \
    BARRIER();                                                                 \
  } while (0)

__global__ __launch_bounds__(512, 2)
void gemm256(const uint16_t* __restrict__ A, const uint16_t* __restrict__ Bt,
             const float* __restrict__ bias, int biasN, int relu,
             uint16_t* __restrict__ C, int Kp, int ldc, int nbn)
{
  extern __shared__ char smem[];   // [A: 2buf x 4 x 64rows x 128B = 64K][B: same]
  const int tid = threadIdx.x;
  const int w = tid >> 6, lane = tid & 63;
  const int wr = w >> 2, wc = w & 3;
  const int fr = lane & 15, g = lane >> 4;

  // T1: bijective XCD swizzle
  const int nwg = (int)gridDim.x;
  const int id = (int)blockIdx.x;
  const int q = nwg >> 3, r = nwg & 7;
  const int xcd = id & 7, idx = id >> 3;
  const int wg = (xcd < r ? xcd * (q + 1) : r * (q + 1) + (xcd - r) * q) + idx;
  const int brow = (wg / nbn) * 256, bcol = (wg % nbn) * 256;

  const size_t Kb = (size_t)Kp * 2;

  // staging: thread tid -> LDS j*8192 + (tid>>3)*128 + (tid&7)*16 (lane*16 by HW)
  const int srow = tid >> 3;
  const int sswz = ((tid & 7) ^ (srow & 7)) * 16;
  const char* pA = (const char*)A + (size_t)(brow + srow) * Kb + sswz;
  const char* pB = (const char*)Bt + (size_t)(bcol + srow) * Kb + sswz;
  char* sA = smem + w * 1024;
  char* sB = smem + 65536 + w * 1024;

  // frag read: slot q=kk*4+g stored at q ^ (row&7), row&7 == fr&7
  const int sw0 = (g ^ (fr & 7)) * 16;
  const int sw1 = ((g + 4) ^ (fr & 7)) * 16;
  const int arow = (wr * 128 + fr) * 128;   // + m*2048
  const int brow_o = (wc * 64 + fr) * 128;  // + n*2048

  f32x4 acc[8][4];
#pragma unroll
  for (int m = 0; m < 8; ++m)
#pragma unroll
    for (int n = 0; n < 4; ++n) acc[m][n] = (f32x4){0.f, 0.f, 0.f, 0.f};
  bf16x8 a0f[4], a1f[4], b0f[4], b1f[4];

  // prologue: stage A(0),B(0),A(1),B(1); VMCNT(8) retires A(0),B(0)
  // (barrier-backed); preload a0,b0 of tile0
  stage4(pA, sA, Kb);
  stage4(pB, sB, Kb);
  stage4(pA + 128, sA + 32768, Kb);
  stage4(pB + 128, sB + 32768, Kb);
  VMCNT(8);
  BARRIER();
#pragma unroll
  for (int m = 0; m < 4; ++m)
    a0f[m] = *(const bf16x8*)(smem + arow + m * 2048 + sw0);
#pragma unroll
  for (int n = 0; n < 4; ++n)
    b0f[n] = *(const bf16x8*)(smem + 65536 + brow_o + n * 2048 + sw0);
  SBAR();

  const int nk = Kp >> 6;
  for (int t = 0; t < nk; t += 2) {
    KTILE(t, 0);
    if (t + 1 < nk) KTILE(t + 1, 32768);
  }

  // epilogue: C/D layout col=lane&15, row=(lane>>4)*4+j
#pragma unroll
  for (int m = 0; m < 8; ++m) {
    const int row = brow + wr * 128 + m * 16 + g * 4;
#pragma unroll
    for (int n = 0; n < 4; ++n) {
      const int col = bcol + wc * 64 + n * 16 + fr;
      const float bv = (col < biasN) ? bias[col] : 0.f;
#pragma unroll
      for (int j = 0; j < 4; ++j) {
        float v = acc[m][n][j] + bv;
        if (relu) v = fmaxf(v, 0.f);
        C[(size_t)(row + j) * ldc + col] = f2bf(v);
      }
    }
  }
}

// ---------------------------------------------------------------- GEMM (m97 structure, small N)
__global__ __launch_bounds__(256)
void gemm_bt(const uint16_t* __restrict__ A, const uint16_t* __restrict__ Bt,
             const float* __restrict__ bias, int biasN, int relu,
             uint16_t* __restrict__ C, int Kp, int ldc)
{
  __shared__ uint16_t As[128 * 32];
  __shared__ uint16_t Bs[128 * 32];
  const int tid  = threadIdx.x;
  const int wave = tid >> 6, lane = tid & 63;
  const int brow = blockIdx.x * 128, bcol = blockIdx.y * 128;
  const int wr = wave >> 1, wc = wave & 1;
  const int fr = lane & 15, g = lane >> 4;

  f32x4 acc[4][4];
#pragma unroll
  for (int m = 0; m < 4; ++m)
#pragma unroll
    for (int n = 0; n < 4; ++n) acc[m][n] = (f32x4){0.f, 0.f, 0.f, 0.f};

  const int rA = tid >> 2;
  const int kc = (tid & 3) * 8;
  const uint16_t* aptr = A  + (size_t)(brow + rA) * Kp + kc;
  const uint16_t* bptr = Bt + (size_t)(bcol + rA) * Kp + kc;
  char* ldsA = (char*)As + wave * 1024;
  char* ldsB = (char*)Bs + wave * 1024;
  const size_t rowskip = (size_t)64 * Kp;

  const int nk = Kp >> 5;
  for (int kt = 0; kt < nk; ++kt) {
    __syncthreads();
    gld_lds16(aptr,           ldsA);
    gld_lds16(aptr + rowskip, ldsA + 4096);
    gld_lds16(bptr,           ldsB);
    gld_lds16(bptr + rowskip, ldsB + 4096);
    aptr += 32; bptr += 32;
    __syncthreads();

    bf16x8 af[4], bfr[4];
#pragma unroll
    for (int m = 0; m < 4; ++m)
      af[m] = *(const bf16x8*)&As[(wr * 64 + m * 16 + fr) * 32 + g * 8];
#pragma unroll
    for (int n = 0; n < 4; ++n)
      bfr[n] = *(const bf16x8*)&Bs[(wc * 64 + n * 16 + fr) * 32 + g * 8];
#pragma unroll
    for (int m = 0; m < 4; ++m)
#pragma unroll
      for (int n = 0; n < 4; ++n)
        acc[m][n] = MFMA16(af[m], bfr[n], acc[m][n]);
  }

#pragma unroll
  for (int m = 0; m < 4; ++m) {
    const int row = brow + wr * 64 + m * 16 + g * 4;
#pragma unroll
    for (int n = 0; n < 4; ++n) {
      const int col = bcol + wc * 64 + n * 16 + fr;
      const float bv = (col < biasN) ? bias[col] : 0.f;
#pragma unroll
      for (int j = 0; j < 4; ++j) {
        float v = acc[m][n][j] + bv;
        if (relu) v = fmaxf(v, 0.f);
        C[(size_t)(row + j) * ldc + col] = f2bf(v);
      }
    }
  }
}

// ---------------------------------------------------------------- conversions
__global__ __launch_bounds__(256)
void cvt_pad(const float* __restrict__ in, uint16_t* __restrict__ out, int cols, int colsPad)
{
  const int r = blockIdx.y;
  const int c = (blockIdx.x * 256 + threadIdx.x) * 2;
  if (c >= colsPad) return;
  const float* ip = in + (size_t)r * cols;
  const float v0 = (c < cols)     ? ip[c]     : 0.f;
  const float v1 = (c + 1 < cols) ? ip[c + 1] : 0.f;
  const uint32_t pk = (uint32_t)f2bf(v0) | ((uint32_t)f2bf(v1) << 16);
  *(uint32_t*)(out + (size_t)r * colsPad + c) = pk;
}

__global__ __launch_bounds__(256)
void transpose_w(const float* __restrict__ W, uint16_t* __restrict__ Wt,
                 int K, int N, int Kp, int Np)
{
  __shared__ float t[32][33];
  const int tx = threadIdx.x, ty = threadIdx.y;
  const int k0 = blockIdx.x * 32, n0 = blockIdx.y * 32;
#pragma unroll
  for (int j = 0; j < 4; ++j) {
    const int k = k0 + ty + j * 8, n = n0 + tx;
    t[ty + j * 8][tx] = (k < K && n < N) ? W[(size_t)k * N + n] : 0.f;
  }
  __syncthreads();
#pragma unroll
  for (int j = 0; j < 4; ++j) {
    const int n = n0 + ty + j * 8, k = k0 + tx;
    Wt[(size_t)n * Kp + k] = f2bf(t[tx][ty + j * 8]);
  }
}

__global__ void concat_bias(const float* __restrict__ bl, const float* __restrict__ br,
                            float* __restrict__ out)
{
  const int i = blockIdx.x * 256 + threadIdx.x;
  if (i < 1536) out[i] = bl[i];
  else if (i < 3072) out[i] = br[i - 1536];
}

// ---------------------------------------------------------------- CSR build
__global__ void count_deg(const int* __restrict__ ei, int* __restrict__ counts)
{
  const int e = blockIdx.x * 256 + threadIdx.x;
  if (e >= ET) return;
  const int d = (e < NE) ? ei[NE + e] : (e - NE);
  atomicAdd(&counts[d], 1);
}

__global__ __launch_bounds__(1024)
void scan_deg(const int* __restrict__ counts, int* __restrict__ row_start, int* __restrict__ cursor)
{
  __shared__ int part[1024];
  const int tid = threadIdx.x;
  int loc[8], pre[8], s = 0;
#pragma unroll
  for (int j = 0; j < 8; ++j) { loc[j] = counts[tid * 8 + j]; pre[j] = s; s += loc[j]; }
  part[tid] = s;
  __syncthreads();
  for (int o = 1; o < 1024; o <<= 1) {
    const int v = part[tid];
    const int a = (tid >= o) ? part[tid - o] : 0;
    __syncthreads();
    part[tid] = v + a;
    __syncthreads();
  }
  const int excl = part[tid] - s;
#pragma unroll
  for (int j = 0; j < 8; ++j) {
    const int v = excl + pre[j];
    row_start[tid * 8 + j] = v;
    cursor[tid * 8 + j]    = v;
  }
  if (tid == 1023) row_start[8192] = excl + s;
}

__global__ void scatter_e(const int* __restrict__ ei, int* __restrict__ cursor,
                          int* __restrict__ csr_src, int* __restrict__ csr_dst)
{
  const int e = blockIdx.x * 256 + threadIdx.x;
  if (e >= ET) return;
  const int sx = (e < NE) ? ei[e]      : (e - NE);
  const int d  = (e < NE) ? ei[NE + e] : (e - NE);
  const int pos = atomicAdd(&cursor[d], 1);
  csr_src[pos] = sx;
  csr_dst[pos] = d;
}

// ---------------------------------------------------------------- GATv2 fused attention
// One wave per node. Single pass over the node's edges: read xl[src] row once
// (3 bf16x8/lane), compute logit (shuffle reduce, wave-uniform), online-softmax
// rescale a 24-f32/lane accumulator. out[i] = relu(acc/z + ob).
__global__ __launch_bounds__(256)
void gat_fused(const uint16_t* __restrict__ xlr, int ld,
               const int* __restrict__ csr_src, const int* __restrict__ row_start,
               const float* __restrict__ att, const float* __restrict__ ob,
               uint16_t* __restrict__ out, int ldc)
{
  const int node = (blockIdx.x << 2) + (threadIdx.x >> 6);
  const int lane = threadIdx.x & 63;

  float av[3][8], xr[3][8];
  const bf16x8* pr = (const bf16x8*)(xlr + (size_t)node * ld + 1536);
#pragma unroll
  for (int h = 0; h < 3; ++h) {
    const float4 a0 = *(const float4*)(att + h * 512 + lane * 8);
    const float4 a1 = *(const float4*)(att + h * 512 + lane * 8 + 4);
    av[h][0] = a0.x; av[h][1] = a0.y; av[h][2] = a0.z; av[h][3] = a0.w;
    av[h][4] = a1.x; av[h][5] = a1.y; av[h][6] = a1.z; av[h][7] = a1.w;
    const bf16x8 v = pr[h * 64 + lane];
#pragma unroll
    for (int j = 0; j < 8; ++j) xr[h][j] = bf2f((uint16_t)v[j]);
  }

  float m[3] = {-1e30f, -1e30f, -1e30f};
  float z[3] = {0.f, 0.f, 0.f};
  float acc[3][8];
#pragma unroll
  for (int h = 0; h < 3; ++h)
#pragma unroll
    for (int j = 0; j < 8; ++j) acc[h][j] = 0.f;

  const int s0 = row_start[node], s1 = row_start[node + 1];
  for (int s = s0; s < s1; ++s) {
    const bf16x8* pl = (const bf16x8*)(xlr + (size_t)csr_src[s] * ld);
    bf16x8 vl[3];
#pragma unroll
    for (int h = 0; h < 3; ++h) vl[h] = pl[h * 64 + lane];

    float hacc[3];
#pragma unroll
    for (int h = 0; h < 3; ++h) {
      float sacc = 0.f;
#pragma unroll
      for (int j = 0; j < 8; ++j) {
        float v = bf2f((uint16_t)vl[h][j]) + xr[h][j];
        v = v > 0.f ? v : 0.2f * v;
        sacc += v * av[h][j];
      }
      hacc[h] = sacc;
    }
#pragma unroll
    for (int o = 32; o; o >>= 1) {
      hacc[0] += __shfl_xor(hacc[0], o);
      hacc[1] += __shfl_xor(hacc[1], o);
      hacc[2] += __shfl_xor(hacc[2], o);
    }
    // online softmax update (wave-uniform scale/p)
#pragma unroll
    for (int h = 0; h < 3; ++h) {
      const float nm = fmaxf(m[h], hacc[h]);
      const float sc = __expf(m[h] - nm);
      const float p  = __expf(hacc[h] - nm);
      z[h] = z[h] * sc + p;
#pragma unroll
      for (int j = 0; j < 8; ++j)
        acc[h][j] = acc[h][j] * sc + p * bf2f((uint16_t)vl[h][j]);
      m[h] = nm;
    }
  }

#pragma unroll
  for (int h = 0; h < 3; ++h) {
    const float rz = 1.f / z[h];
    const float4 b0 = *(const float4*)(ob + h * 512 + lane * 8);
    const float4 b1 = *(const float4*)(ob + h * 512 + lane * 8 + 4);
    float bv[8] = {b0.x, b0.y, b0.z, b0.w, b1.x, b1.y, b1.z, b1.w};
    bf16x8 pk;
#pragma unroll
    for (int j = 0; j < 8; ++j) {
      const float v = fmaxf(acc[h][j] * rz + bv[j], 0.f);
      pk[j] = (short)f2bf(v);
    }
    *(bf16x8*)(out + (size_t)node * ldc + h * 512 + lane * 8) = pk;
  }
}

// ---------------------------------------------------------------- final dot
__global__ __launch_bounds__(256)
void final_dot(const uint16_t* __restrict__ z2, const float* __restrict__ w,
               const float* __restrict__ b, float* __restrict__ out)
{
  const int row  = blockIdx.x * 4 + (threadIdx.x >> 6);
  const int lane = threadIdx.x & 63;
  const uint16_t* p = z2 + (size_t)row * 512;
  float s = 0.f;
#pragma unroll
  for (int j = 0; j < 8; ++j) { const int c = lane + j * 64; s += bf2f(p[c]) * w[c]; }
#pragma unroll
  for (int o = 32; o; o >>= 1) s += __shfl_xor(s, o);
  if (lane == 0) out[row] = s + b[0];
}

// ---------------------------------------------------------------- orchestration
extern "C" void kernel_launch(void* const* d_in, const int* in_sizes, int n_in,
                              void* d_out, int out_size, void* d_ws, size_t ws_size,
                              hipStream_t stream)
{
  (void)in_sizes; (void)n_in; (void)out_size; (void)ws_size;

  const float* x    = (const float*)d_in[0];
  const int*   ei   = (const int*)  d_in[1];
  const float* expm = (const float*)d_in[2];
  const float* w1l = (const float*)d_in[3];  const float* b1l = (const float*)d_in[4];
  const float* w1r = (const float*)d_in[5];  const float* b1r = (const float*)d_in[6];
  const float* a1  = (const float*)d_in[7];  const float* o1  = (const float*)d_in[8];
  const float* w2l = (const float*)d_in[9];  const float* b2l = (const float*)d_in[10];
  const float* w2r = (const float*)d_in[11]; const float* b2r = (const float*)d_in[12];
  const float* a2  = (const float*)d_in[13]; const float* o2  = (const float*)d_in[14];
  const float* w3l = (const float*)d_in[15]; const float* b3l = (const float*)d_in[16];
  const float* w3r = (const float*)d_in[17]; const float* b3r = (const float*)d_in[18];
  const float* a3  = (const float*)d_in[19]; const float* o3  = (const float*)d_in[20];
  const float* e1w = (const float*)d_in[21]; const float* e1b = (const float*)d_in[22];
  const float* e2w = (const float*)d_in[23]; const float* e2b = (const float*)d_in[24];
  const float* e3w = (const float*)d_in[25]; const float* e3b = (const float*)d_in[26];
  const float* l1w = (const float*)d_in[27]; const float* l1b = (const float*)d_in[28];
  const float* l2w = (const float*)d_in[29]; const float* l2b = (const float*)d_in[30];
  const float* l3w = (const float*)d_in[31]; const float* l3b = (const float*)d_in[32];
  float* out = (float*)d_out;

  hipFuncSetAttribute((const void*)gemm256, hipFuncAttributeMaxDynamicSharedMemorySize, 131072);

  char* ws = (char*)d_ws;
  size_t off = 0;
  auto take = [&](size_t b) { char* p = ws + off; off += (b + 255) & ~(size_t)255; return p; };

  int*      counts    = (int*)take((size_t)NN * 4);
  int*      row_start = (int*)take((size_t)(NN + 1) * 4);
  int*      cursor    = (int*)take((size_t)NN * 4);
  int*      csr_src   = (int*)take((size_t)ET * 4);
  int*      csr_dst   = (int*)take((size_t)ET * 4);
  float*    bc1       = (float*)take(3072 * 4);
  float*    bc2       = (float*)take(3072 * 4);
  float*    bc3       = (float*)take(3072 * 4);
  uint16_t* zbuf      = (uint16_t*)take((size_t)NN * 2048 * 2);
  char*     regA      = take((size_t)NN * F_EXP_P * 2);
  char*     regW      = take((size_t)4096 * F_EXP_P * 2);
  char*     regC      = take((size_t)NN * 4096 * 2 + (size_t)NN * 1536 * 2);

  uint16_t* xbf   = (uint16_t*)regA;
  uint16_t* expbf = (uint16_t*)regA;
  uint16_t* wT    = (uint16_t*)regW;
  // phase 1: xlr [8192][3072] + hbuf [8192][1536]
  uint16_t* xlr   = (uint16_t*)regC;
  uint16_t* hbuf  = (uint16_t*)(regC + (size_t)NN * 3072 * 2);
  // phase 2 (encoder): cell1 [8192][4096] | cell2 [8192][1536]
  uint16_t* cell1 = (uint16_t*)regC;
  uint16_t* cell2 = (uint16_t*)(regC + (size_t)NN * 4096 * 2);
  // phase 3 (head): zz1 [8192][1024] | zz2 [8192][512]
  uint16_t* zz1   = (uint16_t*)regC;
  uint16_t* zz2   = (uint16_t*)(regC + (size_t)NN * 1024 * 2);

  // ---- CSR + fused biases
  hipMemsetAsync(counts, 0, (size_t)NN * 4, stream);
  count_deg<<<(ET + 255) / 256, 256, 0, stream>>>(ei, counts);
  scan_deg<<<1, 1024, 0, stream>>>(counts, row_start, cursor);
  scatter_e<<<(ET + 255) / 256, 256, 0, stream>>>(ei, cursor, csr_src, csr_dst);
  concat_bias<<<12, 256, 0, stream>>>(b1l, b1r, bc1);
  concat_bias<<<12, 256, 0, stream>>>(b2l, b2r, bc2);
  concat_bias<<<12, 256, 0, stream>>>(b3l, b3r, bc3);

  // ---- GAT layer 1 (Kp = 3264), fused l|r GEMM -> xlr
  cvt_pad<<<dim3((F_IN_P / 2 + 255) / 256, NN), 256, 0, stream>>>(x, xbf, F_IN, F_IN_P);
  transpose_w<<<dim3(F_IN_P / 32, 1536 / 32), dim3(32, 8), 0, stream>>>(w1l, wT, F_IN, 1536, F_IN_P, 1536);
  transpose_w<<<dim3(F_IN_P / 32, 1536 / 32), dim3(32, 8), 0, stream>>>(w1r, wT + (size_t)1536 * F_IN_P, F_IN, 1536, F_IN_P, 1536);
  gemm256<<<32 * 12, 512, 131072, stream>>>(xbf, wT, bc1, 3072, 0, xlr, F_IN_P, 3072, 12);
  gat_fused<<<NN / 4, 256, 0, stream>>>(xlr, 3072, csr_src, row_start, a1, o1, hbuf, 1536);

  // ---- GAT layer 2 (K = 1536)
  transpose_w<<<dim3(48, 48), dim3(32, 8), 0, stream>>>(w2l, wT, 1536, 1536, 1536, 1536);
  transpose_w<<<dim3(48, 48), dim3(32, 8), 0, stream>>>(w2r, wT + (size_t)1536 * 1536, 1536, 1536, 1536, 1536);
  gemm256<<<32 * 12, 512, 131072, stream>>>(hbuf, wT, bc2, 3072, 0, xlr, 1536, 3072, 12);
  gat_fused<<<NN / 4, 256, 0, stream>>>(xlr, 3072, csr_src, row_start, a2, o2, hbuf, 1536);

  // ---- GAT layer 3 -> zbuf cols [0,1536)
  transpose_w<<<dim3(48, 48), dim3(32, 8), 0, stream>>>(w3l, wT, 1536, 1536, 1536, 1536);
  transpose_w<<<dim3(48, 48), dim3(32, 8), 0, stream>>>(w3r, wT + (size_t)1536 * 1536, 1536, 1536, 1536, 1536);
  gemm256<<<32 * 12, 512, 131072, stream>>>(hbuf, wT, bc3, 3072, 0, xlr, 1536, 3072, 12);
  gat_fused<<<NN / 4, 256, 0, stream>>>(xlr, 3072, csr_src, row_start, a3, o3, zbuf, 2048);

  // ---- encoder: 7993 -> 4000 -> 1500 -> 512 (last into zbuf cols [1536,2048))
  cvt_pad<<<dim3((F_EXP_P / 2 + 255) / 256, NN), 256, 0, stream>>>(expm, expbf, F_EXP, F_EXP_P);
  transpose_w<<<dim3(F_EXP_P / 32, 4096 / 32), dim3(32, 8), 0, stream>>>(e1w, wT, F_EXP, 4000, F_EXP_P, 4096);
  gemm256<<<32 * 16, 512, 131072, stream>>>(expbf, wT, e1b, 4000, 1, cell1, F_EXP_P, 4096, 16);
  transpose_w<<<dim3(4096 / 32, 1536 / 32), dim3(32, 8), 0, stream>>>(e2w, wT, 4000, 1500, 4096, 1536);
  gemm256<<<32 * 6, 512, 131072, stream>>>(cell1, wT, e2b, 1500, 1, cell2, 4096, 1536, 6);
  transpose_w<<<dim3(1536 / 32, 512 / 32), dim3(32, 8), 0, stream>>>(e3w, wT, 1500, 512, 1536, 512);
  gemm_bt<<<dim3(64, 4), 256, 0, stream>>>(cell2, wT, e3b, 512, 0, zbuf + 1536, 1536, 2048);

  // ---- head
  transpose_w<<<dim3(2048 / 32, 1024 / 32), dim3(32, 8), 0, stream>>>(l1w, wT, 2048, 1024, 2048, 1024);
  gemm_bt<<<dim3(64, 8), 256, 0, stream>>>(zbuf, wT, l1b, 1024, 1, zz1, 2048, 1024);
  transpose_w<<<dim3(1024 / 32, 512 / 32), dim3(32, 8), 0, stream>>>(l2w, wT, 1024, 512, 1024, 512);
  gemm_bt<<<dim3(64, 4), 256, 0, stream>>>(zz1, wT, l2b, 512, 1, zz2, 1024, 512);
  final_dot<<<NN / 4, 256, 0, stream>>>(zz2, l3w, l3b, out);
}

// Round 15
// 1440.040 us; speedup vs baseline: 1.1797x; 1.0025x over previous
//
#include <hip/hip_runtime.h>
#include <stdint.h>

#define NN 8192
#define NE 65536
#define ET (NE + NN)
#define F_IN   3247
#define F_IN_P 3264
#define F_EXP   7993
#define F_EXP_P 8000

typedef __attribute__((ext_vector_type(8))) short bf16x8;
typedef __attribute__((ext_vector_type(4))) float f32x4;

typedef const __attribute__((address_space(1))) void gvoid_t;
typedef __attribute__((address_space(3))) void lvoid_t;

__device__ __forceinline__ float bf2f(uint16_t u) {
  union { uint32_t i; float f; } v; v.i = ((uint32_t)u) << 16; return v.f;
}
__device__ __forceinline__ uint16_t f2bf(float f) {
  union { float f; uint32_t i; } v; v.f = f;
  uint32_t r = v.i + 0x7fffu + ((v.i >> 16) & 1u);  // RNE
  return (uint16_t)(r >> 16);
}

__device__ __forceinline__ void gld_lds16(const void* g, void* l) {
  __builtin_amdgcn_global_load_lds((gvoid_t*)g, (lvoid_t*)l, 16, 0, 0);
}

#define SBAR() __builtin_amdgcn_sched_barrier(0)
#define BARRIER() do { SBAR(); __builtin_amdgcn_s_barrier(); SBAR(); } while (0)
#define LGKM0() do { asm volatile("s_waitcnt lgkmcnt(0)" ::: "memory"); SBAR(); } while (0)
#define VMCNT(n) asm volatile("s_waitcnt vmcnt(" #n ")" ::: "memory")
#define MFMA16(a, b, c) __builtin_amdgcn_mfma_f32_16x16x32_bf16(a, b, c, 0, 0, 0)

// =================================================================== gemm256
// 256x256 tile, BK=64, 8 waves (2M x 4N). (m-half x k-slot) quadrant schedule,
// 24 frag reads/tile, 3 barriers/tile. R14-proven sync skeleton (unchanged):
// LGKM0 before overwrite-preceding barriers, VMCNT at end-R2 (barrier-backed
// cross-wave DMA completion). NEW vs R14: MFMA clusters rebalanced 12/20/12/20
// — the m=3 slice of each mh0 quadrant is deferred into the following 8-read
// phase so every read group is covered by a larger MFMA shadow. Only MFMA
// placement changed; no read/stage/sync moved.
__device__ __forceinline__ void stage4(const char* src, char* dst, size_t Kb) {
#pragma unroll
  for (int j = 0; j < 4; ++j)
    gld_lds16(src + (size_t)(j * 64) * Kb, dst + j * 8192);
}

#define KTILE(T, BUF)                                                          \
  do {                                                                         \
    const char* aB_  = smem + (BUF) + arow;                                    \
    const char* bB_  = smem + 65536 + (BUF) + brow_o;                          \
    const char* aBn_ = smem + ((BUF) ^ 32768) + arow;                          \
    const char* bBn_ = smem + 65536 + ((BUF) ^ 32768) + brow_o;                \
    const bool nls = ((T) + 2 < nk);                                           \
    const bool nlr = ((T) + 1 < nk);                                           \
    /* R1a (4 reads, 12 MFMA): read a1; MFMA Q(mh0,k0) m=0..2 */               \
    _Pragma("unroll")                                                          \
    for (int m = 0; m < 4; ++m)                                                \
      a1f[m] = *(const bf16x8*)(aB_ + (m + 4) * 2048 + sw0);                   \
    SBAR();                                                                    \
    __builtin_amdgcn_s_setprio(1);                                             \
    _Pragma("unroll")                                                          \
    for (int m = 0; m < 3; ++m)                                                \
      _Pragma("unroll")                                                        \
      for (int n = 0; n < 4; ++n)                                              \
        acc[m][n] = MFMA16(a0f[m], b0f[n], acc[m][n]);                         \
    __builtin_amdgcn_s_setprio(0);                                             \
    SBAR();                                                                    \
    /* R1b (8 reads, 20 MFMA): deferred Q(mh0,k0) m=3; read a2->a0f, b1;       \
       MFMA Q(mh1,k0) */                                                       \
    __builtin_amdgcn_s_setprio(1);                                             \
    _Pragma("unroll")                                                          \
    for (int n = 0; n < 4; ++n)                                                \
      acc[3][n] = MFMA16(a0f[3], b0f[n], acc[3][n]);                           \
    __builtin_amdgcn_s_setprio(0);                                             \
    _Pragma("unroll")                                                          \
    for (int m = 0; m < 4; ++m)                                                \
      a0f[m] = *(const bf16x8*)(aB_ + m * 2048 + sw1);                         \
    _Pragma("unroll")                                                          \
    for (int n = 0; n < 4; ++n)                                                \
      b1f[n] = *(const bf16x8*)(bB_ + n * 2048 + sw1);                         \
    SBAR();                                                                    \
    __builtin_amdgcn_s_setprio(1);                                             \
    _Pragma("unroll")                                                          \
    for (int m = 0; m < 4; ++m)                                                \
      _Pragma("unroll")                                                        \
      for (int n = 0; n < 4; ++n)                                              \
        acc[m + 4][n] = MFMA16(a1f[m], b0f[n], acc[m + 4][n]);                 \
    __builtin_amdgcn_s_setprio(0);                                             \
    LGKM0();    /* b1f/a2 complete before any wave's R2 B-stage */             \
    BARRIER();                                                                 \
    /* R2 (4 reads, 12 MFMA): stage B(T+2); read a3; MFMA Q(mh0,k1) m=0..2;    \
       end: VMCNT drains A(T+1)+B(T+1) (cross-wave, barrier-backed) */         \
    if (nls) stage4(pB + (size_t)((T) + 2) * 128, sB + (BUF), Kb);             \
    _Pragma("unroll")                                                          \
    for (int m = 0; m < 4; ++m)                                                \
      a1f[m] = *(const bf16x8*)(aB_ + (m + 4) * 2048 + sw1);                   \
    SBAR();                                                                    \
    __builtin_amdgcn_s_setprio(1);                                             \
    _Pragma("unroll")                                                          \
    for (int m = 0; m < 3; ++m)                                                \
      _Pragma("unroll")                                                        \
      for (int n = 0; n < 4; ++n)                                              \
        acc[m][n] = MFMA16(a0f[m], b1f[n], acc[m][n]);                         \
    __builtin_amdgcn_s_setprio(0);                                             \
    if (nls)      { VMCNT(4); }                                                \
    else if (nlr) { VMCNT(0); }                                                \
    LGKM0();    /* a3 complete before any wave's R3 A-stage */                 \
    BARRIER();                                                                 \
    /* R3 (8 reads, 20 MFMA): deferred Q(mh0,k1) m=3; read a0',b0' (T+1 —      \
       DMAs barrier-backed complete); stage A(T+2); MFMA Q(mh1,k1) */          \
    __builtin_amdgcn_s_setprio(1);                                             \
    _Pragma("unroll")                                                          \
    for (int n = 0; n < 4; ++n)                                                \
      acc[3][n] = MFMA16(a0f[3], b1f[n], acc[3][n]);                           \
    __builtin_amdgcn_s_setprio(0);                                             \
    if (nlr) {                                                                 \
      _Pragma("unroll")                                                        \
      for (int m = 0; m < 4; ++m)                                              \
        a0f[m] = *(const bf16x8*)(aBn_ + m * 2048 + sw0);                      \
      _Pragma("unroll")                                                        \
      for (int n = 0; n < 4; ++n)                                              \
        b0f[n] = *(const bf16x8*)(bBn_ + n * 2048 + sw0);                      \
    }                                                                          \
    if (nls) stage4(pA + (size_t)((T) + 2) * 128, sA + (BUF), Kb);             \
    SBAR();                                                                    \
    __builtin_amdgcn_s_setprio(1);                                             \
    _Pragma("unroll")                                                          \
    for (int m = 0; m < 4; ++m)                                                \
      _Pragma("unroll")                                                        \
      for (int n = 0; n < 4; ++n)                                              \
        acc[m + 4][n] = MFMA16(a1f[m], b1f[n], acc[m + 4][n]);                 \
    __builtin_amdgcn_s_setprio(0);                                             \
    BARRIER();                                                                 \
  } while (0)

__global__ __launch_bounds__(512, 2)
void gemm256(const uint16_t* __restrict__ A, const uint16_t* __restrict__ Bt,
             const float* __restrict__ bias, int biasN, int relu,
             uint16_t* __restrict__ C, int Kp, int ldc, int nbn)
{
  extern __shared__ char smem[];   // [A: 2buf x 4 x 64rows x 128B = 64K][B: same]
  const int tid = threadIdx.x;
  const int w = tid >> 6, lane = tid & 63;
  const int wr = w >> 2, wc = w & 3;
  const int fr = lane & 15, g = lane >> 4;

  // T1: bijective XCD swizzle
  const int nwg = (int)gridDim.x;
  const int id = (int)blockIdx.x;
  const int q = nwg >> 3, r = nwg & 7;
  const int xcd = id & 7, idx = id >> 3;
  const int wg = (xcd < r ? xcd * (q + 1) : r * (q + 1) + (xcd - r) * q) + idx;
  const int brow = (wg / nbn) * 256, bcol = (wg % nbn) * 256;

  const size_t Kb = (size_t)Kp * 2;

  // staging: thread tid -> LDS j*8192 + (tid>>3)*128 + (tid&7)*16 (lane*16 by HW)
  const int srow = tid >> 3;
  const int sswz = ((tid & 7) ^ (srow & 7)) * 16;
  const char* pA = (const char*)A + (size_t)(brow + srow) * Kb + sswz;
  const char* pB = (const char*)Bt + (size_t)(bcol + srow) * Kb + sswz;
  char* sA = smem + w * 1024;
  char* sB = smem + 65536 + w * 1024;

  // frag read: slot q=kk*4+g stored at q ^ (row&7), row&7 == fr&7
  const int sw0 = (g ^ (fr & 7)) * 16;
  const int sw1 = ((g + 4) ^ (fr & 7)) * 16;
  const int arow = (wr * 128 + fr) * 128;   // + m*2048
  const int brow_o = (wc * 64 + fr) * 128;  // + n*2048

  f32x4 acc[8][4];
#pragma unroll
  for (int m = 0; m < 8; ++m)
#pragma unroll
    for (int n = 0; n < 4; ++n) acc[m][n] = (f32x4){0.f, 0.f, 0.f, 0.f};
  bf16x8 a0f[4], a1f[4], b0f[4], b1f[4];

  // prologue: stage A(0),B(0),A(1),B(1); VMCNT(8) retires A(0),B(0)
  // (barrier-backed); preload a0,b0 of tile0
  stage4(pA, sA, Kb);
  stage4(pB, sB, Kb);
  stage4(pA + 128, sA + 32768, Kb);
  stage4(pB + 128, sB + 32768, Kb);
  VMCNT(8);
  BARRIER();
#pragma unroll
  for (int m = 0; m < 4; ++m)
    a0f[m] = *(const bf16x8*)(smem + arow + m * 2048 + sw0);
#pragma unroll
  for (int n = 0; n < 4; ++n)
    b0f[n] = *(const bf16x8*)(smem + 65536 + brow_o + n * 2048 + sw0);
  SBAR();

  const int nk = Kp >> 6;
  for (int t = 0; t < nk; t += 2) {
    KTILE(t, 0);
    if (t + 1 < nk) KTILE(t + 1, 32768);
  }

  // epilogue: C/D layout col=lane&15, row=(lane>>4)*4+j
#pragma unroll
  for (int m = 0; m < 8; ++m) {
    const int row = brow + wr * 128 + m * 16 + g * 4;
#pragma unroll
    for (int n = 0; n < 4; ++n) {
      const int col = bcol + wc * 64 + n * 16 + fr;
      const float bv = (col < biasN) ? bias[col] : 0.f;
#pragma unroll
      for (int j = 0; j < 4; ++j) {
        float v = acc[m][n][j] + bv;
        if (relu) v = fmaxf(v, 0.f);
        C[(size_t)(row + j) * ldc + col] = f2bf(v);
      }
    }
  }
}

// ---------------------------------------------------------------- GEMM (m97 structure, small N)
__global__ __launch_bounds__(256)
void gemm_bt(const uint16_t* __restrict__ A, const uint16_t* __restrict__ Bt,
             const float* __restrict__ bias, int biasN, int relu,
             uint16_t* __restrict__ C, int Kp, int ldc)
{
  __shared__ uint16_t As[128 * 32];
  __shared__ uint16_t Bs[128 * 32];
  const int tid  = threadIdx.x;
  const int wave = tid >> 6, lane = tid & 63;
  const int brow = blockIdx.x * 128, bcol = blockIdx.y * 128;
  const int wr = wave >> 1, wc = wave & 1;
  const int fr = lane & 15, g = lane >> 4;

  f32x4 acc[4][4];
#pragma unroll
  for (int m = 0; m < 4; ++m)
#pragma unroll
    for (int n = 0; n < 4; ++n) acc[m][n] = (f32x4){0.f, 0.f, 0.f, 0.f};

  const int rA = tid >> 2;
  const int kc = (tid & 3) * 8;
  const uint16_t* aptr = A  + (size_t)(brow + rA) * Kp + kc;
  const uint16_t* bptr = Bt + (size_t)(bcol + rA) * Kp + kc;
  char* ldsA = (char*)As + wave * 1024;
  char* ldsB = (char*)Bs + wave * 1024;
  const size_t rowskip = (size_t)64 * Kp;

  const int nk = Kp >> 5;
  for (int kt = 0; kt < nk; ++kt) {
    __syncthreads();
    gld_lds16(aptr,           ldsA);
    gld_lds16(aptr + rowskip, ldsA + 4096);
    gld_lds16(bptr,           ldsB);
    gld_lds16(bptr + rowskip, ldsB + 4096);
    aptr += 32; bptr += 32;
    __syncthreads();

    bf16x8 af[4], bfr[4];
#pragma unroll
    for (int m = 0; m < 4; ++m)
      af[m] = *(const bf16x8*)&As[(wr * 64 + m * 16 + fr) * 32 + g * 8];
#pragma unroll
    for (int n = 0; n < 4; ++n)
      bfr[n] = *(const bf16x8*)&Bs[(wc * 64 + n * 16 + fr) * 32 + g * 8];
#pragma unroll
    for (int m = 0; m < 4; ++m)
#pragma unroll
      for (int n = 0; n < 4; ++n)
        acc[m][n] = MFMA16(af[m], bfr[n], acc[m][n]);
  }

#pragma unroll
  for (int m = 0; m < 4; ++m) {
    const int row = brow + wr * 64 + m * 16 + g * 4;
#pragma unroll
    for (int n = 0; n < 4; ++n) {
      const int col = bcol + wc * 64 + n * 16 + fr;
      const float bv = (col < biasN) ? bias[col] : 0.f;
#pragma unroll
      for (int j = 0; j < 4; ++j) {
        float v = acc[m][n][j] + bv;
        if (relu) v = fmaxf(v, 0.f);
        C[(size_t)(row + j) * ldc + col] = f2bf(v);
      }
    }
  }
}

// ---------------------------------------------------------------- conversions
__global__ __launch_bounds__(256)
void cvt_pad(const float* __restrict__ in, uint16_t* __restrict__ out, int cols, int colsPad)
{
  const int r = blockIdx.y;
  const int c = (blockIdx.x * 256 + threadIdx.x) * 2;
  if (c >= colsPad) return;
  const float* ip = in + (size_t)r * cols;
  const float v0 = (c < cols)     ? ip[c]     : 0.f;
  const float v1 = (c + 1 < cols) ? ip[c + 1] : 0.f;
  const uint32_t pk = (uint32_t)f2bf(v0) | ((uint32_t)f2bf(v1) << 16);
  *(uint32_t*)(out + (size_t)r * colsPad + c) = pk;
}

__global__ __launch_bounds__(256)
void transpose_w(const float* __restrict__ W, uint16_t* __restrict__ Wt,
                 int K, int N, int Kp, int Np)
{
  __shared__ float t[32][33];
  const int tx = threadIdx.x, ty = threadIdx.y;
  const int k0 = blockIdx.x * 32, n0 = blockIdx.y * 32;
#pragma unroll
  for (int j = 0; j < 4; ++j) {
    const int k = k0 + ty + j * 8, n = n0 + tx;
    t[ty + j * 8][tx] = (k < K && n < N) ? W[(size_t)k * N + n] : 0.f;
  }
  __syncthreads();
#pragma unroll
  for (int j = 0; j < 4; ++j) {
    const int n = n0 + ty + j * 8, k = k0 + tx;
    Wt[(size_t)n * Kp + k] = f2bf(t[tx][ty + j * 8]);
  }
}

__global__ void concat_bias(const float* __restrict__ bl, const float* __restrict__ br,
                            float* __restrict__ out)
{
  const int i = blockIdx.x * 256 + threadIdx.x;
  if (i < 1536) out[i] = bl[i];
  else if (i < 3072) out[i] = br[i - 1536];
}

// ---------------------------------------------------------------- CSR build
__global__ void count_deg(const int* __restrict__ ei, int* __restrict__ counts)
{
  const int e = blockIdx.x * 256 + threadIdx.x;
  if (e >= ET) return;
  const int d = (e < NE) ? ei[NE + e] : (e - NE);
  atomicAdd(&counts[d], 1);
}

__global__ __launch_bounds__(1024)
void scan_deg(const int* __restrict__ counts, int* __restrict__ row_start, int* __restrict__ cursor)
{
  __shared__ int part[1024];
  const int tid = threadIdx.x;
  int loc[8], pre[8], s = 0;
#pragma unroll
  for (int j = 0; j < 8; ++j) { loc[j] = counts[tid * 8 + j]; pre[j] = s; s += loc[j]; }
  part[tid] = s;
  __syncthreads();
  for (int o = 1; o < 1024; o <<= 1) {
    const int v = part[tid];
    const int a = (tid >= o) ? part[tid - o] : 0;
    __syncthreads();
    part[tid] = v + a;
    __syncthreads();
  }
  const int excl = part[tid] - s;
#pragma unroll
  for (int j = 0; j < 8; ++j) {
    const int v = excl + pre[j];
    row_start[tid * 8 + j] = v;
    cursor[tid * 8 + j]    = v;
  }
  if (tid == 1023) row_start[8192] = excl + s;
}

__global__ void scatter_e(const int* __restrict__ ei, int* __restrict__ cursor,
                          int* __restrict__ csr_src, int* __restrict__ csr_dst)
{
  const int e = blockIdx.x * 256 + threadIdx.x;
  if (e >= ET) return;
  const int sx = (e < NE) ? ei[e]      : (e - NE);
  const int d  = (e < NE) ? ei[NE + e] : (e - NE);
  const int pos = atomicAdd(&cursor[d], 1);
  csr_src[pos] = sx;
  csr_dst[pos] = d;
}

// ---------------------------------------------------------------- GATv2 fused attention
// One wave per node. Single pass over the node's edges: read xl[src] row once
// (3 bf16x8/lane), compute logit (shuffle reduce, wave-uniform), online-softmax
// rescale a 24-f32/lane accumulator. out[i] = relu(acc/z + ob).
__global__ __launch_bounds__(256)
void gat_fused(const uint16_t* __restrict__ xlr, int ld,
               const int* __restrict__ csr_src, const int* __restrict__ row_start,
               const float* __restrict__ att, const float* __restrict__ ob,
               uint16_t* __restrict__ out, int ldc)
{
  const int node = (blockIdx.x << 2) + (threadIdx.x >> 6);
  const int lane = threadIdx.x & 63;

  float av[3][8], xr[3][8];
  const bf16x8* pr = (const bf16x8*)(xlr + (size_t)node * ld + 1536);
#pragma unroll
  for (int h = 0; h < 3; ++h) {
    const float4 a0 = *(const float4*)(att + h * 512 + lane * 8);
    const float4 a1 = *(const float4*)(att + h * 512 + lane * 8 + 4);
    av[h][0] = a0.x; av[h][1] = a0.y; av[h][2] = a0.z; av[h][3] = a0.w;
    av[h][4] = a1.x; av[h][5] = a1.y; av[h][6] = a1.z; av[h][7] = a1.w;
    const bf16x8 v = pr[h * 64 + lane];
#pragma unroll
    for (int j = 0; j < 8; ++j) xr[h][j] = bf2f((uint16_t)v[j]);
  }

  float m[3] = {-1e30f, -1e30f, -1e30f};
  float z[3] = {0.f, 0.f, 0.f};
  float acc[3][8];
#pragma unroll
  for (int h = 0; h < 3; ++h)
#pragma unroll
    for (int j = 0; j < 8; ++j) acc[h][j] = 0.f;

  const int s0 = row_start[node], s1 = row_start[node + 1];
  for (int s = s0; s < s1; ++s) {
    const bf16x8* pl = (const bf16x8*)(xlr + (size_t)csr_src[s] * ld);
    bf16x8 vl[3];
#pragma unroll
    for (int h = 0; h < 3; ++h) vl[h] = pl[h * 64 + lane];

    float hacc[3];
#pragma unroll
    for (int h = 0; h < 3; ++h) {
      float sacc = 0.f;
#pragma unroll
      for (int j = 0; j < 8; ++j) {
        float v = bf2f((uint16_t)vl[h][j]) + xr[h][j];
        v = v > 0.f ? v : 0.2f * v;
        sacc += v * av[h][j];
      }
      hacc[h] = sacc;
    }
#pragma unroll
    for (int o = 32; o; o >>= 1) {
      hacc[0] += __shfl_xor(hacc[0], o);
      hacc[1] += __shfl_xor(hacc[1], o);
      hacc[2] += __shfl_xor(hacc[2], o);
    }
    // online softmax update (wave-uniform scale/p)
#pragma unroll
    for (int h = 0; h < 3; ++h) {
      const float nm = fmaxf(m[h], hacc[h]);
      const float sc = __expf(m[h] - nm);
      const float p  = __expf(hacc[h] - nm);
      z[h] = z[h] * sc + p;
#pragma unroll
      for (int j = 0; j < 8; ++j)
        acc[h][j] = acc[h][j] * sc + p * bf2f((uint16_t)vl[h][j]);
      m[h] = nm;
    }
  }

#pragma unroll
  for (int h = 0; h < 3; ++h) {
    const float rz = 1.f / z[h];
    const float4 b0 = *(const float4*)(ob + h * 512 + lane * 8);
    const float4 b1 = *(const float4*)(ob + h * 512 + lane * 8 + 4);
    float bv[8] = {b0.x, b0.y, b0.z, b0.w, b1.x, b1.y, b1.z, b1.w};
    bf16x8 pk;
#pragma unroll
    for (int j = 0; j < 8; ++j) {
      const float v = fmaxf(acc[h][j] * rz + bv[j], 0.f);
      pk[j] = (short)f2bf(v);
    }
    *(bf16x8*)(out + (size_t)node * ldc + h * 512 + lane * 8) = pk;
  }
}

// ---------------------------------------------------------------- final dot
__global__ __launch_bounds__(256)
void final_dot(const uint16_t* __restrict__ z2, const float* __restrict__ w,
               const float* __restrict__ b, float* __restrict__ out)
{
  const int row  = blockIdx.x * 4 + (threadIdx.x >> 6);
  const int lane = threadIdx.x & 63;
  const uint16_t* p = z2 + (size_t)row * 512;
  float s = 0.f;
#pragma unroll
  for (int j = 0; j < 8; ++j) { const int c = lane + j * 64; s += bf2f(p[c]) * w[c]; }
#pragma unroll
  for (int o = 32; o; o >>= 1) s += __shfl_xor(s, o);
  if (lane == 0) out[row] = s + b[0];
}

// ---------------------------------------------------------------- orchestration
extern "C" void kernel_launch(void* const* d_in, const int* in_sizes, int n_in,
                              void* d_out, int out_size, void* d_ws, size_t ws_size,
                              hipStream_t stream)
{
  (void)in_sizes; (void)n_in; (void)out_size; (void)ws_size;

  const float* x    = (const float*)d_in[0];
  const int*   ei   = (const int*)  d_in[1];
  const float* expm = (const float*)d_in[2];
  const float* w1l = (const float*)d_in[3];  const float* b1l = (const float*)d_in[4];
  const float* w1r = (const float*)d_in[5];  const float* b1r = (const float*)d_in[6];
  const float* a1  = (const float*)d_in[7];  const float* o1  = (const float*)d_in[8];
  const float* w2l = (const float*)d_in[9];  const float* b2l = (const float*)d_in[10];
  const float* w2r = (const float*)d_in[11]; const float* b2r = (const float*)d_in[12];
  const float* a2  = (const float*)d_in[13]; const float* o2  = (const float*)d_in[14];
  const float* w3l = (const float*)d_in[15]; const float* b3l = (const float*)d_in[16];
  const float* w3r = (const float*)d_in[17]; const float* b3r = (const float*)d_in[18];
  const float* a3  = (const float*)d_in[19]; const float* o3  = (const float*)d_in[20];
  const float* e1w = (const float*)d_in[21]; const float* e1b = (const float*)d_in[22];
  const float* e2w = (const float*)d_in[23]; const float* e2b = (const float*)d_in[24];
  const float* e3w = (const float*)d_in[25]; const float* e3b = (const float*)d_in[26];
  const float* l1w = (const float*)d_in[27]; const float* l1b = (const float*)d_in[28];
  const float* l2w = (const float*)d_in[29]; const float* l2b = (const float*)d_in[30];
  const float* l3w = (const float*)d_in[31]; const float* l3b = (const float*)d_in[32];
  float* out = (float*)d_out;

  hipFuncSetAttribute((const void*)gemm256, hipFuncAttributeMaxDynamicSharedMemorySize, 131072);

  char* ws = (char*)d_ws;
  size_t off = 0;
  auto take = [&](size_t b) { char* p = ws + off; off += (b + 255) & ~(size_t)255; return p; };

  int*      counts    = (int*)take((size_t)NN * 4);
  int*      row_start = (int*)take((size_t)(NN + 1) * 4);
  int*      cursor    = (int*)take((size_t)NN * 4);
  int*      csr_src   = (int*)take((size_t)ET * 4);
  int*      csr_dst   = (int*)take((size_t)ET * 4);
  float*    bc1       = (float*)take(3072 * 4);
  float*    bc2       = (float*)take(3072 * 4);
  float*    bc3       = (float*)take(3072 * 4);
  uint16_t* zbuf      = (uint16_t*)take((size_t)NN * 2048 * 2);
  char*     regA      = take((size_t)NN * F_EXP_P * 2);
  char*     regW      = take((size_t)4096 * F_EXP_P * 2);
  char*     regC      = take((size_t)NN * 4096 * 2 + (size_t)NN * 1536 * 2);

  uint16_t* xbf   = (uint16_t*)regA;
  uint16_t* expbf = (uint16_t*)regA;
  uint16_t* wT    = (uint16_t*)regW;
  // phase 1: xlr [8192][3072] + hbuf [8192][1536]
  uint16_t* xlr   = (uint16_t*)regC;
  uint16_t* hbuf  = (uint16_t*)(regC + (size_t)NN * 3072 * 2);
  // phase 2 (encoder): cell1 [8192][4096] | cell2 [8192][1536]
  uint16_t* cell1 = (uint16_t*)regC;
  uint16_t* cell2 = (uint16_t*)(regC + (size_t)NN * 4096 * 2);
  // phase 3 (head): zz1 [8192][1024] | zz2 [8192][512]
  uint16_t* zz1   = (uint16_t*)regC;
  uint16_t* zz2   = (uint16_t*)(regC + (size_t)NN * 1024 * 2);

  // ---- CSR + fused biases
  hipMemsetAsync(counts, 0, (size_t)NN * 4, stream);
  count_deg<<<(ET + 255) / 256, 256, 0, stream>>>(ei, counts);
  scan_deg<<<1, 1024, 0, stream>>>(counts, row_start, cursor);
  scatter_e<<<(ET + 255) / 256, 256, 0, stream>>>(ei, cursor, csr_src, csr_dst);
  concat_bias<<<12, 256, 0, stream>>>(b1l, b1r, bc1);
  concat_bias<<<12, 256, 0, stream>>>(b2l, b2r, bc2);
  concat_bias<<<12, 256, 0, stream>>>(b3l, b3r, bc3);

  // ---- GAT layer 1 (Kp = 3264), fused l|r GEMM -> xlr
  cvt_pad<<<dim3((F_IN_P / 2 + 255) / 256, NN), 256, 0, stream>>>(x, xbf, F_IN, F_IN_P);
  transpose_w<<<dim3(F_IN_P / 32, 1536 / 32), dim3(32, 8), 0, stream>>>(w1l, wT, F_IN, 1536, F_IN_P, 1536);
  transpose_w<<<dim3(F_IN_P / 32, 1536 / 32), dim3(32, 8), 0, stream>>>(w1r, wT + (size_t)1536 * F_IN_P, F_IN, 1536, F_IN_P, 1536);
  gemm256<<<32 * 12, 512, 131072, stream>>>(xbf, wT, bc1, 3072, 0, xlr, F_IN_P, 3072, 12);
  gat_fused<<<NN / 4, 256, 0, stream>>>(xlr, 3072, csr_src, row_start, a1, o1, hbuf, 1536);

  // ---- GAT layer 2 (K = 1536)
  transpose_w<<<dim3(48, 48), dim3(32, 8), 0, stream>>>(w2l, wT, 1536, 1536, 1536, 1536);
  transpose_w<<<dim3(48, 48), dim3(32, 8), 0, stream>>>(w2r, wT + (size_t)1536 * 1536, 1536, 1536, 1536, 1536);
  gemm256<<<32 * 12, 512, 131072, stream>>>(hbuf, wT, bc2, 3072, 0, xlr, 1536, 3072, 12);
  gat_fused<<<NN / 4, 256, 0, stream>>>(xlr, 3072, csr_src, row_start, a2, o2, hbuf, 1536);

  // ---- GAT layer 3 -> zbuf cols [0,1536)
  transpose_w<<<dim3(48, 48), dim3(32, 8), 0, stream>>>(w3l, wT, 1536, 1536, 1536, 1536);
  transpose_w<<<dim3(48, 48), dim3(32, 8), 0, stream>>>(w3r, wT + (size_t)1536 * 1536, 1536, 1536, 1536, 1536);
  gemm256<<<32 * 12, 512, 131072, stream>>>(hbuf, wT, bc3, 3072, 0, xlr, 1536, 3072, 12);
  gat_fused<<<NN / 4, 256, 0, stream>>>(xlr, 3072, csr_src, row_start, a3, o3, zbuf, 2048);

  // ---- encoder: 7993 -> 4000 -> 1500 -> 512 (last into zbuf cols [1536,2048))
  cvt_pad<<<dim3((F_EXP_P / 2 + 255) / 256, NN), 256, 0, stream>>>(expm, expbf, F_EXP, F_EXP_P);
  transpose_w<<<dim3(F_EXP_P / 32, 4096 / 32), dim3(32, 8), 0, stream>>>(e1w, wT, F_EXP, 4000, F_EXP_P, 4096);
  gemm256<<<32 * 16, 512, 131072, stream>>>(expbf, wT, e1b, 4000, 1, cell1, F_EXP_P, 4096, 16);
  transpose_w<<<dim3(4096 / 32, 1536 / 32), dim3(32, 8), 0, stream>>>(e2w, wT, 4000, 1500, 4096, 1536);
  gemm256<<<32 * 6, 512, 131072, stream>>>(cell1, wT, e2b, 1500, 1, cell2, 4096, 1536, 6);
  transpose_w<<<dim3(1536 / 32, 512 / 32), dim3(32, 8), 0, stream>>>(e3w, wT, 1500, 512, 1536, 512);
  gemm_bt<<<dim3(64, 4), 256, 0, stream>>>(cell2, wT, e3b, 512, 0, zbuf + 1536, 1536, 2048);

  // ---- head
  transpose_w<<<dim3(2048 / 32, 1024 / 32), dim3(32, 8), 0, stream>>>(l1w, wT, 2048, 1024, 2048, 1024);
  gemm_bt<<<dim3(64, 8), 256, 0, stream>>>(zbuf, wT, l1b, 1024, 1, zz1, 2048, 1024);
  transpose_w<<<dim3(1024 / 32, 512 / 32), dim3(32, 8), 0, stream>>>(l2w, wT, 1024, 512, 1024, 512);
  gemm_bt<<<dim3(64, 4), 256, 0, stream>>>(zz1, wT, l2b, 512, 1, zz2, 1024, 512);
  final_dot<<<NN / 4, 256, 0, stream>>>(zz2, l3w, l3b, out);
}

// Round 16
// 1423.096 us; speedup vs baseline: 1.1938x; 1.0119x over previous
//
#include <hip/hip_runtime.h>
#include <stdint.h>

#define NN 8192
#define NE 65536
#define ET (NE + NN)
#define F_IN   3247
#define F_IN_P 3264
#define F_EXP   7993
#define F_EXP_P 8000

typedef __attribute__((ext_vector_type(8))) short bf16x8;
typedef __attribute__((ext_vector_type(4))) float f32x4;

typedef const __attribute__((address_space(1))) void gvoid_t;
typedef __attribute__((address_space(3))) void lvoid_t;

__device__ __forceinline__ float bf2f(uint16_t u) {
  union { uint32_t i; float f; } v; v.i = ((uint32_t)u) << 16; return v.f;
}
__device__ __forceinline__ uint16_t f2bf(float f) {
  union { float f; uint32_t i; } v; v.f = f;
  uint32_t r = v.i + 0x7fffu + ((v.i >> 16) & 1u);  // RNE
  return (uint16_t)(r >> 16);
}

__device__ __forceinline__ void gld_lds16(const void* g, void* l) {
  __builtin_amdgcn_global_load_lds((gvoid_t*)g, (lvoid_t*)l, 16, 0, 0);
}

#define SBAR() __builtin_amdgcn_sched_barrier(0)
#define BARRIER() do { SBAR(); __builtin_amdgcn_s_barrier(); SBAR(); } while (0)
#define LGKM0() do { asm volatile("s_waitcnt lgkmcnt(0)" ::: "memory"); SBAR(); } while (0)
#define VMCNT(n) asm volatile("s_waitcnt vmcnt(" #n ")" ::: "memory")
#define MFMA16(a, b, c) __builtin_amdgcn_mfma_f32_16x16x32_bf16(a, b, c, 0, 0, 0)

// =================================================================== gemm256
// 256x256 tile, BK=64, 8 waves (2M x 4N). (m-half x k-slot) quadrant schedule,
// 24 frag reads/tile, 12/20 MFMA rebalance. NOW 2 barriers/tile: the
// end-of-tile barrier is removed — every edge it ordered is covered by the
// next tile's R1b LGKM0+barrier (drains ALL outstanding DS reads incl. the
// prior tile's R3 other-buf reads, before any overwrite of that buffer) and
// the end-R2 VMCNT(4)+barrier (DMA visibility for R3's T+1 reads). The only
// cross-tile reg dependence (R3 MFMA reads a1f; next R1a overwrites) is an
// in-wave WAR the compiler enforces. Waves free-run across tile boundaries.
__device__ __forceinline__ void stage4(const char* src, char* dst, size_t Kb) {
#pragma unroll
  for (int j = 0; j < 4; ++j)
    gld_lds16(src + (size_t)(j * 64) * Kb, dst + j * 8192);
}

#define KTILE(T, BUF)                                                          \
  do {                                                                         \
    const char* aB_  = smem + (BUF) + arow;                                    \
    const char* bB_  = smem + 65536 + (BUF) + brow_o;                          \
    const char* aBn_ = smem + ((BUF) ^ 32768) + arow;                          \
    const char* bBn_ = smem + 65536 + ((BUF) ^ 32768) + brow_o;                \
    const bool nls = ((T) + 2 < nk);                                           \
    const bool nlr = ((T) + 1 < nk);                                           \
    /* R1a (4 reads, 12 MFMA): read a1; MFMA Q(mh0,k0) m=0..2 */               \
    _Pragma("unroll")                                                          \
    for (int m = 0; m < 4; ++m)                                                \
      a1f[m] = *(const bf16x8*)(aB_ + (m + 4) * 2048 + sw0);                   \
    SBAR();                                                                    \
    __builtin_amdgcn_s_setprio(1);                                             \
    _Pragma("unroll")                                                          \
    for (int m = 0; m < 3; ++m)                                                \
      _Pragma("unroll")                                                        \
      for (int n = 0; n < 4; ++n)                                              \
        acc[m][n] = MFMA16(a0f[m], b0f[n], acc[m][n]);                         \
    __builtin_amdgcn_s_setprio(0);                                             \
    SBAR();                                                                    \
    /* R1b (8 reads, 20 MFMA): deferred Q(mh0,k0) m=3; read a2->a0f, b1;       \
       MFMA Q(mh1,k0) */                                                       \
    __builtin_amdgcn_s_setprio(1);                                             \
    _Pragma("unroll")                                                          \
    for (int n = 0; n < 4; ++n)                                                \
      acc[3][n] = MFMA16(a0f[3], b0f[n], acc[3][n]);                           \
    __builtin_amdgcn_s_setprio(0);                                             \
    _Pragma("unroll")                                                          \
    for (int m = 0; m < 4; ++m)                                                \
      a0f[m] = *(const bf16x8*)(aB_ + m * 2048 + sw1);                         \
    _Pragma("unroll")                                                          \
    for (int n = 0; n < 4; ++n)                                                \
      b1f[n] = *(const bf16x8*)(bB_ + n * 2048 + sw1);                         \
    SBAR();                                                                    \
    __builtin_amdgcn_s_setprio(1);                                             \
    _Pragma("unroll")                                                          \
    for (int m = 0; m < 4; ++m)                                                \
      _Pragma("unroll")                                                        \
      for (int n = 0; n < 4; ++n)                                              \
        acc[m + 4][n] = MFMA16(a1f[m], b0f[n], acc[m + 4][n]);                 \
    __builtin_amdgcn_s_setprio(0);                                             \
    LGKM0();    /* ALL pending DS reads (incl. prev R3 other-buf) complete     \
                   before any wave's R2 B-stage */                             \
    BARRIER();                                                                 \
    /* R2 (4 reads, 12 MFMA): stage B(T+2); read a3; MFMA Q(mh0,k1) m=0..2;    \
       end: VMCNT drains A(T+1)+B(T+1) (cross-wave, barrier-backed) */         \
    if (nls) stage4(pB + (size_t)((T) + 2) * 128, sB + (BUF), Kb);             \
    _Pragma("unroll")                                                          \
    for (int m = 0; m < 4; ++m)                                                \
      a1f[m] = *(const bf16x8*)(aB_ + (m + 4) * 2048 + sw1);                   \
    SBAR();                                                                    \
    __builtin_amdgcn_s_setprio(1);                                             \
    _Pragma("unroll")                                                          \
    for (int m = 0; m < 3; ++m)                                                \
      _Pragma("unroll")                                                        \
      for (int n = 0; n < 4; ++n)                                              \
        acc[m][n] = MFMA16(a0f[m], b1f[n], acc[m][n]);                         \
    __builtin_amdgcn_s_setprio(0);                                             \
    if (nls)      { VMCNT(4); }                                                \
    else if (nlr) { VMCNT(0); }                                                \
    LGKM0();    /* a3 complete before any wave's R3 A-stage */                 \
    BARRIER();                                                                 \
    /* R3 (8 reads, 20 MFMA): deferred Q(mh0,k1) m=3; read a0',b0' (T+1 —      \
       DMAs barrier-backed complete); stage A(T+2); MFMA Q(mh1,k1).            \
       NO tile-end barrier: waves free-run into next tile's R1a. */            \
    __builtin_amdgcn_s_setprio(1);                                             \
    _Pragma("unroll")                                                          \
    for (int n = 0; n < 4; ++n)                                                \
      acc[3][n] = MFMA16(a0f[3], b1f[n], acc[3][n]);                           \
    __builtin_amdgcn_s_setprio(0);                                             \
    if (nlr) {                                                                 \
      _Pragma("unroll")                                                        \
      for (int m = 0; m < 4; ++m)                                              \
        a0f[m] = *(const bf16x8*)(aBn_ + m * 2048 + sw0);                      \
      _Pragma("unroll")                                                        \
      for (int n = 0; n < 4; ++n)                                              \
        b0f[n] = *(const bf16x8*)(bBn_ + n * 2048 + sw0);                      \
    }                                                                          \
    if (nls) stage4(pA + (size_t)((T) + 2) * 128, sA + (BUF), Kb);             \
    SBAR();                                                                    \
    __builtin_amdgcn_s_setprio(1);                                             \
    _Pragma("unroll")                                                          \
    for (int m = 0; m < 4; ++m)                                                \
      _Pragma("unroll")                                                        \
      for (int n = 0; n < 4; ++n)                                              \
        acc[m + 4][n] = MFMA16(a1f[m], b1f[n], acc[m + 4][n]);                 \
    __builtin_amdgcn_s_setprio(0);                                             \
    SBAR();                                                                    \
  } while (0)

__global__ __launch_bounds__(512, 2)
void gemm256(const uint16_t* __restrict__ A, const uint16_t* __restrict__ Bt,
             const float* __restrict__ bias, int biasN, int relu,
             uint16_t* __restrict__ C, int Kp, int ldc, int nbn)
{
  extern __shared__ char smem[];   // [A: 2buf x 4 x 64rows x 128B = 64K][B: same]
  const int tid = threadIdx.x;
  const int w = tid >> 6, lane = tid & 63;
  const int wr = w >> 2, wc = w & 3;
  const int fr = lane & 15, g = lane >> 4;

  // T1: bijective XCD swizzle
  const int nwg = (int)gridDim.x;
  const int id = (int)blockIdx.x;
  const int q = nwg >> 3, r = nwg & 7;
  const int xcd = id & 7, idx = id >> 3;
  const int wg = (xcd < r ? xcd * (q + 1) : r * (q + 1) + (xcd - r) * q) + idx;
  const int brow = (wg / nbn) * 256, bcol = (wg % nbn) * 256;

  const size_t Kb = (size_t)Kp * 2;

  // staging: thread tid -> LDS j*8192 + (tid>>3)*128 + (tid&7)*16 (lane*16 by HW)
  const int srow = tid >> 3;
  const int sswz = ((tid & 7) ^ (srow & 7)) * 16;
  const char* pA = (const char*)A + (size_t)(brow + srow) * Kb + sswz;
  const char* pB = (const char*)Bt + (size_t)(bcol + srow) * Kb + sswz;
  char* sA = smem + w * 1024;
  char* sB = smem + 65536 + w * 1024;

  // frag read: slot q=kk*4+g stored at q ^ (row&7), row&7 == fr&7
  const int sw0 = (g ^ (fr & 7)) * 16;
  const int sw1 = ((g + 4) ^ (fr & 7)) * 16;
  const int arow = (wr * 128 + fr) * 128;   // + m*2048
  const int brow_o = (wc * 64 + fr) * 128;  // + n*2048

  f32x4 acc[8][4];
#pragma unroll
  for (int m = 0; m < 8; ++m)
#pragma unroll
    for (int n = 0; n < 4; ++n) acc[m][n] = (f32x4){0.f, 0.f, 0.f, 0.f};
  bf16x8 a0f[4], a1f[4], b0f[4], b1f[4];

  // prologue: stage A(0),B(0),A(1),B(1); VMCNT(8) retires A(0),B(0)
  // (barrier-backed); preload a0,b0 of tile0
  stage4(pA, sA, Kb);
  stage4(pB, sB, Kb);
  stage4(pA + 128, sA + 32768, Kb);
  stage4(pB + 128, sB + 32768, Kb);
  VMCNT(8);
  BARRIER();
#pragma unroll
  for (int m = 0; m < 4; ++m)
    a0f[m] = *(const bf16x8*)(smem + arow + m * 2048 + sw0);
#pragma unroll
  for (int n = 0; n < 4; ++n)
    b0f[n] = *(const bf16x8*)(smem + 65536 + brow_o + n * 2048 + sw0);
  SBAR();

  const int nk = Kp >> 6;
  for (int t = 0; t < nk; t += 2) {
    KTILE(t, 0);
    if (t + 1 < nk) KTILE(t + 1, 32768);
  }

  // epilogue: C/D layout col=lane&15, row=(lane>>4)*4+j
#pragma unroll
  for (int m = 0; m < 8; ++m) {
    const int row = brow + wr * 128 + m * 16 + g * 4;
#pragma unroll
    for (int n = 0; n < 4; ++n) {
      const int col = bcol + wc * 64 + n * 16 + fr;
      const float bv = (col < biasN) ? bias[col] : 0.f;
#pragma unroll
      for (int j = 0; j < 4; ++j) {
        float v = acc[m][n][j] + bv;
        if (relu) v = fmaxf(v, 0.f);
        C[(size_t)(row + j) * ldc + col] = f2bf(v);
      }
    }
  }
}

// ---------------------------------------------------------------- GEMM (m97 structure, small N)
__global__ __launch_bounds__(256)
void gemm_bt(const uint16_t* __restrict__ A, const uint16_t* __restrict__ Bt,
             const float* __restrict__ bias, int biasN, int relu,
             uint16_t* __restrict__ C, int Kp, int ldc)
{
  __shared__ uint16_t As[128 * 32];
  __shared__ uint16_t Bs[128 * 32];
  const int tid  = threadIdx.x;
  const int wave = tid >> 6, lane = tid & 63;
  const int brow = blockIdx.x * 128, bcol = blockIdx.y * 128;
  const int wr = wave >> 1, wc = wave & 1;
  const int fr = lane & 15, g = lane >> 4;

  f32x4 acc[4][4];
#pragma unroll
  for (int m = 0; m < 4; ++m)
#pragma unroll
    for (int n = 0; n < 4; ++n) acc[m][n] = (f32x4){0.f, 0.f, 0.f, 0.f};

  const int rA = tid >> 2;
  const int kc = (tid & 3) * 8;
  const uint16_t* aptr = A  + (size_t)(brow + rA) * Kp + kc;
  const uint16_t* bptr = Bt + (size_t)(bcol + rA) * Kp + kc;
  char* ldsA = (char*)As + wave * 1024;
  char* ldsB = (char*)Bs + wave * 1024;
  const size_t rowskip = (size_t)64 * Kp;

  const int nk = Kp >> 5;
  for (int kt = 0; kt < nk; ++kt) {
    __syncthreads();
    gld_lds16(aptr,           ldsA);
    gld_lds16(aptr + rowskip, ldsA + 4096);
    gld_lds16(bptr,           ldsB);
    gld_lds16(bptr + rowskip, ldsB + 4096);
    aptr += 32; bptr += 32;
    __syncthreads();

    bf16x8 af[4], bfr[4];
#pragma unroll
    for (int m = 0; m < 4; ++m)
      af[m] = *(const bf16x8*)&As[(wr * 64 + m * 16 + fr) * 32 + g * 8];
#pragma unroll
    for (int n = 0; n < 4; ++n)
      bfr[n] = *(const bf16x8*)&Bs[(wc * 64 + n * 16 + fr) * 32 + g * 8];
#pragma unroll
    for (int m = 0; m < 4; ++m)
#pragma unroll
      for (int n = 0; n < 4; ++n)
        acc[m][n] = MFMA16(af[m], bfr[n], acc[m][n]);
  }

#pragma unroll
  for (int m = 0; m < 4; ++m) {
    const int row = brow + wr * 64 + m * 16 + g * 4;
#pragma unroll
    for (int n = 0; n < 4; ++n) {
      const int col = bcol + wc * 64 + n * 16 + fr;
      const float bv = (col < biasN) ? bias[col] : 0.f;
#pragma unroll
      for (int j = 0; j < 4; ++j) {
        float v = acc[m][n][j] + bv;
        if (relu) v = fmaxf(v, 0.f);
        C[(size_t)(row + j) * ldc + col] = f2bf(v);
      }
    }
  }
}

// ---------------------------------------------------------------- conversions
__global__ __launch_bounds__(256)
void cvt_pad(const float* __restrict__ in, uint16_t* __restrict__ out, int cols, int colsPad)
{
  const int r = blockIdx.y;
  const int c = (blockIdx.x * 256 + threadIdx.x) * 2;
  if (c >= colsPad) return;
  const float* ip = in + (size_t)r * cols;
  const float v0 = (c < cols)     ? ip[c]     : 0.f;
  const float v1 = (c + 1 < cols) ? ip[c + 1] : 0.f;
  const uint32_t pk = (uint32_t)f2bf(v0) | ((uint32_t)f2bf(v1) << 16);
  *(uint32_t*)(out + (size_t)r * colsPad + c) = pk;
}

__global__ __launch_bounds__(256)
void transpose_w(const float* __restrict__ W, uint16_t* __restrict__ Wt,
                 int K, int N, int Kp, int Np)
{
  __shared__ float t[32][33];
  const int tx = threadIdx.x, ty = threadIdx.y;
  const int k0 = blockIdx.x * 32, n0 = blockIdx.y * 32;
#pragma unroll
  for (int j = 0; j < 4; ++j) {
    const int k = k0 + ty + j * 8, n = n0 + tx;
    t[ty + j * 8][tx] = (k < K && n < N) ? W[(size_t)k * N + n] : 0.f;
  }
  __syncthreads();
#pragma unroll
  for (int j = 0; j < 4; ++j) {
    const int n = n0 + ty + j * 8, k = k0 + tx;
    Wt[(size_t)n * Kp + k] = f2bf(t[tx][ty + j * 8]);
  }
}

__global__ void concat_bias(const float* __restrict__ bl, const float* __restrict__ br,
                            float* __restrict__ out)
{
  const int i = blockIdx.x * 256 + threadIdx.x;
  if (i < 1536) out[i] = bl[i];
  else if (i < 3072) out[i] = br[i - 1536];
}

// ---------------------------------------------------------------- CSR build
__global__ void count_deg(const int* __restrict__ ei, int* __restrict__ counts)
{
  const int e = blockIdx.x * 256 + threadIdx.x;
  if (e >= ET) return;
  const int d = (e < NE) ? ei[NE + e] : (e - NE);
  atomicAdd(&counts[d], 1);
}

__global__ __launch_bounds__(1024)
void scan_deg(const int* __restrict__ counts, int* __restrict__ row_start, int* __restrict__ cursor)
{
  __shared__ int part[1024];
  const int tid = threadIdx.x;
  int loc[8], pre[8], s = 0;
#pragma unroll
  for (int j = 0; j < 8; ++j) { loc[j] = counts[tid * 8 + j]; pre[j] = s; s += loc[j]; }
  part[tid] = s;
  __syncthreads();
  for (int o = 1; o < 1024; o <<= 1) {
    const int v = part[tid];
    const int a = (tid >= o) ? part[tid - o] : 0;
    __syncthreads();
    part[tid] = v + a;
    __syncthreads();
  }
  const int excl = part[tid] - s;
#pragma unroll
  for (int j = 0; j < 8; ++j) {
    const int v = excl + pre[j];
    row_start[tid * 8 + j] = v;
    cursor[tid * 8 + j]    = v;
  }
  if (tid == 1023) row_start[8192] = excl + s;
}

__global__ void scatter_e(const int* __restrict__ ei, int* __restrict__ cursor,
                          int* __restrict__ csr_src, int* __restrict__ csr_dst)
{
  const int e = blockIdx.x * 256 + threadIdx.x;
  if (e >= ET) return;
  const int sx = (e < NE) ? ei[e]      : (e - NE);
  const int d  = (e < NE) ? ei[NE + e] : (e - NE);
  const int pos = atomicAdd(&cursor[d], 1);
  csr_src[pos] = sx;
  csr_dst[pos] = d;
}

// ---------------------------------------------------------------- GATv2 fused attention
// One wave per node. Single pass over the node's edges: read xl[src] row once
// (3 bf16x8/lane), compute logit (shuffle reduce, wave-uniform), online-softmax
// rescale a 24-f32/lane accumulator. out[i] = relu(acc/z + ob).
__global__ __launch_bounds__(256)
void gat_fused(const uint16_t* __restrict__ xlr, int ld,
               const int* __restrict__ csr_src, const int* __restrict__ row_start,
               const float* __restrict__ att, const float* __restrict__ ob,
               uint16_t* __restrict__ out, int ldc)
{
  const int node = (blockIdx.x << 2) + (threadIdx.x >> 6);
  const int lane = threadIdx.x & 63;

  float av[3][8], xr[3][8];
  const bf16x8* pr = (const bf16x8*)(xlr + (size_t)node * ld + 1536);
#pragma unroll
  for (int h = 0; h < 3; ++h) {
    const float4 a0 = *(const float4*)(att + h * 512 + lane * 8);
    const float4 a1 = *(const float4*)(att + h * 512 + lane * 8 + 4);
    av[h][0] = a0.x; av[h][1] = a0.y; av[h][2] = a0.z; av[h][3] = a0.w;
    av[h][4] = a1.x; av[h][5] = a1.y; av[h][6] = a1.z; av[h][7] = a1.w;
    const bf16x8 v = pr[h * 64 + lane];
#pragma unroll
    for (int j = 0; j < 8; ++j) xr[h][j] = bf2f((uint16_t)v[j]);
  }

  float m[3] = {-1e30f, -1e30f, -1e30f};
  float z[3] = {0.f, 0.f, 0.f};
  float acc[3][8];
#pragma unroll
  for (int h = 0; h < 3; ++h)
#pragma unroll
    for (int j = 0; j < 8; ++j) acc[h][j] = 0.f;

  const int s0 = row_start[node], s1 = row_start[node + 1];
  for (int s = s0; s < s1; ++s) {
    const bf16x8* pl = (const bf16x8*)(xlr + (size_t)csr_src[s] * ld);
    bf16x8 vl[3];
#pragma unroll
    for (int h = 0; h < 3; ++h) vl[h] = pl[h * 64 + lane];

    float hacc[3];
#pragma unroll
    for (int h = 0; h < 3; ++h) {
      float sacc = 0.f;
#pragma unroll
      for (int j = 0; j < 8; ++j) {
        float v = bf2f((uint16_t)vl[h][j]) + xr[h][j];
        v = v > 0.f ? v : 0.2f * v;
        sacc += v * av[h][j];
      }
      hacc[h] = sacc;
    }
#pragma unroll
    for (int o = 32; o; o >>= 1) {
      hacc[0] += __shfl_xor(hacc[0], o);
      hacc[1] += __shfl_xor(hacc[1], o);
      hacc[2] += __shfl_xor(hacc[2], o);
    }
    // online softmax update (wave-uniform scale/p)
#pragma unroll
    for (int h = 0; h < 3; ++h) {
      const float nm = fmaxf(m[h], hacc[h]);
      const float sc = __expf(m[h] - nm);
      const float p  = __expf(hacc[h] - nm);
      z[h] = z[h] * sc + p;
#pragma unroll
      for (int j = 0; j < 8; ++j)
        acc[h][j] = acc[h][j] * sc + p * bf2f((uint16_t)vl[h][j]);
      m[h] = nm;
    }
  }

#pragma unroll
  for (int h = 0; h < 3; ++h) {
    const float rz = 1.f / z[h];
    const float4 b0 = *(const float4*)(ob + h * 512 + lane * 8);
    const float4 b1 = *(const float4*)(ob + h * 512 + lane * 8 + 4);
    float bv[8] = {b0.x, b0.y, b0.z, b0.w, b1.x, b1.y, b1.z, b1.w};
    bf16x8 pk;
#pragma unroll
    for (int j = 0; j < 8; ++j) {
      const float v = fmaxf(acc[h][j] * rz + bv[j], 0.f);
      pk[j] = (short)f2bf(v);
    }
    *(bf16x8*)(out + (size_t)node * ldc + h * 512 + lane * 8) = pk;
  }
}

// ---------------------------------------------------------------- final dot
__global__ __launch_bounds__(256)
void final_dot(const uint16_t* __restrict__ z2, const float* __restrict__ w,
               const float* __restrict__ b, float* __restrict__ out)
{
  const int row  = blockIdx.x * 4 + (threadIdx.x >> 6);
  const int lane = threadIdx.x & 63;
  const uint16_t* p = z2 + (size_t)row * 512;
  float s = 0.f;
#pragma unroll
  for (int j = 0; j < 8; ++j) { const int c = lane + j * 64; s += bf2f(p[c]) * w[c]; }
#pragma unroll
  for (int o = 32; o; o >>= 1) s += __shfl_xor(s, o);
  if (lane == 0) out[row] = s + b[0];
}

// ---------------------------------------------------------------- orchestration
extern "C" void kernel_launch(void* const* d_in, const int* in_sizes, int n_in,
                              void* d_out, int out_size, void* d_ws, size_t ws_size,
                              hipStream_t stream)
{
  (void)in_sizes; (void)n_in; (void)out_size; (void)ws_size;

  const float* x    = (const float*)d_in[0];
  const int*   ei   = (const int*)  d_in[1];
  const float* expm = (const float*)d_in[2];
  const float* w1l = (const float*)d_in[3];  const float* b1l = (const float*)d_in[4];
  const float* w1r = (const float*)d_in[5];  const float* b1r = (const float*)d_in[6];
  const float* a1  = (const float*)d_in[7];  const float* o1  = (const float*)d_in[8];
  const float* w2l = (const float*)d_in[9];  const float* b2l = (const float*)d_in[10];
  const float* w2r = (const float*)d_in[11]; const float* b2r = (const float*)d_in[12];
  const float* a2  = (const float*)d_in[13]; const float* o2  = (const float*)d_in[14];
  const float* w3l = (const float*)d_in[15]; const float* b3l = (const float*)d_in[16];
  const float* w3r = (const float*)d_in[17]; const float* b3r = (const float*)d_in[18];
  const float* a3  = (const float*)d_in[19]; const float* o3  = (const float*)d_in[20];
  const float* e1w = (const float*)d_in[21]; const float* e1b = (const float*)d_in[22];
  const float* e2w = (const float*)d_in[23]; const float* e2b = (const float*)d_in[24];
  const float* e3w = (const float*)d_in[25]; const float* e3b = (const float*)d_in[26];
  const float* l1w = (const float*)d_in[27]; const float* l1b = (const float*)d_in[28];
  const float* l2w = (const float*)d_in[29]; const float* l2b = (const float*)d_in[30];
  const float* l3w = (const float*)d_in[31]; const float* l3b = (const float*)d_in[32];
  float* out = (float*)d_out;

  hipFuncSetAttribute((const void*)gemm256, hipFuncAttributeMaxDynamicSharedMemorySize, 131072);

  char* ws = (char*)d_ws;
  size_t off = 0;
  auto take = [&](size_t b) { char* p = ws + off; off += (b + 255) & ~(size_t)255; return p; };

  int*      counts    = (int*)take((size_t)NN * 4);
  int*      row_start = (int*)take((size_t)(NN + 1) * 4);
  int*      cursor    = (int*)take((size_t)NN * 4);
  int*      csr_src   = (int*)take((size_t)ET * 4);
  int*      csr_dst   = (int*)take((size_t)ET * 4);
  float*    bc1       = (float*)take(3072 * 4);
  float*    bc2       = (float*)take(3072 * 4);
  float*    bc3       = (float*)take(3072 * 4);
  uint16_t* zbuf      = (uint16_t*)take((size_t)NN * 2048 * 2);
  char*     regA      = take((size_t)NN * F_EXP_P * 2);
  char*     regW      = take((size_t)4096 * F_EXP_P * 2);
  char*     regC      = take((size_t)NN * 4096 * 2 + (size_t)NN * 1536 * 2);

  uint16_t* xbf   = (uint16_t*)regA;
  uint16_t* expbf = (uint16_t*)regA;
  uint16_t* wT    = (uint16_t*)regW;
  // phase 1: xlr [8192][3072] + hbuf [8192][1536]
  uint16_t* xlr   = (uint16_t*)regC;
  uint16_t* hbuf  = (uint16_t*)(regC + (size_t)NN * 3072 * 2);
  // phase 2 (encoder): cell1 [8192][4096] | cell2 [8192][1536]
  uint16_t* cell1 = (uint16_t*)regC;
  uint16_t* cell2 = (uint16_t*)(regC + (size_t)NN * 4096 * 2);
  // phase 3 (head): zz1 [8192][1024] | zz2 [8192][512]
  uint16_t* zz1   = (uint16_t*)regC;
  uint16_t* zz2   = (uint16_t*)(regC + (size_t)NN * 1024 * 2);

  // ---- CSR + fused biases
  hipMemsetAsync(counts, 0, (size_t)NN * 4, stream);
  count_deg<<<(ET + 255) / 256, 256, 0, stream>>>(ei, counts);
  scan_deg<<<1, 1024, 0, stream>>>(counts, row_start, cursor);
  scatter_e<<<(ET + 255) / 256, 256, 0, stream>>>(ei, cursor, csr_src, csr_dst);
  concat_bias<<<12, 256, 0, stream>>>(b1l, b1r, bc1);
  concat_bias<<<12, 256, 0, stream>>>(b2l, b2r, bc2);
  concat_bias<<<12, 256, 0, stream>>>(b3l, b3r, bc3);

  // ---- GAT layer 1 (Kp = 3264), fused l|r GEMM -> xlr
  cvt_pad<<<dim3((F_IN_P / 2 + 255) / 256, NN), 256, 0, stream>>>(x, xbf, F_IN, F_IN_P);
  transpose_w<<<dim3(F_IN_P / 32, 1536 / 32), dim3(32, 8), 0, stream>>>(w1l, wT, F_IN, 1536, F_IN_P, 1536);
  transpose_w<<<dim3(F_IN_P / 32, 1536 / 32), dim3(32, 8), 0, stream>>>(w1r, wT + (size_t)1536 * F_IN_P, F_IN, 1536, F_IN_P, 1536);
  gemm256<<<32 * 12, 512, 131072, stream>>>(xbf, wT, bc1, 3072, 0, xlr, F_IN_P, 3072, 12);
  gat_fused<<<NN / 4, 256, 0, stream>>>(xlr, 3072, csr_src, row_start, a1, o1, hbuf, 1536);

  // ---- GAT layer 2 (K = 1536)
  transpose_w<<<dim3(48, 48), dim3(32, 8), 0, stream>>>(w2l, wT, 1536, 1536, 1536, 1536);
  transpose_w<<<dim3(48, 48), dim3(32, 8), 0, stream>>>(w2r, wT + (size_t)1536 * 1536, 1536, 1536, 1536, 1536);
  gemm256<<<32 * 12, 512, 131072, stream>>>(hbuf, wT, bc2, 3072, 0, xlr, 1536, 3072, 12);
  gat_fused<<<NN / 4, 256, 0, stream>>>(xlr, 3072, csr_src, row_start, a2, o2, hbuf, 1536);

  // ---- GAT layer 3 -> zbuf cols [0,1536)
  transpose_w<<<dim3(48, 48), dim3(32, 8), 0, stream>>>(w3l, wT, 1536, 1536, 1536, 1536);
  transpose_w<<<dim3(48, 48), dim3(32, 8), 0, stream>>>(w3r, wT + (size_t)1536 * 1536, 1536, 1536, 1536, 1536);
  gemm256<<<32 * 12, 512, 131072, stream>>>(hbuf, wT, bc3, 3072, 0, xlr, 1536, 3072, 12);
  gat_fused<<<NN / 4, 256, 0, stream>>>(xlr, 3072, csr_src, row_start, a3, o3, zbuf, 2048);

  // ---- encoder: 7993 -> 4000 -> 1500 -> 512 (last into zbuf cols [1536,2048))
  cvt_pad<<<dim3((F_EXP_P / 2 + 255) / 256, NN), 256, 0, stream>>>(expm, expbf, F_EXP, F_EXP_P);
  transpose_w<<<dim3(F_EXP_P / 32, 4096 / 32), dim3(32, 8), 0, stream>>>(e1w, wT, F_EXP, 4000, F_EXP_P, 4096);
  gemm256<<<32 * 16, 512, 131072, stream>>>(expbf, wT, e1b, 4000, 1, cell1, F_EXP_P, 4096, 16);
  transpose_w<<<dim3(4096 / 32, 1536 / 32), dim3(32, 8), 0, stream>>>(e2w, wT, 4000, 1500, 4096, 1536);
  gemm256<<<32 * 6, 512, 131072, stream>>>(cell1, wT, e2b, 1500, 1, cell2, 4096, 1536, 6);
  transpose_w<<<dim3(1536 / 32, 512 / 32), dim3(32, 8), 0, stream>>>(e3w, wT, 1500, 512, 1536, 512);
  gemm_bt<<<dim3(64, 4), 256, 0, stream>>>(cell2, wT, e3b, 512, 0, zbuf + 1536, 1536, 2048);

  // ---- head
  transpose_w<<<dim3(2048 / 32, 1024 / 32), dim3(32, 8), 0, stream>>>(l1w, wT, 2048, 1024, 2048, 1024);
  gemm_bt<<<dim3(64, 8), 256, 0, stream>>>(zbuf, wT, l1b, 1024, 1, zz1, 2048, 1024);
  transpose_w<<<dim3(1024 / 32, 512 / 32), dim3(32, 8), 0, stream>>>(l2w, wT, 1024, 512, 1024, 512);
  gemm_bt<<<dim3(64, 4), 256, 0, stream>>>(zz1, wT, l2b, 512, 1, zz2, 1024, 512);
  final_dot<<<NN / 4, 256, 0, stream>>>(zz2, l3w, l3b, out);
}

// Round 17
// 1379.605 us; speedup vs baseline: 1.2314x; 1.0315x over previous
//
#include <hip/hip_runtime.h>
#include <stdint.h>

#define NN 8192
#define NE 65536
#define ET (NE + NN)
#define F_IN   3247
#define F_IN_P 3264
#define F_EXP   7993
#define F_EXP_P 8000

typedef __attribute__((ext_vector_type(8))) short bf16x8;
typedef __attribute__((ext_vector_type(4))) float f32x4;

typedef const __attribute__((address_space(1))) void gvoid_t;
typedef __attribute__((address_space(3))) void lvoid_t;

__device__ __forceinline__ float bf2f(uint16_t u) {
  union { uint32_t i; float f; } v; v.i = ((uint32_t)u) << 16; return v.f;
}
__device__ __forceinline__ uint16_t f2bf(float f) {
  union { float f; uint32_t i; } v; v.f = f;
  uint32_t r = v.i + 0x7fffu + ((v.i >> 16) & 1u);  // RNE
  return (uint16_t)(r >> 16);
}

__device__ __forceinline__ void gld_lds16(const void* g, void* l) {
  __builtin_amdgcn_global_load_lds((gvoid_t*)g, (lvoid_t*)l, 16, 0, 0);
}

#define SBAR() __builtin_amdgcn_sched_barrier(0)
#define BARRIER() do { SBAR(); __builtin_amdgcn_s_barrier(); SBAR(); } while (0)
#define LGKM0() do { asm volatile("s_waitcnt lgkmcnt(0)" ::: "memory"); SBAR(); } while (0)
#define VMCNT(n) asm volatile("s_waitcnt vmcnt(" #n ")" ::: "memory")
#define MFMA16(a, b, c) __builtin_amdgcn_mfma_f32_16x16x32_bf16(a, b, c, 0, 0, 0)

// =================================================================== gemm256
// 256x256 tile, BK=64, 8 waves (2M x 4N). (m-half x k-slot) quadrant schedule,
// 24 frag reads/tile, 12/20 MFMA rebalance, 2 barriers/tile (R16-verified):
// tile-end barrier removed — edges covered by next tile's R1b LGKM0+barrier
// and end-R2 VMCNT(4)+barrier. Waves free-run across tile boundaries.
__device__ __forceinline__ void stage4(const char* src, char* dst, size_t Kb) {
#pragma unroll
  for (int j = 0; j < 4; ++j)
    gld_lds16(src + (size_t)(j * 64) * Kb, dst + j * 8192);
}

#define KTILE(T, BUF)                                                          \
  do {                                                                         \
    const char* aB_  = smem + (BUF) + arow;                                    \
    const char* bB_  = smem + 65536 + (BUF) + brow_o;                          \
    const char* aBn_ = smem + ((BUF) ^ 32768) + arow;                          \
    const char* bBn_ = smem + 65536 + ((BUF) ^ 32768) + brow_o;                \
    const bool nls = ((T) + 2 < nk);                                           \
    const bool nlr = ((T) + 1 < nk);                                           \
    /* R1a (4 reads, 12 MFMA): read a1; MFMA Q(mh0,k0) m=0..2 */               \
    _Pragma("unroll")                                                          \
    for (int m = 0; m < 4; ++m)                                                \
      a1f[m] = *(const bf16x8*)(aB_ + (m + 4) * 2048 + sw0);                   \
    SBAR();                                                                    \
    __builtin_amdgcn_s_setprio(1);                                             \
    _Pragma("unroll")                                                          \
    for (int m = 0; m < 3; ++m)                                                \
      _Pragma("unroll")                                                        \
      for (int n = 0; n < 4; ++n)                                              \
        acc[m][n] = MFMA16(a0f[m], b0f[n], acc[m][n]);                         \
    __builtin_amdgcn_s_setprio(0);                                             \
    SBAR();                                                                    \
    /* R1b (8 reads, 20 MFMA): deferred Q(mh0,k0) m=3; read a2->a0f, b1;       \
       MFMA Q(mh1,k0) */                                                       \
    __builtin_amdgcn_s_setprio(1);                                             \
    _Pragma("unroll")                                                          \
    for (int n = 0; n < 4; ++n)                                                \
      acc[3][n] = MFMA16(a0f[3], b0f[n], acc[3][n]);                           \
    __builtin_amdgcn_s_setprio(0);                                             \
    _Pragma("unroll")                                                          \
    for (int m = 0; m < 4; ++m)                                                \
      a0f[m] = *(const bf16x8*)(aB_ + m * 2048 + sw1);                         \
    _Pragma("unroll")                                                          \
    for (int n = 0; n < 4; ++n)                                                \
      b1f[n] = *(const bf16x8*)(bB_ + n * 2048 + sw1);                         \
    SBAR();                                                                    \
    __builtin_amdgcn_s_setprio(1);                                             \
    _Pragma("unroll")                                                          \
    for (int m = 0; m < 4; ++m)                                                \
      _Pragma("unroll")                                                        \
      for (int n = 0; n < 4; ++n)                                              \
        acc[m + 4][n] = MFMA16(a1f[m], b0f[n], acc[m + 4][n]);                 \
    __builtin_amdgcn_s_setprio(0);                                             \
    LGKM0();    /* ALL pending DS reads (incl. prev R3 other-buf) complete     \
                   before any wave's R2 B-stage */                             \
    BARRIER();                                                                 \
    /* R2 (4 reads, 12 MFMA): stage B(T+2); read a3; MFMA Q(mh0,k1) m=0..2;    \
       end: VMCNT drains A(T+1)+B(T+1) (cross-wave, barrier-backed) */         \
    if (nls) stage4(pB + (size_t)((T) + 2) * 128, sB + (BUF), Kb);             \
    _Pragma("unroll")                                                          \
    for (int m = 0; m < 4; ++m)                                                \
      a1f[m] = *(const bf16x8*)(aB_ + (m + 4) * 2048 + sw1);                   \
    SBAR();                                                                    \
    __builtin_amdgcn_s_setprio(1);                                             \
    _Pragma("unroll")                                                          \
    for (int m = 0; m < 3; ++m)                                                \
      _Pragma("unroll")                                                        \
      for (int n = 0; n < 4; ++n)                                              \
        acc[m][n] = MFMA16(a0f[m], b1f[n], acc[m][n]);                         \
    __builtin_amdgcn_s_setprio(0);                                             \
    if (nls)      { VMCNT(4); }                                                \
    else if (nlr) { VMCNT(0); }                                                \
    LGKM0();    /* a3 complete before any wave's R3 A-stage */                 \
    BARRIER();                                                                 \
    /* R3 (8 reads, 20 MFMA): deferred Q(mh0,k1) m=3; read a0',b0' (T+1 —      \
       DMAs barrier-backed complete); stage A(T+2); MFMA Q(mh1,k1).            \
       NO tile-end barrier: waves free-run into next tile's R1a. */            \
    __builtin_amdgcn_s_setprio(1);                                             \
    _Pragma("unroll")                                                          \
    for (int n = 0; n < 4; ++n)                                                \
      acc[3][n] = MFMA16(a0f[3], b1f[n], acc[3][n]);                           \
    __builtin_amdgcn_s_setprio(0);                                             \
    if (nlr) {                                                                 \
      _Pragma("unroll")                                                        \
      for (int m = 0; m < 4; ++m)                                              \
        a0f[m] = *(const bf16x8*)(aBn_ + m * 2048 + sw0);                      \
      _Pragma("unroll")                                                        \
      for (int n = 0; n < 4; ++n)                                              \
        b0f[n] = *(const bf16x8*)(bBn_ + n * 2048 + sw0);                      \
    }                                                                          \
    if (nls) stage4(pA + (size_t)((T) + 2) * 128, sA + (BUF), Kb);             \
    SBAR();                                                                    \
    __builtin_amdgcn_s_setprio(1);                                             \
    _Pragma("unroll")                                                          \
    for (int m = 0; m < 4; ++m)                                                \
      _Pragma("unroll")                                                        \
      for (int n = 0; n < 4; ++n)                                              \
        acc[m + 4][n] = MFMA16(a1f[m], b1f[n], acc[m + 4][n]);                 \
    __builtin_amdgcn_s_setprio(0);                                             \
    SBAR();                                                                    \
  } while (0)

__global__ __launch_bounds__(512, 2)
void gemm256(const uint16_t* __restrict__ A, const uint16_t* __restrict__ Bt,
             const float* __restrict__ bias, int biasN, int relu,
             uint16_t* __restrict__ C, int Kp, int ldc, int nbn)
{
  extern __shared__ char smem[];   // [A: 2buf x 4 x 64rows x 128B = 64K][B: same]
  const int tid = threadIdx.x;
  const int w = tid >> 6, lane = tid & 63;
  const int wr = w >> 2, wc = w & 3;
  const int fr = lane & 15, g = lane >> 4;

  // T1: bijective XCD swizzle
  const int nwg = (int)gridDim.x;
  const int id = (int)blockIdx.x;
  const int q = nwg >> 3, r = nwg & 7;
  const int xcd = id & 7, idx = id >> 3;
  const int wg = (xcd < r ? xcd * (q + 1) : r * (q + 1) + (xcd - r) * q) + idx;
  const int brow = (wg / nbn) * 256, bcol = (wg % nbn) * 256;

  const size_t Kb = (size_t)Kp * 2;

  // staging: thread tid -> LDS j*8192 + (tid>>3)*128 + (tid&7)*16 (lane*16 by HW)
  const int srow = tid >> 3;
  const int sswz = ((tid & 7) ^ (srow & 7)) * 16;
  const char* pA = (const char*)A + (size_t)(brow + srow) * Kb + sswz;
  const char* pB = (const char*)Bt + (size_t)(bcol + srow) * Kb + sswz;
  char* sA = smem + w * 1024;
  char* sB = smem + 65536 + w * 1024;

  // frag read: slot q=kk*4+g stored at q ^ (row&7), row&7 == fr&7
  const int sw0 = (g ^ (fr & 7)) * 16;
  const int sw1 = ((g + 4) ^ (fr & 7)) * 16;
  const int arow = (wr * 128 + fr) * 128;   // + m*2048
  const int brow_o = (wc * 64 + fr) * 128;  // + n*2048

  f32x4 acc[8][4];
#pragma unroll
  for (int m = 0; m < 8; ++m)
#pragma unroll
    for (int n = 0; n < 4; ++n) acc[m][n] = (f32x4){0.f, 0.f, 0.f, 0.f};
  bf16x8 a0f[4], a1f[4], b0f[4], b1f[4];

  // prologue: stage A(0),B(0),A(1),B(1); VMCNT(8) retires A(0),B(0)
  // (barrier-backed); preload a0,b0 of tile0
  stage4(pA, sA, Kb);
  stage4(pB, sB, Kb);
  stage4(pA + 128, sA + 32768, Kb);
  stage4(pB + 128, sB + 32768, Kb);
  VMCNT(8);
  BARRIER();
#pragma unroll
  for (int m = 0; m < 4; ++m)
    a0f[m] = *(const bf16x8*)(smem + arow + m * 2048 + sw0);
#pragma unroll
  for (int n = 0; n < 4; ++n)
    b0f[n] = *(const bf16x8*)(smem + 65536 + brow_o + n * 2048 + sw0);
  SBAR();

  const int nk = Kp >> 6;
  for (int t = 0; t < nk; t += 2) {
    KTILE(t, 0);
    if (t + 1 < nk) KTILE(t + 1, 32768);
  }

  // epilogue: C/D layout col=lane&15, row=(lane>>4)*4+j
#pragma unroll
  for (int m = 0; m < 8; ++m) {
    const int row = brow + wr * 128 + m * 16 + g * 4;
#pragma unroll
    for (int n = 0; n < 4; ++n) {
      const int col = bcol + wc * 64 + n * 16 + fr;
      const float bv = (col < biasN) ? bias[col] : 0.f;
#pragma unroll
      for (int j = 0; j < 4; ++j) {
        float v = acc[m][n][j] + bv;
        if (relu) v = fmaxf(v, 0.f);
        C[(size_t)(row + j) * ldc + col] = f2bf(v);
      }
    }
  }
}

// ---------------------------------------------------------------- GEMM (m97 structure, small N)
__global__ __launch_bounds__(256)
void gemm_bt(const uint16_t* __restrict__ A, const uint16_t* __restrict__ Bt,
             const float* __restrict__ bias, int biasN, int relu,
             uint16_t* __restrict__ C, int Kp, int ldc)
{
  __shared__ uint16_t As[128 * 32];
  __shared__ uint16_t Bs[128 * 32];
  const int tid  = threadIdx.x;
  const int wave = tid >> 6, lane = tid & 63;
  const int brow = blockIdx.x * 128, bcol = blockIdx.y * 128;
  const int wr = wave >> 1, wc = wave & 1;
  const int fr = lane & 15, g = lane >> 4;

  f32x4 acc[4][4];
#pragma unroll
  for (int m = 0; m < 4; ++m)
#pragma unroll
    for (int n = 0; n < 4; ++n) acc[m][n] = (f32x4){0.f, 0.f, 0.f, 0.f};

  const int rA = tid >> 2;
  const int kc = (tid & 3) * 8;
  const uint16_t* aptr = A  + (size_t)(brow + rA) * Kp + kc;
  const uint16_t* bptr = Bt + (size_t)(bcol + rA) * Kp + kc;
  char* ldsA = (char*)As + wave * 1024;
  char* ldsB = (char*)Bs + wave * 1024;
  const size_t rowskip = (size_t)64 * Kp;

  const int nk = Kp >> 5;
  for (int kt = 0; kt < nk; ++kt) {
    __syncthreads();
    gld_lds16(aptr,           ldsA);
    gld_lds16(aptr + rowskip, ldsA + 4096);
    gld_lds16(bptr,           ldsB);
    gld_lds16(bptr + rowskip, ldsB + 4096);
    aptr += 32; bptr += 32;
    __syncthreads();

    bf16x8 af[4], bfr[4];
#pragma unroll
    for (int m = 0; m < 4; ++m)
      af[m] = *(const bf16x8*)&As[(wr * 64 + m * 16 + fr) * 32 + g * 8];
#pragma unroll
    for (int n = 0; n < 4; ++n)
      bfr[n] = *(const bf16x8*)&Bs[(wc * 64 + n * 16 + fr) * 32 + g * 8];
#pragma unroll
    for (int m = 0; m < 4; ++m)
#pragma unroll
      for (int n = 0; n < 4; ++n)
        acc[m][n] = MFMA16(af[m], bfr[n], acc[m][n]);
  }

#pragma unroll
  for (int m = 0; m < 4; ++m) {
    const int row = brow + wr * 64 + m * 16 + g * 4;
#pragma unroll
    for (int n = 0; n < 4; ++n) {
      const int col = bcol + wc * 64 + n * 16 + fr;
      const float bv = (col < biasN) ? bias[col] : 0.f;
#pragma unroll
      for (int j = 0; j < 4; ++j) {
        float v = acc[m][n][j] + bv;
        if (relu) v = fmaxf(v, 0.f);
        C[(size_t)(row + j) * ldc + col] = f2bf(v);
      }
    }
  }
}

// ---------------------------------------------------------------- conversions
// G13: 8 cols/thread, 2x float4 loads + one bf16x8 store; scalar-guard tail.
__global__ __launch_bounds__(256)
void cvt_pad8(const float* __restrict__ in, uint16_t* __restrict__ out, int cols, int colsPad)
{
  const int r = blockIdx.y;
  const int c = (blockIdx.x * 256 + threadIdx.x) * 8;
  if (c >= colsPad) return;
  const float* ip = in + (size_t)r * cols;
  uint16_t* op = out + (size_t)r * colsPad + c;
  bf16x8 pk;
  if (c + 8 <= cols) {
    const float4 v0 = *(const float4*)(ip + c);
    const float4 v1 = *(const float4*)(ip + c + 4);
    pk[0] = (short)f2bf(v0.x); pk[1] = (short)f2bf(v0.y);
    pk[2] = (short)f2bf(v0.z); pk[3] = (short)f2bf(v0.w);
    pk[4] = (short)f2bf(v1.x); pk[5] = (short)f2bf(v1.y);
    pk[6] = (short)f2bf(v1.z); pk[7] = (short)f2bf(v1.w);
  } else {
#pragma unroll
    for (int j = 0; j < 8; ++j)
      pk[j] = (short)((c + j < cols) ? f2bf(ip[c + j]) : (uint16_t)0);
  }
  *(bf16x8*)op = pk;
}

__global__ __launch_bounds__(256)
void transpose_w(const float* __restrict__ W, uint16_t* __restrict__ Wt,
                 int K, int N, int Kp, int Np)
{
  __shared__ float t[32][33];
  const int tx = threadIdx.x, ty = threadIdx.y;
  const int k0 = blockIdx.x * 32, n0 = blockIdx.y * 32;
#pragma unroll
  for (int j = 0; j < 4; ++j) {
    const int k = k0 + ty + j * 8, n = n0 + tx;
    t[ty + j * 8][tx] = (k < K && n < N) ? W[(size_t)k * N + n] : 0.f;
  }
  __syncthreads();
#pragma unroll
  for (int j = 0; j < 4; ++j) {
    const int n = n0 + ty + j * 8, k = k0 + tx;
    Wt[(size_t)n * Kp + k] = f2bf(t[tx][ty + j * 8]);
  }
}

__global__ void concat_bias3(const float* __restrict__ b1l, const float* __restrict__ b1r,
                             const float* __restrict__ b2l, const float* __restrict__ b2r,
                             const float* __restrict__ b3l, const float* __restrict__ b3r,
                             float* __restrict__ o1, float* __restrict__ o2,
                             float* __restrict__ o3)
{
  const int i = blockIdx.x * 256 + threadIdx.x;
  if (i >= 3072) return;
  const int k = (i < 1536) ? i : i - 1536;
  o1[i] = (i < 1536) ? b1l[k] : b1r[k];
  o2[i] = (i < 1536) ? b2l[k] : b2r[k];
  o3[i] = (i < 1536) ? b3l[k] : b3r[k];
}

// ---------------------------------------------------------------- CSR build
__global__ void count_deg(const int* __restrict__ ei, int* __restrict__ counts)
{
  const int e = blockIdx.x * 256 + threadIdx.x;
  if (e >= ET) return;
  const int d = (e < NE) ? ei[NE + e] : (e - NE);
  atomicAdd(&counts[d], 1);
}

__global__ __launch_bounds__(1024)
void scan_deg(const int* __restrict__ counts, int* __restrict__ row_start, int* __restrict__ cursor)
{
  __shared__ int part[1024];
  const int tid = threadIdx.x;
  int loc[8], pre[8], s = 0;
#pragma unroll
  for (int j = 0; j < 8; ++j) { loc[j] = counts[tid * 8 + j]; pre[j] = s; s += loc[j]; }
  part[tid] = s;
  __syncthreads();
  for (int o = 1; o < 1024; o <<= 1) {
    const int v = part[tid];
    const int a = (tid >= o) ? part[tid - o] : 0;
    __syncthreads();
    part[tid] = v + a;
    __syncthreads();
  }
  const int excl = part[tid] - s;
#pragma unroll
  for (int j = 0; j < 8; ++j) {
    const int v = excl + pre[j];
    row_start[tid * 8 + j] = v;
    cursor[tid * 8 + j]    = v;
  }
  if (tid == 1023) row_start[8192] = excl + s;
}

__global__ void scatter_e(const int* __restrict__ ei, int* __restrict__ cursor,
                          int* __restrict__ csr_src, int* __restrict__ csr_dst)
{
  const int e = blockIdx.x * 256 + threadIdx.x;
  if (e >= ET) return;
  const int sx = (e < NE) ? ei[e]      : (e - NE);
  const int d  = (e < NE) ? ei[NE + e] : (e - NE);
  const int pos = atomicAdd(&cursor[d], 1);
  csr_src[pos] = sx;
  csr_dst[pos] = d;
}

// ---------------------------------------------------------------- GATv2 fused attention
// One wave per node. Single pass over the node's edges: read xl[src] row once
// (3 bf16x8/lane), compute logit (shuffle reduce, wave-uniform), online-softmax
// rescale a 24-f32/lane accumulator. out[i] = relu(acc/z + ob).
__global__ __launch_bounds__(256)
void gat_fused(const uint16_t* __restrict__ xlr, int ld,
               const int* __restrict__ csr_src, const int* __restrict__ row_start,
               const float* __restrict__ att, const float* __restrict__ ob,
               uint16_t* __restrict__ out, int ldc)
{
  const int node = (blockIdx.x << 2) + (threadIdx.x >> 6);
  const int lane = threadIdx.x & 63;

  float av[3][8], xr[3][8];
  const bf16x8* pr = (const bf16x8*)(xlr + (size_t)node * ld + 1536);
#pragma unroll
  for (int h = 0; h < 3; ++h) {
    const float4 a0 = *(const float4*)(att + h * 512 + lane * 8);
    const float4 a1 = *(const float4*)(att + h * 512 + lane * 8 + 4);
    av[h][0] = a0.x; av[h][1] = a0.y; av[h][2] = a0.z; av[h][3] = a0.w;
    av[h][4] = a1.x; av[h][5] = a1.y; av[h][6] = a1.z; av[h][7] = a1.w;
    const bf16x8 v = pr[h * 64 + lane];
#pragma unroll
    for (int j = 0; j < 8; ++j) xr[h][j] = bf2f((uint16_t)v[j]);
  }

  float m[3] = {-1e30f, -1e30f, -1e30f};
  float z[3] = {0.f, 0.f, 0.f};
  float acc[3][8];
#pragma unroll
  for (int h = 0; h < 3; ++h)
#pragma unroll
    for (int j = 0; j < 8; ++j) acc[h][j] = 0.f;

  const int s0 = row_start[node], s1 = row_start[node + 1];
  for (int s = s0; s < s1; ++s) {
    const bf16x8* pl = (const bf16x8*)(xlr + (size_t)csr_src[s] * ld);
    bf16x8 vl[3];
#pragma unroll
    for (int h = 0; h < 3; ++h) vl[h] = pl[h * 64 + lane];

    float hacc[3];
#pragma unroll
    for (int h = 0; h < 3; ++h) {
      float sacc = 0.f;
#pragma unroll
      for (int j = 0; j < 8; ++j) {
        float v = bf2f((uint16_t)vl[h][j]) + xr[h][j];
        v = v > 0.f ? v : 0.2f * v;
        sacc += v * av[h][j];
      }
      hacc[h] = sacc;
    }
#pragma unroll
    for (int o = 32; o; o >>= 1) {
      hacc[0] += __shfl_xor(hacc[0], o);
      hacc[1] += __shfl_xor(hacc[1], o);
      hacc[2] += __shfl_xor(hacc[2], o);
    }
    // online softmax update (wave-uniform scale/p)
#pragma unroll
    for (int h = 0; h < 3; ++h) {
      const float nm = fmaxf(m[h], hacc[h]);
      const float sc = __expf(m[h] - nm);
      const float p  = __expf(hacc[h] - nm);
      z[h] = z[h] * sc + p;
#pragma unroll
      for (int j = 0; j < 8; ++j)
        acc[h][j] = acc[h][j] * sc + p * bf2f((uint16_t)vl[h][j]);
      m[h] = nm;
    }
  }

#pragma unroll
  for (int h = 0; h < 3; ++h) {
    const float rz = 1.f / z[h];
    const float4 b0 = *(const float4*)(ob + h * 512 + lane * 8);
    const float4 b1 = *(const float4*)(ob + h * 512 + lane * 8 + 4);
    float bv[8] = {b0.x, b0.y, b0.z, b0.w, b1.x, b1.y, b1.z, b1.w};
    bf16x8 pk;
#pragma unroll
    for (int j = 0; j < 8; ++j) {
      const float v = fmaxf(acc[h][j] * rz + bv[j], 0.f);
      pk[j] = (short)f2bf(v);
    }
    *(bf16x8*)(out + (size_t)node * ldc + h * 512 + lane * 8) = pk;
  }
}

// ---------------------------------------------------------------- final dot
__global__ __launch_bounds__(256)
void final_dot(const uint16_t* __restrict__ z2, const float* __restrict__ w,
               const float* __restrict__ b, float* __restrict__ out)
{
  const int row  = blockIdx.x * 4 + (threadIdx.x >> 6);
  const int lane = threadIdx.x & 63;
  const uint16_t* p = z2 + (size_t)row * 512;
  float s = 0.f;
#pragma unroll
  for (int j = 0; j < 8; ++j) { const int c = lane + j * 64; s += bf2f(p[c]) * w[c]; }
#pragma unroll
  for (int o = 32; o; o >>= 1) s += __shfl_xor(s, o);
  if (lane == 0) out[row] = s + b[0];
}

// ---------------------------------------------------------------- orchestration
extern "C" void kernel_launch(void* const* d_in, const int* in_sizes, int n_in,
                              void* d_out, int out_size, void* d_ws, size_t ws_size,
                              hipStream_t stream)
{
  (void)in_sizes; (void)n_in; (void)out_size; (void)ws_size;

  const float* x    = (const float*)d_in[0];
  const int*   ei   = (const int*)  d_in[1];
  const float* expm = (const float*)d_in[2];
  const float* w1l = (const float*)d_in[3];  const float* b1l = (const float*)d_in[4];
  const float* w1r = (const float*)d_in[5];  const float* b1r = (const float*)d_in[6];
  const float* a1  = (const float*)d_in[7];  const float* o1  = (const float*)d_in[8];
  const float* w2l = (const float*)d_in[9];  const float* b2l = (const float*)d_in[10];
  const float* w2r = (const float*)d_in[11]; const float* b2r = (const float*)d_in[12];
  const float* a2  = (const float*)d_in[13]; const float* o2  = (const float*)d_in[14];
  const float* w3l = (const float*)d_in[15]; const float* b3l = (const float*)d_in[16];
  const float* w3r = (const float*)d_in[17]; const float* b3r = (const float*)d_in[18];
  const float* a3  = (const float*)d_in[19]; const float* o3  = (const float*)d_in[20];
  const float* e1w = (const float*)d_in[21]; const float* e1b = (const float*)d_in[22];
  const float* e2w = (const float*)d_in[23]; const float* e2b = (const float*)d_in[24];
  const float* e3w = (const float*)d_in[25]; const float* e3b = (const float*)d_in[26];
  const float* l1w = (const float*)d_in[27]; const float* l1b = (const float*)d_in[28];
  const float* l2w = (const float*)d_in[29]; const float* l2b = (const float*)d_in[30];
  const float* l3w = (const float*)d_in[31]; const float* l3b = (const float*)d_in[32];
  float* out = (float*)d_out;

  hipFuncSetAttribute((const void*)gemm256, hipFuncAttributeMaxDynamicSharedMemorySize, 131072);

  char* ws = (char*)d_ws;
  size_t off = 0;
  auto take = [&](size_t b) { char* p = ws + off; off += (b + 255) & ~(size_t)255; return p; };

  int*      counts    = (int*)take((size_t)NN * 4);
  int*      row_start = (int*)take((size_t)(NN + 1) * 4);
  int*      cursor    = (int*)take((size_t)NN * 4);
  int*      csr_src   = (int*)take((size_t)ET * 4);
  int*      csr_dst   = (int*)take((size_t)ET * 4);
  float*    bc1       = (float*)take(3072 * 4);
  float*    bc2       = (float*)take(3072 * 4);
  float*    bc3       = (float*)take(3072 * 4);
  uint16_t* zbuf      = (uint16_t*)take((size_t)NN * 2048 * 2);
  char*     regA      = take((size_t)NN * F_EXP_P * 2);
  char*     regW      = take((size_t)4096 * F_EXP_P * 2);
  char*     regC      = take((size_t)NN * 4096 * 2 + (size_t)NN * 1536 * 2);

  uint16_t* xbf   = (uint16_t*)regA;
  uint16_t* expbf = (uint16_t*)regA;
  uint16_t* wT    = (uint16_t*)regW;
  // phase 1: xlr [8192][3072] + hbuf [8192][1536]
  uint16_t* xlr   = (uint16_t*)regC;
  uint16_t* hbuf  = (uint16_t*)(regC + (size_t)NN * 3072 * 2);
  // phase 2 (encoder): cell1 [8192][4096] | cell2 [8192][1536]
  uint16_t* cell1 = (uint16_t*)regC;
  uint16_t* cell2 = (uint16_t*)(regC + (size_t)NN * 4096 * 2);
  // phase 3 (head): zz1 [8192][1024] | zz2 [8192][512]
  uint16_t* zz1   = (uint16_t*)regC;
  uint16_t* zz2   = (uint16_t*)(regC + (size_t)NN * 1024 * 2);

  // ---- CSR + fused biases
  hipMemsetAsync(counts, 0, (size_t)NN * 4, stream);
  count_deg<<<(ET + 255) / 256, 256, 0, stream>>>(ei, counts);
  scan_deg<<<1, 1024, 0, stream>>>(counts, row_start, cursor);
  scatter_e<<<(ET + 255) / 256, 256, 0, stream>>>(ei, cursor, csr_src, csr_dst);
  concat_bias3<<<12, 256, 0, stream>>>(b1l, b1r, b2l, b2r, b3l, b3r, bc1, bc2, bc3);

  // ---- GAT layer 1 (Kp = 3264), fused l|r GEMM -> xlr
  cvt_pad8<<<dim3((F_IN_P / 8 + 255) / 256, NN), 256, 0, stream>>>(x, xbf, F_IN, F_IN_P);
  transpose_w<<<dim3(F_IN_P / 32, 1536 / 32), dim3(32, 8), 0, stream>>>(w1l, wT, F_IN, 1536, F_IN_P, 1536);
  transpose_w<<<dim3(F_IN_P / 32, 1536 / 32), dim3(32, 8), 0, stream>>>(w1r, wT + (size_t)1536 * F_IN_P, F_IN, 1536, F_IN_P, 1536);
  gemm256<<<32 * 12, 512, 131072, stream>>>(xbf, wT, bc1, 3072, 0, xlr, F_IN_P, 3072, 12);
  gat_fused<<<NN / 4, 256, 0, stream>>>(xlr, 3072, csr_src, row_start, a1, o1, hbuf, 1536);

  // ---- GAT layer 2 (K = 1536)
  transpose_w<<<dim3(48, 48), dim3(32, 8), 0, stream>>>(w2l, wT, 1536, 1536, 1536, 1536);
  transpose_w<<<dim3(48, 48), dim3(32, 8), 0, stream>>>(w2r, wT + (size_t)1536 * 1536, 1536, 1536, 1536, 1536);
  gemm256<<<32 * 12, 512, 131072, stream>>>(hbuf, wT, bc2, 3072, 0, xlr, 1536, 3072, 12);
  gat_fused<<<NN / 4, 256, 0, stream>>>(xlr, 3072, csr_src, row_start, a2, o2, hbuf, 1536);

  // ---- GAT layer 3 -> zbuf cols [0,1536)
  transpose_w<<<dim3(48, 48), dim3(32, 8), 0, stream>>>(w3l, wT, 1536, 1536, 1536, 1536);
  transpose_w<<<dim3(48, 48), dim3(32, 8), 0, stream>>>(w3r, wT + (size_t)1536 * 1536, 1536, 1536, 1536, 1536);
  gemm256<<<32 * 12, 512, 131072, stream>>>(hbuf, wT, bc3, 3072, 0, xlr, 1536, 3072, 12);
  gat_fused<<<NN / 4, 256, 0, stream>>>(xlr, 3072, csr_src, row_start, a3, o3, zbuf, 2048);

  // ---- encoder: 7993 -> 4000 -> 1500 -> 512 (last into zbuf cols [1536,2048))
  cvt_pad8<<<dim3((F_EXP_P / 8 + 255) / 256, NN), 256, 0, stream>>>(expm, expbf, F_EXP, F_EXP_P);
  transpose_w<<<dim3(F_EXP_P / 32, 4096 / 32), dim3(32, 8), 0, stream>>>(e1w, wT, F_EXP, 4000, F_EXP_P, 4096);
  gemm256<<<32 * 16, 512, 131072, stream>>>(expbf, wT, e1b, 4000, 1, cell1, F_EXP_P, 4096, 16);
  transpose_w<<<dim3(4096 / 32, 1536 / 32), dim3(32, 8), 0, stream>>>(e2w, wT, 4000, 1500, 4096, 1536);
  gemm256<<<32 * 6, 512, 131072, stream>>>(cell1, wT, e2b, 1500, 1, cell2, 4096, 1536, 6);
  transpose_w<<<dim3(1536 / 32, 512 / 32), dim3(32, 8), 0, stream>>>(e3w, wT, 1500, 512, 1536, 512);
  gemm_bt<<<dim3(64, 4), 256, 0, stream>>>(cell2, wT, e3b, 512, 0, zbuf + 1536, 1536, 2048);

  // ---- head
  transpose_w<<<dim3(2048 / 32, 1024 / 32), dim3(32, 8), 0, stream>>>(l1w, wT, 2048, 1024, 2048, 1024);
  gemm_bt<<<dim3(64, 8), 256, 0, stream>>>(zbuf, wT, l1b, 1024, 1, zz1, 2048, 1024);
  transpose_w<<<dim3(1024 / 32, 512 / 32), dim3(32, 8), 0, stream>>>(l2w, wT, 1024, 512, 1024, 512);
  gemm_bt<<<dim3(64, 4), 256, 0, stream>>>(zz1, wT, l2b, 512, 1, zz2, 1024, 512);
  final_dot<<<NN / 4, 256, 0, stream>>>(zz2, l3w, l3b, out);
}

// Round 18
// 1377.305 us; speedup vs baseline: 1.2334x; 1.0017x over previous
//
#include <hip/hip_runtime.h>
#include <stdint.h>

#define NN 8192
#define NE 65536
#define ET (NE + NN)
#define F_IN   3247
#define F_IN_P 3264
#define F_EXP   7993
#define F_EXP_P 8000

typedef __attribute__((ext_vector_type(8))) short bf16x8;
typedef __attribute__((ext_vector_type(4))) float f32x4;

typedef const __attribute__((address_space(1))) void gvoid_t;
typedef __attribute__((address_space(3))) void lvoid_t;

__device__ __forceinline__ float bf2f(uint16_t u) {
  union { uint32_t i; float f; } v; v.i = ((uint32_t)u) << 16; return v.f;
}
__device__ __forceinline__ uint16_t f2bf(float f) {
  union { float f; uint32_t i; } v; v.f = f;
  uint32_t r = v.i + 0x7fffu + ((v.i >> 16) & 1u);  // RNE
  return (uint16_t)(r >> 16);
}

__device__ __forceinline__ void gld_lds16(const void* g, void* l) {
  __builtin_amdgcn_global_load_lds((gvoid_t*)g, (lvoid_t*)l, 16, 0, 0);
}

#define SBAR() __builtin_amdgcn_sched_barrier(0)
#define BARRIER() do { SBAR(); __builtin_amdgcn_s_barrier(); SBAR(); } while (0)
#define LGKM0() do { asm volatile("s_waitcnt lgkmcnt(0)" ::: "memory"); SBAR(); } while (0)
#define VMCNT(n) asm volatile("s_waitcnt vmcnt(" #n ")" ::: "memory")
#define MFMA16(a, b, c) __builtin_amdgcn_mfma_f32_16x16x32_bf16(a, b, c, 0, 0, 0)

// =================================================================== gemm256
// 256x256 tile, BK=64, 8 waves (2M x 4N). (m-half x k-slot) quadrant schedule,
// 24 frag reads/tile, 12/20 MFMA rebalance, 2 barriers/tile (R16-verified):
// tile-end barrier removed — edges covered by next tile's R1b LGKM0+barrier
// and end-R2 VMCNT(4)+barrier. Waves free-run across tile boundaries.
__device__ __forceinline__ void stage4(const char* src, char* dst, size_t Kb) {
#pragma unroll
  for (int j = 0; j < 4; ++j)
    gld_lds16(src + (size_t)(j * 64) * Kb, dst + j * 8192);
}

#define KTILE(T, BUF)                                                          \
  do {                                                                         \
    const char* aB_  = smem + (BUF) + arow;                                    \
    const char* bB_  = smem + 65536 + (BUF) + brow_o;                          \
    const char* aBn_ = smem + ((BUF) ^ 32768) + arow;                          \
    const char* bBn_ = smem + 65536 + ((BUF) ^ 32768) + brow_o;                \
    const bool nls = ((T) + 2 < nk);                                           \
    const bool nlr = ((T) + 1 < nk);                                           \
    /* R1a (4 reads, 12 MFMA): read a1; MFMA Q(mh0,k0) m=0..2 */               \
    _Pragma("unroll")                                                          \
    for (int m = 0; m < 4; ++m)                                                \
      a1f[m] = *(const bf16x8*)(aB_ + (m + 4) * 2048 + sw0);                   \
    SBAR();                                                                    \
    __builtin_amdgcn_s_setprio(1);                                             \
    _Pragma("unroll")                                                          \
    for (int m = 0; m < 3; ++m)                                                \
      _Pragma("unroll")                                                        \
      for (int n = 0; n < 4; ++n)                                              \
        acc[m][n] = MFMA16(a0f[m], b0f[n], acc[m][n]);                         \
    __builtin_amdgcn_s_setprio(0);                                             \
    SBAR();                                                                    \
    /* R1b (8 reads, 20 MFMA): deferred Q(mh0,k0) m=3; read a2->a0f, b1;       \
       MFMA Q(mh1,k0) */                                                       \
    __builtin_amdgcn_s_setprio(1);                                             \
    _Pragma("unroll")                                                          \
    for (int n = 0; n < 4; ++n)                                                \
      acc[3][n] = MFMA16(a0f[3], b0f[n], acc[3][n]);                           \
    __builtin_amdgcn_s_setprio(0);                                             \
    _Pragma("unroll")                                                          \
    for (int m = 0; m < 4; ++m)                                                \
      a0f[m] = *(const bf16x8*)(aB_ + m * 2048 + sw1);                         \
    _Pragma("unroll")                                                          \
    for (int n = 0; n < 4; ++n)                                                \
      b1f[n] = *(const bf16x8*)(bB_ + n * 2048 + sw1);                         \
    SBAR();                                                                    \
    __builtin_amdgcn_s_setprio(1);                                             \
    _Pragma("unroll")                                                          \
    for (int m = 0; m < 4; ++m)                                                \
      _Pragma("unroll")                                                        \
      for (int n = 0; n < 4; ++n)                                              \
        acc[m + 4][n] = MFMA16(a1f[m], b0f[n], acc[m + 4][n]);                 \
    __builtin_amdgcn_s_setprio(0);                                             \
    LGKM0();    /* ALL pending DS reads (incl. prev R3 other-buf) complete     \
                   before any wave's R2 B-stage */                             \
    BARRIER();                                                                 \
    /* R2 (4 reads, 12 MFMA): stage B(T+2); read a3; MFMA Q(mh0,k1) m=0..2;    \
       end: VMCNT drains A(T+1)+B(T+1) (cross-wave, barrier-backed) */         \
    if (nls) stage4(pB + (size_t)((T) + 2) * 128, sB + (BUF), Kb);             \
    _Pragma("unroll")                                                          \
    for (int m = 0; m < 4; ++m)                                                \
      a1f[m] = *(const bf16x8*)(aB_ + (m + 4) * 2048 + sw1);                   \
    SBAR();                                                                    \
    __builtin_amdgcn_s_setprio(1);                                             \
    _Pragma("unroll")                                                          \
    for (int m = 0; m < 3; ++m)                                                \
      _Pragma("unroll")                                                        \
      for (int n = 0; n < 4; ++n)                                              \
        acc[m][n] = MFMA16(a0f[m], b1f[n], acc[m][n]);                         \
    __builtin_amdgcn_s_setprio(0);                                             \
    if (nls)      { VMCNT(4); }                                                \
    else if (nlr) { VMCNT(0); }                                                \
    LGKM0();    /* a3 complete before any wave's R3 A-stage */                 \
    BARRIER();                                                                 \
    /* R3 (8 reads, 20 MFMA): deferred Q(mh0,k1) m=3; read a0',b0' (T+1 —      \
       DMAs barrier-backed complete); stage A(T+2); MFMA Q(mh1,k1).            \
       NO tile-end barrier: waves free-run into next tile's R1a. */            \
    __builtin_amdgcn_s_setprio(1);                                             \
    _Pragma("unroll")                                                          \
    for (int n = 0; n < 4; ++n)                                                \
      acc[3][n] = MFMA16(a0f[3], b1f[n], acc[3][n]);                           \
    __builtin_amdgcn_s_setprio(0);                                             \
    if (nlr) {                                                                 \
      _Pragma("unroll")                                                        \
      for (int m = 0; m < 4; ++m)                                              \
        a0f[m] = *(const bf16x8*)(aBn_ + m * 2048 + sw0);                      \
      _Pragma("unroll")                                                        \
      for (int n = 0; n < 4; ++n)                                              \
        b0f[n] = *(const bf16x8*)(bBn_ + n * 2048 + sw0);                      \
    }                                                                          \
    if (nls) stage4(pA + (size_t)((T) + 2) * 128, sA + (BUF), Kb);             \
    SBAR();                                                                    \
    __builtin_amdgcn_s_setprio(1);                                             \
    _Pragma("unroll")                                                          \
    for (int m = 0; m < 4; ++m)                                                \
      _Pragma("unroll")                                                        \
      for (int n = 0; n < 4; ++n)                                              \
        acc[m + 4][n] = MFMA16(a1f[m], b1f[n], acc[m + 4][n]);                 \
    __builtin_amdgcn_s_setprio(0);                                             \
    SBAR();                                                                    \
  } while (0)

__global__ __launch_bounds__(512, 2)
void gemm256(const uint16_t* __restrict__ A, const uint16_t* __restrict__ Bt,
             const float* __restrict__ bias, int biasN, int relu,
             uint16_t* __restrict__ C, int Kp, int ldc, int nbn)
{
  extern __shared__ char smem[];   // [A: 2buf x 4 x 64rows x 128B = 64K][B: same]
  const int tid = threadIdx.x;
  const int w = tid >> 6, lane = tid & 63;
  const int wr = w >> 2, wc = w & 3;
  const int fr = lane & 15, g = lane >> 4;

  // T1: bijective XCD swizzle
  const int nwg = (int)gridDim.x;
  const int id = (int)blockIdx.x;
  const int q = nwg >> 3, r = nwg & 7;
  const int xcd = id & 7, idx = id >> 3;
  const int wg = (xcd < r ? xcd * (q + 1) : r * (q + 1) + (xcd - r) * q) + idx;
  const int brow = (wg / nbn) * 256, bcol = (wg % nbn) * 256;

  const size_t Kb = (size_t)Kp * 2;

  // staging: thread tid -> LDS j*8192 + (tid>>3)*128 + (tid&7)*16 (lane*16 by HW)
  const int srow = tid >> 3;
  const int sswz = ((tid & 7) ^ (srow & 7)) * 16;
  const char* pA = (const char*)A + (size_t)(brow + srow) * Kb + sswz;
  const char* pB = (const char*)Bt + (size_t)(bcol + srow) * Kb + sswz;
  char* sA = smem + w * 1024;
  char* sB = smem + 65536 + w * 1024;

  // frag read: slot q=kk*4+g stored at q ^ (row&7), row&7 == fr&7
  const int sw0 = (g ^ (fr & 7)) * 16;
  const int sw1 = ((g + 4) ^ (fr & 7)) * 16;
  const int arow = (wr * 128 + fr) * 128;   // + m*2048
  const int brow_o = (wc * 64 + fr) * 128;  // + n*2048

  f32x4 acc[8][4];
#pragma unroll
  for (int m = 0; m < 8; ++m)
#pragma unroll
    for (int n = 0; n < 4; ++n) acc[m][n] = (f32x4){0.f, 0.f, 0.f, 0.f};
  bf16x8 a0f[4], a1f[4], b0f[4], b1f[4];

  // prologue: stage A(0),B(0),A(1),B(1); VMCNT(8) retires A(0),B(0)
  // (barrier-backed); preload a0,b0 of tile0
  stage4(pA, sA, Kb);
  stage4(pB, sB, Kb);
  stage4(pA + 128, sA + 32768, Kb);
  stage4(pB + 128, sB + 32768, Kb);
  VMCNT(8);
  BARRIER();
#pragma unroll
  for (int m = 0; m < 4; ++m)
    a0f[m] = *(const bf16x8*)(smem + arow + m * 2048 + sw0);
#pragma unroll
  for (int n = 0; n < 4; ++n)
    b0f[n] = *(const bf16x8*)(smem + 65536 + brow_o + n * 2048 + sw0);
  SBAR();

  const int nk = Kp >> 6;
  for (int t = 0; t < nk; t += 2) {
    KTILE(t, 0);
    if (t + 1 < nk) KTILE(t + 1, 32768);
  }

  // epilogue: C/D layout col=lane&15, row=(lane>>4)*4+j
#pragma unroll
  for (int m = 0; m < 8; ++m) {
    const int row = brow + wr * 128 + m * 16 + g * 4;
#pragma unroll
    for (int n = 0; n < 4; ++n) {
      const int col = bcol + wc * 64 + n * 16 + fr;
      const float bv = (col < biasN) ? bias[col] : 0.f;
#pragma unroll
      for (int j = 0; j < 4; ++j) {
        float v = acc[m][n][j] + bv;
        if (relu) v = fmaxf(v, 0.f);
        C[(size_t)(row + j) * ldc + col] = f2bf(v);
      }
    }
  }
}

// ---------------------------------------------------------------- GEMM (m97 structure, small N)
__global__ __launch_bounds__(256)
void gemm_bt(const uint16_t* __restrict__ A, const uint16_t* __restrict__ Bt,
             const float* __restrict__ bias, int biasN, int relu,
             uint16_t* __restrict__ C, int Kp, int ldc)
{
  __shared__ uint16_t As[128 * 32];
  __shared__ uint16_t Bs[128 * 32];
  const int tid  = threadIdx.x;
  const int wave = tid >> 6, lane = tid & 63;
  const int brow = blockIdx.x * 128, bcol = blockIdx.y * 128;
  const int wr = wave >> 1, wc = wave & 1;
  const int fr = lane & 15, g = lane >> 4;

  f32x4 acc[4][4];
#pragma unroll
  for (int m = 0; m < 4; ++m)
#pragma unroll
    for (int n = 0; n < 4; ++n) acc[m][n] = (f32x4){0.f, 0.f, 0.f, 0.f};

  const int rA = tid >> 2;
  const int kc = (tid & 3) * 8;
  const uint16_t* aptr = A  + (size_t)(brow + rA) * Kp + kc;
  const uint16_t* bptr = Bt + (size_t)(bcol + rA) * Kp + kc;
  char* ldsA = (char*)As + wave * 1024;
  char* ldsB = (char*)Bs + wave * 1024;
  const size_t rowskip = (size_t)64 * Kp;

  const int nk = Kp >> 5;
  for (int kt = 0; kt < nk; ++kt) {
    __syncthreads();
    gld_lds16(aptr,           ldsA);
    gld_lds16(aptr + rowskip, ldsA + 4096);
    gld_lds16(bptr,           ldsB);
    gld_lds16(bptr + rowskip, ldsB + 4096);
    aptr += 32; bptr += 32;
    __syncthreads();

    bf16x8 af[4], bfr[4];
#pragma unroll
    for (int m = 0; m < 4; ++m)
      af[m] = *(const bf16x8*)&As[(wr * 64 + m * 16 + fr) * 32 + g * 8];
#pragma unroll
    for (int n = 0; n < 4; ++n)
      bfr[n] = *(const bf16x8*)&Bs[(wc * 64 + n * 16 + fr) * 32 + g * 8];
#pragma unroll
    for (int m = 0; m < 4; ++m)
#pragma unroll
      for (int n = 0; n < 4; ++n)
        acc[m][n] = MFMA16(af[m], bfr[n], acc[m][n]);
  }

#pragma unroll
  for (int m = 0; m < 4; ++m) {
    const int row = brow + wr * 64 + m * 16 + g * 4;
#pragma unroll
    for (int n = 0; n < 4; ++n) {
      const int col = bcol + wc * 64 + n * 16 + fr;
      const float bv = (col < biasN) ? bias[col] : 0.f;
#pragma unroll
      for (int j = 0; j < 4; ++j) {
        float v = acc[m][n][j] + bv;
        if (relu) v = fmaxf(v, 0.f);
        C[(size_t)(row + j) * ldc + col] = f2bf(v);
      }
    }
  }
}

// ---------------------------------------------------------------- conversions
// G13: 8 cols/thread, 2x float4 loads + one bf16x8 store; scalar-guard tail.
__global__ __launch_bounds__(256)
void cvt_pad8(const float* __restrict__ in, uint16_t* __restrict__ out, int cols, int colsPad)
{
  const int r = blockIdx.y;
  const int c = (blockIdx.x * 256 + threadIdx.x) * 8;
  if (c >= colsPad) return;
  const float* ip = in + (size_t)r * cols;
  uint16_t* op = out + (size_t)r * colsPad + c;
  bf16x8 pk;
  if (c + 8 <= cols) {
    const float4 v0 = *(const float4*)(ip + c);
    const float4 v1 = *(const float4*)(ip + c + 4);
    pk[0] = (short)f2bf(v0.x); pk[1] = (short)f2bf(v0.y);
    pk[2] = (short)f2bf(v0.z); pk[3] = (short)f2bf(v0.w);
    pk[4] = (short)f2bf(v1.x); pk[5] = (short)f2bf(v1.y);
    pk[6] = (short)f2bf(v1.z); pk[7] = (short)f2bf(v1.w);
  } else {
#pragma unroll
    for (int j = 0; j < 8; ++j)
      pk[j] = (short)((c + j < cols) ? f2bf(ip[c + j]) : (uint16_t)0);
  }
  *(bf16x8*)op = pk;
}

// transpose: load phase coalesced f32; store phase 256 threads = 32 n-rows x
// 8 k-groups of 4 -> one 8B store (4x bf16) per thread (G13).
__global__ __launch_bounds__(256)
void transpose_w(const float* __restrict__ W, uint16_t* __restrict__ Wt,
                 int K, int N, int Kp, int Np)
{
  __shared__ float t[32][33];
  const int tx = threadIdx.x, ty = threadIdx.y;
  const int k0 = blockIdx.x * 32, n0 = blockIdx.y * 32;
#pragma unroll
  for (int j = 0; j < 4; ++j) {
    const int k = k0 + ty + j * 8, n = n0 + tx;
    t[ty + j * 8][tx] = (k < K && n < N) ? W[(size_t)k * N + n] : 0.f;
  }
  __syncthreads();
  const int idx = ty * 32 + tx;
  const int wn = idx >> 3;        // 0..31 (n-row within tile)
  const int wk = (idx & 7) * 4;   // 0,4,...,28 (k-group start)
  const int n = n0 + wn;
  uint16_t pk[4];
#pragma unroll
  for (int j = 0; j < 4; ++j) pk[j] = f2bf(t[wk + j][wn]);
  *(uint64_t*)(Wt + (size_t)n * Kp + k0 + wk) = *(const uint64_t*)pk;
}

__global__ void concat_bias3(const float* __restrict__ b1l, const float* __restrict__ b1r,
                             const float* __restrict__ b2l, const float* __restrict__ b2r,
                             const float* __restrict__ b3l, const float* __restrict__ b3r,
                             float* __restrict__ o1, float* __restrict__ o2,
                             float* __restrict__ o3)
{
  const int i = blockIdx.x * 256 + threadIdx.x;
  if (i >= 3072) return;
  const int k = (i < 1536) ? i : i - 1536;
  o1[i] = (i < 1536) ? b1l[k] : b1r[k];
  o2[i] = (i < 1536) ? b2l[k] : b2r[k];
  o3[i] = (i < 1536) ? b3l[k] : b3r[k];
}

// ---------------------------------------------------------------- CSR build
__global__ void count_deg(const int* __restrict__ ei, int* __restrict__ counts)
{
  const int e = blockIdx.x * 256 + threadIdx.x;
  if (e >= ET) return;
  const int d = (e < NE) ? ei[NE + e] : (e - NE);
  atomicAdd(&counts[d], 1);
}

__global__ __launch_bounds__(1024)
void scan_deg(const int* __restrict__ counts, int* __restrict__ row_start, int* __restrict__ cursor)
{
  __shared__ int part[1024];
  const int tid = threadIdx.x;
  int loc[8], pre[8], s = 0;
#pragma unroll
  for (int j = 0; j < 8; ++j) { loc[j] = counts[tid * 8 + j]; pre[j] = s; s += loc[j]; }
  part[tid] = s;
  __syncthreads();
  for (int o = 1; o < 1024; o <<= 1) {
    const int v = part[tid];
    const int a = (tid >= o) ? part[tid - o] : 0;
    __syncthreads();
    part[tid] = v + a;
    __syncthreads();
  }
  const int excl = part[tid] - s;
#pragma unroll
  for (int j = 0; j < 8; ++j) {
    const int v = excl + pre[j];
    row_start[tid * 8 + j] = v;
    cursor[tid * 8 + j]    = v;
  }
  if (tid == 1023) row_start[8192] = excl + s;
}

__global__ void scatter_e(const int* __restrict__ ei, int* __restrict__ cursor,
                          int* __restrict__ csr_src, int* __restrict__ csr_dst)
{
  const int e = blockIdx.x * 256 + threadIdx.x;
  if (e >= ET) return;
  const int sx = (e < NE) ? ei[e]      : (e - NE);
  const int d  = (e < NE) ? ei[NE + e] : (e - NE);
  const int pos = atomicAdd(&cursor[d], 1);
  csr_src[pos] = sx;
  csr_dst[pos] = d;
}

// ---------------------------------------------------------------- GATv2 fused attention
// One wave per node. Single pass over the node's edges: read xl[src] row once
// (3 bf16x8/lane), compute logit (shuffle reduce, wave-uniform), online-softmax
// rescale a 24-f32/lane accumulator. out[i] = relu(acc/z + ob).
__global__ __launch_bounds__(256)
void gat_fused(const uint16_t* __restrict__ xlr, int ld,
               const int* __restrict__ csr_src, const int* __restrict__ row_start,
               const float* __restrict__ att, const float* __restrict__ ob,
               uint16_t* __restrict__ out, int ldc)
{
  const int node = (blockIdx.x << 2) + (threadIdx.x >> 6);
  const int lane = threadIdx.x & 63;

  float av[3][8], xr[3][8];
  const bf16x8* pr = (const bf16x8*)(xlr + (size_t)node * ld + 1536);
#pragma unroll
  for (int h = 0; h < 3; ++h) {
    const float4 a0 = *(const float4*)(att + h * 512 + lane * 8);
    const float4 a1 = *(const float4*)(att + h * 512 + lane * 8 + 4);
    av[h][0] = a0.x; av[h][1] = a0.y; av[h][2] = a0.z; av[h][3] = a0.w;
    av[h][4] = a1.x; av[h][5] = a1.y; av[h][6] = a1.z; av[h][7] = a1.w;
    const bf16x8 v = pr[h * 64 + lane];
#pragma unroll
    for (int j = 0; j < 8; ++j) xr[h][j] = bf2f((uint16_t)v[j]);
  }

  float m[3] = {-1e30f, -1e30f, -1e30f};
  float z[3] = {0.f, 0.f, 0.f};
  float acc[3][8];
#pragma unroll
  for (int h = 0; h < 3; ++h)
#pragma unroll
    for (int j = 0; j < 8; ++j) acc[h][j] = 0.f;

  const int s0 = row_start[node], s1 = row_start[node + 1];
  for (int s = s0; s < s1; ++s) {
    const bf16x8* pl = (const bf16x8*)(xlr + (size_t)csr_src[s] * ld);
    bf16x8 vl[3];
#pragma unroll
    for (int h = 0; h < 3; ++h) vl[h] = pl[h * 64 + lane];

    float hacc[3];
#pragma unroll
    for (int h = 0; h < 3; ++h) {
      float sacc = 0.f;
#pragma unroll
      for (int j = 0; j < 8; ++j) {
        float v = bf2f((uint16_t)vl[h][j]) + xr[h][j];
        v = v > 0.f ? v : 0.2f * v;
        sacc += v * av[h][j];
      }
      hacc[h] = sacc;
    }
#pragma unroll
    for (int o = 32; o; o >>= 1) {
      hacc[0] += __shfl_xor(hacc[0], o);
      hacc[1] += __shfl_xor(hacc[1], o);
      hacc[2] += __shfl_xor(hacc[2], o);
    }
    // online softmax update (wave-uniform scale/p)
#pragma unroll
    for (int h = 0; h < 3; ++h) {
      const float nm = fmaxf(m[h], hacc[h]);
      const float sc = __expf(m[h] - nm);
      const float p  = __expf(hacc[h] - nm);
      z[h] = z[h] * sc + p;
#pragma unroll
      for (int j = 0; j < 8; ++j)
        acc[h][j] = acc[h][j] * sc + p * bf2f((uint16_t)vl[h][j]);
      m[h] = nm;
    }
  }

#pragma unroll
  for (int h = 0; h < 3; ++h) {
    const float rz = 1.f / z[h];
    const float4 b0 = *(const float4*)(ob + h * 512 + lane * 8);
    const float4 b1 = *(const float4*)(ob + h * 512 + lane * 8 + 4);
    float bv[8] = {b0.x, b0.y, b0.z, b0.w, b1.x, b1.y, b1.z, b1.w};
    bf16x8 pk;
#pragma unroll
    for (int j = 0; j < 8; ++j) {
      const float v = fmaxf(acc[h][j] * rz + bv[j], 0.f);
      pk[j] = (short)f2bf(v);
    }
    *(bf16x8*)(out + (size_t)node * ldc + h * 512 + lane * 8) = pk;
  }
}

// ---------------------------------------------------------------- final dot
__global__ __launch_bounds__(256)
void final_dot(const uint16_t* __restrict__ z2, const float* __restrict__ w,
               const float* __restrict__ b, float* __restrict__ out)
{
  const int row  = blockIdx.x * 4 + (threadIdx.x >> 6);
  const int lane = threadIdx.x & 63;
  const uint16_t* p = z2 + (size_t)row * 512;
  float s = 0.f;
#pragma unroll
  for (int j = 0; j < 8; ++j) { const int c = lane + j * 64; s += bf2f(p[c]) * w[c]; }
#pragma unroll
  for (int o = 32; o; o >>= 1) s += __shfl_xor(s, o);
  if (lane == 0) out[row] = s + b[0];
}

// ---------------------------------------------------------------- orchestration
extern "C" void kernel_launch(void* const* d_in, const int* in_sizes, int n_in,
                              void* d_out, int out_size, void* d_ws, size_t ws_size,
                              hipStream_t stream)
{
  (void)in_sizes; (void)n_in; (void)out_size; (void)ws_size;

  const float* x    = (const float*)d_in[0];
  const int*   ei   = (const int*)  d_in[1];
  const float* expm = (const float*)d_in[2];
  const float* w1l = (const float*)d_in[3];  const float* b1l = (const float*)d_in[4];
  const float* w1r = (const float*)d_in[5];  const float* b1r = (const float*)d_in[6];
  const float* a1  = (const float*)d_in[7];  const float* o1  = (const float*)d_in[8];
  const float* w2l = (const float*)d_in[9];  const float* b2l = (const float*)d_in[10];
  const float* w2r = (const float*)d_in[11]; const float* b2r = (const float*)d_in[12];
  const float* a2  = (const float*)d_in[13]; const float* o2  = (const float*)d_in[14];
  const float* w3l = (const float*)d_in[15]; const float* b3l = (const float*)d_in[16];
  const float* w3r = (const float*)d_in[17]; const float* b3r = (const float*)d_in[18];
  const float* a3  = (const float*)d_in[19]; const float* o3  = (const float*)d_in[20];
  const float* e1w = (const float*)d_in[21]; const float* e1b = (const float*)d_in[22];
  const float* e2w = (const float*)d_in[23]; const float* e2b = (const float*)d_in[24];
  const float* e3w = (const float*)d_in[25]; const float* e3b = (const float*)d_in[26];
  const float* l1w = (const float*)d_in[27]; const float* l1b = (const float*)d_in[28];
  const float* l2w = (const float*)d_in[29]; const float* l2b = (const float*)d_in[30];
  const float* l3w = (const float*)d_in[31]; const float* l3b = (const float*)d_in[32];
  float* out = (float*)d_out;

  hipFuncSetAttribute((const void*)gemm256, hipFuncAttributeMaxDynamicSharedMemorySize, 131072);

  char* ws = (char*)d_ws;
  size_t off = 0;
  auto take = [&](size_t b) { char* p = ws + off; off += (b + 255) & ~(size_t)255; return p; };

  int*      counts    = (int*)take((size_t)NN * 4);
  int*      row_start = (int*)take((size_t)(NN + 1) * 4);
  int*      cursor    = (int*)take((size_t)NN * 4);
  int*      csr_src   = (int*)take((size_t)ET * 4);
  int*      csr_dst   = (int*)take((size_t)ET * 4);
  float*    bc1       = (float*)take(3072 * 4);
  float*    bc2       = (float*)take(3072 * 4);
  float*    bc3       = (float*)take(3072 * 4);
  uint16_t* zbuf      = (uint16_t*)take((size_t)NN * 2048 * 2);
  char*     regA      = take((size_t)NN * F_EXP_P * 2);
  char*     regW      = take((size_t)4096 * F_EXP_P * 2);
  char*     regC      = take((size_t)NN * 4096 * 2 + (size_t)NN * 1536 * 2);

  uint16_t* xbf   = (uint16_t*)regA;
  uint16_t* expbf = (uint16_t*)regA;
  uint16_t* wT    = (uint16_t*)regW;
  // phase 1: xlr [8192][3072] + hbuf [8192][1536]
  uint16_t* xlr   = (uint16_t*)regC;
  uint16_t* hbuf  = (uint16_t*)(regC + (size_t)NN * 3072 * 2);
  // phase 2 (encoder): cell1 [8192][4096] | cell2 [8192][1536]
  uint16_t* cell1 = (uint16_t*)regC;
  uint16_t* cell2 = (uint16_t*)(regC + (size_t)NN * 4096 * 2);
  // phase 3 (head): zz1 [8192][1024] | zz2 [8192][512]
  uint16_t* zz1   = (uint16_t*)regC;
  uint16_t* zz2   = (uint16_t*)(regC + (size_t)NN * 1024 * 2);

  // ---- CSR + fused biases
  hipMemsetAsync(counts, 0, (size_t)NN * 4, stream);
  count_deg<<<(ET + 255) / 256, 256, 0, stream>>>(ei, counts);
  scan_deg<<<1, 1024, 0, stream>>>(counts, row_start, cursor);
  scatter_e<<<(ET + 255) / 256, 256, 0, stream>>>(ei, cursor, csr_src, csr_dst);
  concat_bias3<<<12, 256, 0, stream>>>(b1l, b1r, b2l, b2r, b3l, b3r, bc1, bc2, bc3);

  // ---- GAT layer 1 (Kp = 3264), fused l|r GEMM -> xlr
  cvt_pad8<<<dim3((F_IN_P / 8 + 255) / 256, NN), 256, 0, stream>>>(x, xbf, F_IN, F_IN_P);
  transpose_w<<<dim3(F_IN_P / 32, 1536 / 32), dim3(32, 8), 0, stream>>>(w1l, wT, F_IN, 1536, F_IN_P, 1536);
  transpose_w<<<dim3(F_IN_P / 32, 1536 / 32), dim3(32, 8), 0, stream>>>(w1r, wT + (size_t)1536 * F_IN_P, F_IN, 1536, F_IN_P, 1536);
  gemm256<<<32 * 12, 512, 131072, stream>>>(xbf, wT, bc1, 3072, 0, xlr, F_IN_P, 3072, 12);
  gat_fused<<<NN / 4, 256, 0, stream>>>(xlr, 3072, csr_src, row_start, a1, o1, hbuf, 1536);

  // ---- GAT layer 2 (K = 1536)
  transpose_w<<<dim3(48, 48), dim3(32, 8), 0, stream>>>(w2l, wT, 1536, 1536, 1536, 1536);
  transpose_w<<<dim3(48, 48), dim3(32, 8), 0, stream>>>(w2r, wT + (size_t)1536 * 1536, 1536, 1536, 1536, 1536);
  gemm256<<<32 * 12, 512, 131072, stream>>>(hbuf, wT, bc2, 3072, 0, xlr, 1536, 3072, 12);
  gat_fused<<<NN / 4, 256, 0, stream>>>(xlr, 3072, csr_src, row_start, a2, o2, hbuf, 1536);

  // ---- GAT layer 3 -> zbuf cols [0,1536)
  transpose_w<<<dim3(48, 48), dim3(32, 8), 0, stream>>>(w3l, wT, 1536, 1536, 1536, 1536);
  transpose_w<<<dim3(48, 48), dim3(32, 8), 0, stream>>>(w3r, wT + (size_t)1536 * 1536, 1536, 1536, 1536, 1536);
  gemm256<<<32 * 12, 512, 131072, stream>>>(hbuf, wT, bc3, 3072, 0, xlr, 1536, 3072, 12);
  gat_fused<<<NN / 4, 256, 0, stream>>>(xlr, 3072, csr_src, row_start, a3, o3, zbuf, 2048);

  // ---- encoder: 7993 -> 4000 -> 1500 -> 512 (last into zbuf cols [1536,2048))
  cvt_pad8<<<dim3((F_EXP_P / 8 + 255) / 256, NN), 256, 0, stream>>>(expm, expbf, F_EXP, F_EXP_P);
  transpose_w<<<dim3(F_EXP_P / 32, 4096 / 32), dim3(32, 8), 0, stream>>>(e1w, wT, F_EXP, 4000, F_EXP_P, 4096);
  gemm256<<<32 * 16, 512, 131072, stream>>>(expbf, wT, e1b, 4000, 1, cell1, F_EXP_P, 4096, 16);
  transpose_w<<<dim3(4096 / 32, 1536 / 32), dim3(32, 8), 0, stream>>>(e2w, wT, 4000, 1500, 4096, 1536);
  gemm256<<<32 * 6, 512, 131072, stream>>>(cell1, wT, e2b, 1500, 1, cell2, 4096, 1536, 6);
  transpose_w<<<dim3(1536 / 32, 512 / 32), dim3(32, 8), 0, stream>>>(e3w, wT, 1500, 512, 1536, 512);
  gemm_bt<<<dim3(64, 4), 256, 0, stream>>>(cell2, wT, e3b, 512, 0, zbuf + 1536, 1536, 2048);

  // ---- head
  transpose_w<<<dim3(2048 / 32, 1024 / 32), dim3(32, 8), 0, stream>>>(l1w, wT, 2048, 1024, 2048, 1024);
  gemm_bt<<<dim3(64, 8), 256, 0, stream>>>(zbuf, wT, l1b, 1024, 1, zz1, 2048, 1024);
  transpose_w<<<dim3(1024 / 32, 512 / 32), dim3(32, 8), 0, stream>>>(l2w, wT, 1024, 512, 1024, 512);
  gemm_bt<<<dim3(64, 4), 256, 0, stream>>>(zz1, wT, l2b, 512, 1, zz2, 1024, 512);
  final_dot<<<NN / 4, 256, 0, stream>>>(zz2, l3w, l3b, out);
}